// Round 5
// baseline (240.140 us; speedup 1.0000x reference)
//
#include <hip/hip_runtime.h>
#include <math.h>

#define N_DIA 48
#define NTOT  3072     // N utterances
#define DD    512      // D == H
#define M3    9216     // 3N
#define SEG   ((size_t)NTOT * DD)

#define SCALE_F 0.99999f
#define PI_F    3.14159274101257324f

typedef __attribute__((ext_vector_type(8))) short frag8;
typedef __attribute__((ext_vector_type(4))) float f32x4;

__device__ __forceinline__ float ang_sim(float cs) {
    float cc = cs * SCALE_F;
    cc = fminf(fmaxf(cc, -SCALE_F), SCALE_F);
    return 1.0f - acosf(cc) / PI_F;
}
__device__ __forceinline__ unsigned short f2bf(float x) {
    union { float f; unsigned int u; } c; c.f = x;
    unsigned int r = c.u + 0x7fffu + ((c.u >> 16) & 1u);
    return (unsigned short)(r >> 16);
}
__device__ __forceinline__ float bf2f(unsigned short h) {
    union { unsigned int u; float f; } c; c.u = ((unsigned int)h) << 16;
    return c.f;
}
__device__ __forceinline__ void gload16(const unsigned short* g, unsigned short* s) {
    __builtin_amdgcn_global_load_lds(
        (const __attribute__((address_space(1))) unsigned int*)g,
        (__attribute__((address_space(3))) unsigned int*)s, 16, 0, 0);
}
__device__ __forceinline__ float d8(float4 x0, float4 x1, float4 y0, float4 y1) {
    return x0.x*y0.x + x0.y*y0.y + x0.z*y0.z + x0.w*y0.w
         + x1.x*y1.x + x1.y*y1.y + x1.z*y1.z + x1.w*y1.w;
}

// ---------- K1: blocks [0,144): self-contained pre+gram per (dialogue, modality)
//            blocks [144,528): W -> bf16 [n][k], 2 tiles per block ----------
__global__ __launch_bounds__(512) void k_pre_gram_wt(
    const float* __restrict__ a, const float* __restrict__ v,
    const float* __restrict__ l, const float* __restrict__ qmask,
    const float* __restrict__ Wspk, const float* __restrict__ W0,
    const float* __restrict__ Wg,
    float* __restrict__ out, unsigned short* __restrict__ xb,
    float* __restrict__ cross, float* __restrict__ blk,
    float* __restrict__ dinv, unsigned short* __restrict__ Wt)
{
    __shared__ __align__(16) char smem[66816];
    int b = blockIdx.x;
    int t = threadIdx.x;

    if (b >= 144) {
        // ---- wt flavor: two 32x32 transpose tiles per block ----
        float (*tile)[32][33] = (float (*)[32][33])smem;
        int sub = t >> 8, tid = t & 255;
        int idx = (b - 144) * 2 + sub;
        int mm = idx >> 8, rem = idx & 255;
        int by = rem >> 4, bx = rem & 15;
        const float* W = (mm == 0) ? W0 : Wg + (size_t)(mm - 1) * DD * DD;
        int tx = tid & 31, ty = tid >> 5;
#pragma unroll
        for (int q = 0; q < 4; q++) {
            int k = by * 32 + ty + q * 8;
            tile[sub][ty + q * 8][tx] = W[(size_t)k * DD + bx * 32 + tx];
        }
        __syncthreads();
#pragma unroll
        for (int q = 0; q < 4; q++) {
            int n = bx * 32 + ty + q * 8;
            Wt[(size_t)mm * DD * DD + (size_t)n * DD + by * 32 + tx] = f2bf(tile[sub][tx][ty + q * 8]);
        }
        return;
    }

    // ---- gram flavor ----
    unsigned short* Xs = (unsigned short*)smem;          // 64 KB
    float* invnL = (float*)(smem + 65536);               // [64]
    float* c1L = invnL + 64;                             // [64]
    float* c2L = c1L + 64;                               // [64]
    int d = b % N_DIA, m = b / N_DIA;
    int lane = t & 63, wv = t >> 6;                      // 8 waves
    int dbase = d * 64;

    // streaming: 8 utterances per wave; lane covers cols lane*8..lane*8+7
    for (int u = 0; u < 8; u++) {
        int r = u * 8 + wv;
        int i = dbase + r;
        int qb = (r * N_DIA + d) * 2;
        float q0 = qmask[qb], q1 = qmask[qb + 1];
        int spk = (q0 >= q1) ? 0 : 1;
        const float4* ap = (const float4*)(a + (size_t)i * DD) + lane * 2;
        const float4* vp = (const float4*)(v + (size_t)i * DD) + lane * 2;
        const float4* lp = (const float4*)(l + (size_t)i * DD) + lane * 2;
        const float4* wp = (const float4*)(Wspk + (size_t)spk * DD) + lane * 2;
        float4 a0 = ap[0], a1 = ap[1];
        float4 v0 = vp[0], v1 = vp[1];
        float4 l0 = lp[0], l1 = lp[1];
        float4 w0 = wp[0], w1 = wp[1];
        float4 L0 = make_float4(l0.x + w0.x, l0.y + w0.y, l0.z + w0.z, l0.w + w0.w);
        float4 L1 = make_float4(l1.x + w1.x, l1.y + w1.y, l1.z + w1.z, l1.w + w1.w);
        // out x-columns for own modality only
        float* ob = out + (size_t)i * 3072 + m * 1024 + lane * 8;
        if (m == 0)      { *(float4*)ob = a0; *(float4*)(ob + 4) = a1; }
        else if (m == 1) { *(float4*)ob = v0; *(float4*)(ob + 4) = v1; }
        else             { *(float4*)ob = L0; *(float4*)(ob + 4) = L1; }
        // own-modality bf16 -> xb global + Xs LDS (gram layout, unit-swizzled)
        float4 m0, m1;
        if (m == 0) { m0 = a0; m1 = a1; } else if (m == 1) { m0 = v0; m1 = v1; }
        else { m0 = L0; m1 = L1; }
        ushort4 y0, y1;
        y0.x = f2bf(m0.x); y0.y = f2bf(m0.y); y0.z = f2bf(m0.z); y0.w = f2bf(m0.w);
        y1.x = f2bf(m1.x); y1.y = f2bf(m1.y); y1.z = f2bf(m1.z); y1.w = f2bf(m1.w);
        unsigned short* xg = xb + (size_t)m * SEG + (size_t)i * DD + lane * 8;
        *(ushort4*)xg = y0; *(ushort4*)(xg + 4) = y1;
        unsigned short* xd = &Xs[(lane >> 2) * 2048 + r * 32 + (((lane & 3) ^ (r & 3)) << 3)];
        *(ushort4*)xd = y0; *(ushort4*)(xd + 4) = y1;
        // fp32 dots
        float saa = d8(a0, a1, a0, a1), svv = d8(v0, v1, v0, v1), sll = d8(L0, L1, L0, L1);
        float sav = d8(a0, a1, v0, v1), sal = d8(a0, a1, L0, L1), svl = d8(v0, v1, L0, L1);
#pragma unroll
        for (int off = 32; off; off >>= 1) {
            saa += __shfl_down(saa, off, 64);
            svv += __shfl_down(svv, off, 64);
            sll += __shfl_down(sll, off, 64);
            sav += __shfl_down(sav, off, 64);
            sal += __shfl_down(sal, off, 64);
            svl += __shfl_down(svl, off, 64);
        }
        if (lane == 0) {
            float ina = 1.0f / sqrtf(saa);
            float inv_ = 1.0f / sqrtf(svv);
            float inl = 1.0f / sqrtf(sll);
            float s_av = ang_sim(sav * ina * inv_);
            float s_al = ang_sim(sal * ina * inl);
            float s_vl = ang_sim(svl * inv_ * inl);
            if (m == 0) { cross[i] = s_av; cross[NTOT + i] = s_al; cross[2 * NTOT + i] = s_vl; }
            invnL[r] = (m == 0) ? ina : ((m == 1) ? inv_ : inl);
            c1L[r] = (m == 2) ? s_al : s_av;
            c2L[r] = (m == 0) ? s_al : s_vl;
        }
    }
    __syncthreads();

    if (wv < 4) {
        int rsel = lane & 15, quad = lane >> 4;
        int sq = (quad ^ (rsel & 3)) * 8;
        f32x4 acc[4];
#pragma unroll
        for (int j = 0; j < 4; j++) acc[j] = (f32x4){0.f, 0.f, 0.f, 0.f};
#pragma unroll
        for (int c = 0; c < 16; c++) {
            const unsigned short* base = &Xs[c * 2048];
            frag8 bf[4];
#pragma unroll
            for (int j = 0; j < 4; j++)
                bf[j] = *(const frag8*)&base[(j * 16 + rsel) * 32 + sq];
            frag8 af = *(const frag8*)&base[(wv * 16 + rsel) * 32 + sq];
#pragma unroll
            for (int j = 0; j < 4; j++)
                acc[j] = __builtin_amdgcn_mfma_f32_16x16x32_bf16(af, bf[j], acc[j], 0, 0, 0);
        }
        size_t bbase = (size_t)(m * N_DIA + d) * 4096;
        int rowl0 = wv * 16 + quad * 4;
        float ir[4], rs[4] = {0.f, 0.f, 0.f, 0.f};
#pragma unroll
        for (int r = 0; r < 4; r++) ir[r] = invnL[rowl0 + r];
#pragma unroll
        for (int j = 0; j < 4; j++) {
            int coll = j * 16 + rsel;
            float ic = invnL[coll];
#pragma unroll
            for (int r = 0; r < 4; r++) {
                float sim = ang_sim(acc[j][r] * ir[r] * ic);
                blk[bbase + (size_t)(rowl0 + r) * 64 + coll] = sim;
                rs[r] += sim;
            }
        }
#pragma unroll
        for (int off = 8; off; off >>= 1)
#pragma unroll
            for (int r = 0; r < 4; r++) rs[r] += __shfl_down(rs[r], off, 16);
        if (rsel == 0) {
#pragma unroll
            for (int r = 0; r < 4; r++) {
                int rl = rowl0 + r;
                dinv[m * NTOT + dbase + rl] = 1.0f / sqrtf(rs[r] + c1L[rl] + c2L[rl]);
            }
        }
    }
}

// ---------- K2: fused h0 -> G1(rows+T) -> P02, 32 rows x 512 cols per block ----------
__global__ __launch_bounds__(512) void k_fgemm(
    const unsigned short* __restrict__ xb, const unsigned short* __restrict__ Wt,
    const float* __restrict__ bias,
    unsigned short* __restrict__ G1r, unsigned short* __restrict__ G1T,
    unsigned short* __restrict__ P02, float th1, float th2)
{
    __shared__ __align__(16) char smem[102400];
    unsigned short* const Xs0 = (unsigned short*)smem;             // 2 KB
    unsigned short* const Xs1 = (unsigned short*)(smem + 2048);
    unsigned short* const Bs0 = (unsigned short*)(smem + 4096);    // 32 KB
    unsigned short* const Bs1 = (unsigned short*)(smem + 36864);
    unsigned short* const H0s = (unsigned short*)(smem + 69632);   // 32 KB
    unsigned short* const tS  = (unsigned short*)(smem + 4096);    // epilogue staging (Bs region)

    int t = threadIdx.x, lane = t & 63, wv = t >> 6;
    int mbase = blockIdx.x * 32;
    int srow = lane >> 2;
    int scol = ((lane & 3) ^ (srow & 3)) * 8;
    int rsel = lane & 15, quad = lane >> 4;
    int sq = (quad ^ (rsel & 3)) * 8;

    const unsigned short* W0t = Wt;
    const unsigned short* W1t = Wt + (size_t)DD * DD;
    const unsigned short* W2t = Wt + (size_t)2 * DD * DD;
    const unsigned short* Ag = xb + (size_t)(mbase + wv * 16 + srow) * DD + scol;  // wv<2

    f32x4 acc[8];

#define STAGE_B(Wb, kt, Bd) do { \
    const unsigned short* _s = (Wb) + (size_t)(wv * 64 + srow) * DD + (kt) * 32 + scol; \
    unsigned short* _d = (Bd) + (wv * 64) * 32; \
    gload16(_s,                       _d); \
    gload16(_s + (size_t)16 * DD,     _d + 512); \
    gload16(_s + (size_t)32 * DD,     _d + 1024); \
    gload16(_s + (size_t)48 * DD,     _d + 1536); \
} while (0)

    // ---- phase A: h0 = relu(xb @ W0 + b0) -> H0s (LDS only) ----
#pragma unroll
    for (int z = 0; z < 8; z++) acc[z] = (f32x4){0.f, 0.f, 0.f, 0.f};
    if (wv < 2) gload16(Ag, Xs0 + wv * 512);
    STAGE_B(W0t, 0, Bs0);
    for (int kt = 0; kt < 16; kt++) {
        __syncthreads();
        const unsigned short* Xc = (kt & 1) ? Xs1 : Xs0;
        const unsigned short* Bc = (kt & 1) ? Bs1 : Bs0;
        if (kt < 15) {
            unsigned short* Xn = (kt & 1) ? Xs0 : Xs1;
            unsigned short* Bn = (kt & 1) ? Bs0 : Bs1;
            if (wv < 2) gload16(Ag + (kt + 1) * 32, Xn + wv * 512);
            STAGE_B(W0t, kt + 1, Bn);
        }
        frag8 af[2], bfr[4];
#pragma unroll
        for (int i = 0; i < 2; i++)
            af[i] = *(const frag8*)&Xc[(i * 16 + rsel) * 32 + sq];
#pragma unroll
        for (int j = 0; j < 4; j++)
            bfr[j] = *(const frag8*)&Bc[(wv * 64 + j * 16 + rsel) * 32 + sq];
#pragma unroll
        for (int i = 0; i < 2; i++)
#pragma unroll
            for (int j = 0; j < 4; j++)
                acc[i * 4 + j] = __builtin_amdgcn_mfma_f32_16x16x32_bf16(
                    af[i], bfr[j], acc[i * 4 + j], 0, 0, 0);
    }
#pragma unroll
    for (int i = 0; i < 2; i++)
#pragma unroll
        for (int j = 0; j < 4; j++) {
            int col = wv * 64 + j * 16 + rsel;
            float bv = bias[col];
#pragma unroll
            for (int rr = 0; rr < 4; rr++) {
                int row = i * 16 + quad * 4 + rr;
                float x = fmaxf(acc[i * 4 + j][rr] + bv, 0.f);
                H0s[row * 512 + (((col >> 3) ^ (row & 7)) << 3) + (col & 7)] = f2bf(x);
            }
        }

    // ---- phase B: G1 = th1*(h0@W1) + (1-th1)*h0 ----
#pragma unroll
    for (int z = 0; z < 8; z++) acc[z] = (f32x4){0.f, 0.f, 0.f, 0.f};
    STAGE_B(W1t, 0, Bs0);
    for (int kt = 0; kt < 16; kt++) {
        __syncthreads();
        const unsigned short* Bc = (kt & 1) ? Bs1 : Bs0;
        if (kt < 15) {
            unsigned short* Bn = (kt & 1) ? Bs0 : Bs1;
            STAGE_B(W1t, kt + 1, Bn);
        }
        frag8 af[2], bfr[4];
#pragma unroll
        for (int i = 0; i < 2; i++) {
            int row = i * 16 + rsel;
            int pu = (kt * 4 + quad) ^ (row & 7);
            af[i] = *(const frag8*)&H0s[row * 512 + pu * 8];
        }
#pragma unroll
        for (int j = 0; j < 4; j++)
            bfr[j] = *(const frag8*)&Bc[(wv * 64 + j * 16 + rsel) * 32 + sq];
#pragma unroll
        for (int i = 0; i < 2; i++)
#pragma unroll
            for (int j = 0; j < 4; j++)
                acc[i * 4 + j] = __builtin_amdgcn_mfma_f32_16x16x32_bf16(
                    af[i], bfr[j], acc[i * 4 + j], 0, 0, 0);
    }
    {
        float om1 = 1.0f - th1;
#pragma unroll
        for (int i = 0; i < 2; i++)
#pragma unroll
            for (int j = 0; j < 4; j++) {
                int col = wv * 64 + j * 16 + rsel;
#pragma unroll
                for (int rr = 0; rr < 4; rr++) {
                    int row = i * 16 + quad * 4 + rr;
                    float h0v = bf2f(H0s[row * 512 + (((col >> 3) ^ (row & 7)) << 3) + (col & 7)]);
                    acc[i * 4 + j][rr] = th1 * acc[i * 4 + j][rr] + om1 * h0v;
                }
            }
    }
    __syncthreads();                       // all Bs reads done
#pragma unroll
    for (int i = 0; i < 2; i++)
#pragma unroll
        for (int j = 0; j < 4; j++) {
            int col = wv * 64 + j * 16 + rsel;
#pragma unroll
            for (int rr = 0; rr < 4; rr++)
                tS[(i * 16 + quad * 4 + rr) * 520 + col] = f2bf(acc[i * 4 + j][rr]);
        }
    __syncthreads();
    {
        int rw = t >> 4, c0 = (t & 15) * 32;
        unsigned short* dst = G1r + (size_t)(mbase + rw) * DD + c0;
#pragma unroll
        for (int u = 0; u < 4; u++)
            *(uint4*)(dst + u * 8) = *(const uint4*)&tS[rw * 520 + c0 + u * 8];
    }
    __syncthreads();
#pragma unroll
    for (int i = 0; i < 2; i++)
#pragma unroll
        for (int j = 0; j < 4; j++) {
            int col = wv * 64 + j * 16 + rsel;
            ushort4 w4;
            w4.x = f2bf(acc[i * 4 + j][0]); w4.y = f2bf(acc[i * 4 + j][1]);
            w4.z = f2bf(acc[i * 4 + j][2]); w4.w = f2bf(acc[i * 4 + j][3]);
            *(ushort4*)&tS[col * 40 + i * 16 + quad * 4] = w4;
        }
    __syncthreads();
    {
        unsigned short* dst = G1T + (size_t)t * M3 + mbase;
#pragma unroll
        for (int u = 0; u < 4; u++)
            *(uint4*)(dst + u * 8) = *(const uint4*)&tS[t * 40 + u * 8];
    }
    __syncthreads();

    // ---- phase C: P02 = th2*(h0@W2) + (1-th2)*h0 ----
#pragma unroll
    for (int z = 0; z < 8; z++) acc[z] = (f32x4){0.f, 0.f, 0.f, 0.f};
    STAGE_B(W2t, 0, Bs0);
    for (int kt = 0; kt < 16; kt++) {
        __syncthreads();
        const unsigned short* Bc = (kt & 1) ? Bs1 : Bs0;
        if (kt < 15) {
            unsigned short* Bn = (kt & 1) ? Bs0 : Bs1;
            STAGE_B(W2t, kt + 1, Bn);
        }
        frag8 af[2], bfr[4];
#pragma unroll
        for (int i = 0; i < 2; i++) {
            int row = i * 16 + rsel;
            int pu = (kt * 4 + quad) ^ (row & 7);
            af[i] = *(const frag8*)&H0s[row * 512 + pu * 8];
        }
#pragma unroll
        for (int j = 0; j < 4; j++)
            bfr[j] = *(const frag8*)&Bc[(wv * 64 + j * 16 + rsel) * 32 + sq];
#pragma unroll
        for (int i = 0; i < 2; i++)
#pragma unroll
            for (int j = 0; j < 4; j++)
                acc[i * 4 + j] = __builtin_amdgcn_mfma_f32_16x16x32_bf16(
                    af[i], bfr[j], acc[i * 4 + j], 0, 0, 0);
    }
    {
        float om2 = 1.0f - th2;
#pragma unroll
        for (int i = 0; i < 2; i++)
#pragma unroll
            for (int j = 0; j < 4; j++) {
                int col = wv * 64 + j * 16 + rsel;
#pragma unroll
                for (int rr = 0; rr < 4; rr++) {
                    int row = i * 16 + quad * 4 + rr;
                    float h0v = bf2f(H0s[row * 512 + (((col >> 3) ^ (row & 7)) << 3) + (col & 7)]);
                    acc[i * 4 + j][rr] = th2 * acc[i * 4 + j][rr] + om2 * h0v;
                }
            }
    }
    __syncthreads();
#pragma unroll
    for (int i = 0; i < 2; i++)
#pragma unroll
        for (int j = 0; j < 4; j++) {
            int col = wv * 64 + j * 16 + rsel;
#pragma unroll
            for (int rr = 0; rr < 4; rr++)
                tS[(i * 16 + quad * 4 + rr) * 520 + col] = f2bf(acc[i * 4 + j][rr]);
        }
    __syncthreads();
    {
        int rw = t >> 4, c0 = (t & 15) * 32;
        unsigned short* dst = P02 + (size_t)(mbase + rw) * DD + c0;
#pragma unroll
        for (int u = 0; u < 4; u++)
            *(uint4*)(dst + u * 8) = *(const uint4*)&tS[rw * 520 + c0 + u * 8];
    }
#undef STAGE_B
}

// ---------- GEMM: 64(M) x 128(N) tile, dbuf LDS, swizzled, coalesced LDS epilogue ----------
__global__ __launch_bounds__(256) void k_gemm(
    const unsigned short* __restrict__ A, const unsigned short* __restrict__ W,
    const float* __restrict__ bias,
    unsigned short* __restrict__ oRows, unsigned short* __restrict__ oT,
    float theta, int mode,
    const unsigned short* __restrict__ A2, unsigned short* __restrict__ oRows2)
{
    __shared__ __align__(16) char smem[53248];
    unsigned short* const As0 = (unsigned short*)smem;            // 4 KB
    unsigned short* const As1 = (unsigned short*)(smem + 4096);
    unsigned short* const Bs0 = (unsigned short*)(smem + 8192);   // 8 KB
    unsigned short* const Bs1 = (unsigned short*)(smem + 16384);
    unsigned short* const tH  = (unsigned short*)smem;            // [64][136]
    unsigned short* const tR  = (unsigned short*)(smem + 17408);  // [64][136]
    unsigned short* const tT  = (unsigned short*)(smem + 34816);  // [128][72]

    int t = threadIdx.x, lane = t & 63, wv = t >> 6;
    int bx = blockIdx.x, by = blockIdx.y;
    const unsigned short* Ap = A;
    unsigned short* oR = oRows;
    unsigned short* oTp = oT;
    if (by >= 144) { Ap = A2; oR = oRows2; oTp = nullptr; by -= 144; }
    int mbase = by * 64, nbase = bx * 128;
    int srow = lane >> 2;
    int scol = (((lane & 3) ^ (srow & 3)) * 8);
    int rsel = lane & 15, quad = lane >> 4;
    int sq = (quad ^ (rsel & 3)) * 8;

    const unsigned short* Ag  = Ap + (size_t)(mbase + wv * 16 + srow) * DD + scol;
    const unsigned short* Bg0 = W  + (size_t)(nbase + wv * 32 + srow) * DD + scol;
    const unsigned short* Bg1 = W  + (size_t)(nbase + wv * 32 + 16 + srow) * DD + scol;

    f32x4 acc[8];
#pragma unroll
    for (int i = 0; i < 8; i++) acc[i] = (f32x4){0.f, 0.f, 0.f, 0.f};

    gload16(Ag,  As0 + wv * 512);
    gload16(Bg0, Bs0 + wv * 1024);
    gload16(Bg1, Bs0 + wv * 1024 + 512);

#pragma unroll
    for (int kt = 0; kt < 16; kt++) {
        __syncthreads();
        const unsigned short* Ac = (kt & 1) ? As1 : As0;
        const unsigned short* Bc = (kt & 1) ? Bs1 : Bs0;
        if (kt < 15) {
            unsigned short* An = (kt & 1) ? As0 : As1;
            unsigned short* Bn = (kt & 1) ? Bs0 : Bs1;
            gload16(Ag + (kt + 1) * 32,  An + wv * 512);
            gload16(Bg0 + (kt + 1) * 32, Bn + wv * 1024);
            gload16(Bg1 + (kt + 1) * 32, Bn + wv * 1024 + 512);
        }
        frag8 af[4], bfr[2];
#pragma unroll
        for (int i = 0; i < 4; i++)
            af[i] = *(const frag8*)&Ac[(i * 16 + rsel) * 32 + sq];
#pragma unroll
        for (int j = 0; j < 2; j++)
            bfr[j] = *(const frag8*)&Bc[(wv * 32 + j * 16 + rsel) * 32 + sq];
#pragma unroll
        for (int i = 0; i < 4; i++)
#pragma unroll
            for (int j = 0; j < 2; j++)
                acc[i * 2 + j] = __builtin_amdgcn_mfma_f32_16x16x32_bf16(
                    af[i], bfr[j], acc[i * 2 + j], 0, 0, 0);
    }
    __syncthreads();

    int r = t >> 2, c0 = (t & 3) * 32;
    if (mode == 1) {
        const unsigned short* srcA = Ap + (size_t)(mbase + r) * DD + nbase + c0;
#pragma unroll
        for (int u = 0; u < 4; u++)
            *(uint4*)&tH[r * 136 + c0 + u * 8] = *(const uint4*)(srcA + u * 8);
        __syncthreads();
    }
    float omt = 1.0f - theta;
#pragma unroll
    for (int i = 0; i < 4; i++)
#pragma unroll
        for (int j = 0; j < 2; j++) {
            int cl = wv * 32 + j * 16 + rsel;
            float bv = 0.f;
            if (mode == 0) bv = bias[nbase + cl];
            float vv[4];
#pragma unroll
            for (int rr = 0; rr < 4; rr++) {
                int rl = i * 16 + quad * 4 + rr;
                float x = acc[i * 2 + j][rr];
                if (mode == 0) x = fmaxf(x + bv, 0.f);
                else           x = theta * x + omt * bf2f(tH[rl * 136 + cl]);
                vv[rr] = x;
            }
#pragma unroll
            for (int rr = 0; rr < 4; rr++)
                tR[(i * 16 + quad * 4 + rr) * 136 + cl] = f2bf(vv[rr]);
            if (oTp) {
                ushort4 w4;
                w4.x = f2bf(vv[0]); w4.y = f2bf(vv[1]);
                w4.z = f2bf(vv[2]); w4.w = f2bf(vv[3]);
                *(ushort4*)&tT[cl * 72 + i * 16 + quad * 4] = w4;
            }
        }
    __syncthreads();
    {
        unsigned short* dst = oR + (size_t)(mbase + r) * DD + nbase + c0;
#pragma unroll
        for (int u = 0; u < 4; u++)
            *(uint4*)(dst + u * 8) = *(const uint4*)&tR[r * 136 + c0 + u * 8];
    }
    if (oTp) {
        int c = t >> 1, r0 = (t & 1) * 32;
        unsigned short* dst = oTp + (size_t)(nbase + c) * M3 + mbase + r0;
#pragma unroll
        for (int u = 0; u < 4; u++)
            *(uint4*)(dst + u * 8) = *(const uint4*)&tT[c * 72 + r0 + u * 8];
    }
}

// ---------- adj step on G: h = relu(0.9*(Ad@G + cv1.Gn1 + cv2.Gn2) + 0.1*P0) ----------
__global__ __launch_bounds__(256) void k_adj(
    const float* __restrict__ blk, const float* __restrict__ cross,
    const float* __restrict__ dinv,
    const unsigned short* __restrict__ GT, const unsigned short* __restrict__ Gr,
    const unsigned short* __restrict__ P0,
    unsigned short* __restrict__ hout, float* __restrict__ outF, int final_mode)
{
    __shared__ __align__(16) unsigned short AdL[64 * 64];    //  8 KB swizzled pitch-64
    __shared__ __align__(16) unsigned short GTL[128 * 64];   // 16 KB swizzled pitch-64
    __shared__ __align__(16) unsigned short OT[64 * 136];    // 17 KB out tile (mode 0)
    __shared__ float dv[64];
    int ch = blockIdx.x, d = blockIdx.y, m = blockIdx.z;
    int t = threadIdx.x;
    int lane = t & 63, wv = t >> 6;
    int dbase = d * 64, cbase = ch * 128;
    int rsel = lane & 15, quad = lane >> 4;

    if (t < 64) dv[t] = dinv[m * NTOT + dbase + t];
    __syncthreads();

    size_t bbase = (size_t)(m * N_DIA + d) * 4096;
#pragma unroll
    for (int q = 0; q < 4; q++) {
        int e4 = t + 256 * q;
        int i = e4 >> 4, j4 = e4 & 15;
        float4 w = *(const float4*)(blk + bbase + (size_t)i * 64 + j4 * 4);
        float di = dv[i];
        ushort4 o;
        o.x = f2bf(w.x * di * dv[j4 * 4 + 0]);
        o.y = f2bf(w.y * di * dv[j4 * 4 + 1]);
        o.z = f2bf(w.z * di * dv[j4 * 4 + 2]);
        o.w = f2bf(w.w * di * dv[j4 * 4 + 3]);
        *(ushort4*)((char*)AdL + i * 128 + (((j4 >> 1) ^ (i & 7)) << 4) + ((j4 & 1) << 3)) = o;
    }
#pragma unroll
    for (int p = 0; p < 4; p++) {
        int e = t + 256 * p;
        int cl = e >> 3;
        int uo = e & 7;
        uint4 w = *(const uint4*)(GT + (size_t)(cbase + cl) * M3 + m * NTOT + dbase + uo * 8);
        *(uint4*)((char*)GTL + cl * 128 + ((uo ^ (cl & 7)) << 4)) = w;
    }
    __syncthreads();

    f32x4 acc[8];
#pragma unroll
    for (int i = 0; i < 8; i++) acc[i] = (f32x4){0.f, 0.f, 0.f, 0.f};
#pragma unroll
    for (int kk = 0; kk < 2; kk++) {
        int su = ((kk * 4 + quad) ^ (rsel & 7)) << 4;
        frag8 bfr[4];
#pragma unroll
        for (int it = 0; it < 4; it++)
            bfr[it] = *(const frag8*)((const char*)AdL + (it * 16 + rsel) * 128 + su);
#pragma unroll
        for (int jc = 0; jc < 2; jc++) {
            frag8 af = *(const frag8*)((const char*)GTL + (wv * 32 + jc * 16 + rsel) * 128 + su);
#pragma unroll
            for (int it = 0; it < 4; it++)
                acc[jc * 4 + it] = __builtin_amdgcn_mfma_f32_16x16x32_bf16(
                    af, bfr[it], acc[jc * 4 + it], 0, 0, 0);
        }
    }

    int n1, n2, p1, p2;
    if (m == 0)      { n1 = 1; n2 = 2; p1 = 0; p2 = 1; }
    else if (m == 1) { n1 = 0; n2 = 2; p1 = 0; p2 = 2; }
    else             { n1 = 0; n2 = 1; p1 = 1; p2 = 2; }
#pragma unroll
    for (int it = 0; it < 4; it++) {
        int il = it * 16 + rsel;
        int gi = dbase + il;
        float dm = dv[il];
        float cv1 = cross[p1 * NTOT + gi] * dm * dinv[n1 * NTOT + gi];
        float cv2 = cross[p2 * NTOT + gi] * dm * dinv[n2 * NTOT + gi];
        size_t r1 = (size_t)(n1 * NTOT + gi) * DD;
        size_t r2 = (size_t)(n2 * NTOT + gi) * DD;
        size_t r0 = (size_t)(m * NTOT + gi) * DD;
#pragma unroll
        for (int jc = 0; jc < 2; jc++) {
            int cl = wv * 32 + jc * 16 + quad * 4;
            int cg = cbase + cl;
            ushort4 u1 = *(const ushort4*)(Gr + r1 + cg);
            ushort4 u2 = *(const ushort4*)(Gr + r2 + cg);
            ushort4 u0 = *(const ushort4*)(P0 + r0 + cg);
            f32x4 aa = acc[jc * 4 + it];
            float o0 = fmaxf(0.9f * (aa[0] + cv1 * bf2f(u1.x) + cv2 * bf2f(u2.x)) + 0.1f * bf2f(u0.x), 0.f);
            float o1 = fmaxf(0.9f * (aa[1] + cv1 * bf2f(u1.y) + cv2 * bf2f(u2.y)) + 0.1f * bf2f(u0.y), 0.f);
            float o2 = fmaxf(0.9f * (aa[2] + cv1 * bf2f(u1.z) + cv2 * bf2f(u2.z)) + 0.1f * bf2f(u0.z), 0.f);
            float o3 = fmaxf(0.9f * (aa[3] + cv1 * bf2f(u1.w) + cv2 * bf2f(u2.w)) + 0.1f * bf2f(u0.w), 0.f);
            if (final_mode) {
                *(float4*)(outF + (size_t)gi * 3072 + m * 1024 + 512 + cg) =
                    make_float4(o0, o1, o2, o3);
            } else {
                ushort4 w;
                w.x = f2bf(o0); w.y = f2bf(o1); w.z = f2bf(o2); w.w = f2bf(o3);
                *(ushort4*)&OT[il * 136 + cl] = w;
            }
        }
    }
    if (!final_mode) {
        __syncthreads();
        int r = t >> 2, c0 = (t & 3) * 32;
        unsigned short* dst = hout + (size_t)(m * NTOT + dbase + r) * DD + cbase + c0;
#pragma unroll
        for (int u = 0; u < 4; u++)
            *(uint4*)(dst + u * 8) = *(const uint4*)&OT[r * 136 + c0 + u * 8];
    }
}

extern "C" void kernel_launch(void* const* d_in, const int* in_sizes, int n_in,
                              void* d_out, int out_size, void* d_ws, size_t ws_size,
                              hipStream_t stream) {
    (void)in_sizes; (void)n_in; (void)out_size; (void)ws_size;
    const float* a     = (const float*)d_in[0];
    const float* v     = (const float*)d_in[1];
    const float* l     = (const float*)d_in[2];
    const float* qmask = (const float*)d_in[3];
    const float* Wspk  = (const float*)d_in[5];
    const float* W0    = (const float*)d_in[6];
    const float* b0    = (const float*)d_in[7];
    const float* Wg    = (const float*)d_in[8];
    float* out = (float*)d_out;
    float* ws = (float*)d_ws;

    float* invn  = ws;                                  // M3 (slot retained, unused)
    float* blk   = invn + M3;                           // 3*48*4096
    float* cross = blk + (size_t)3 * N_DIA * 4096;      // M3
    float* dinvp = cross + M3;                          // M3
    unsigned short* Wt  = (unsigned short*)(dinvp + M3);   // 3*DD*DD
    unsigned short* xb  = Wt + (size_t)3 * DD * DD;        // 3*SEG
    unsigned short* P02 = xb  + 3 * SEG;                   // 3*SEG
    unsigned short* G1r = P02 + 3 * SEG;                   // 3*SEG
    unsigned short* G1T = G1r + 3 * SEG;                   // 3*SEG
    unsigned short* h1  = G1T + 3 * SEG;                   // 3*SEG
    // lifetime aliases (ws footprint identical to verified round-4 layout):
    unsigned short* G2r = xb;    // xb dead after k_fgemm
    unsigned short* G2T = G1T;   // G1T dead after adj1

    const float th1 = 0.40546510810816438f;  // log(1.5)
    const float th2 = 0.22314355131420976f;  // log(1.25)

    // K1: pre+gram (self-contained, dialogue-local) + W conversion
    k_pre_gram_wt<<<528, 512, 0, stream>>>(a, v, l, qmask, Wspk, W0, Wg,
                                           out, xb, cross, blk, dinvp, Wt);
    // K2: h0 (LDS-only) -> G1 rows+T, P02 rows
    k_fgemm<<<288, 512, 0, stream>>>(xb, Wt, b0, G1r, G1T, P02, th1, th2);
    // K3: h1 = relu(0.9*(Ad@G1 + cross terms) + 0.1*G1)
    k_adj<<<dim3(4, N_DIA, 3), 256, 0, stream>>>(blk, cross, dinvp, G1T, G1r, G1r,
                                                 h1, nullptr, 0);
    // K4: G2 = th2*(h1@W2) + (1-th2)*h1 (rows + T)
    k_gemm<<<dim3(4, 144), 256, 0, stream>>>(h1, Wt + (size_t)2 * DD * DD, nullptr, G2r, G2T,
                                             th2, 1, nullptr, nullptr);
    // K5: out_h = relu(0.9*(Ad@G2 + cross terms) + 0.1*P02) -> fp32 output
    k_adj<<<dim3(4, N_DIA, 3), 256, 0, stream>>>(blk, cross, dinvp, G2T, G2r, P02,
                                                 nullptr, out, 1);
}

// Round 6
// 208.459 us; speedup vs baseline: 1.1520x; 1.1520x over previous
//
#include <hip/hip_runtime.h>
#include <math.h>

#define N_DIA 48
#define NTOT  3072     // N utterances
#define DD    512      // D == H
#define M3    9216     // 3N
#define SEG   ((size_t)NTOT * DD)

#define SCALE_F 0.99999f
#define PI_F    3.14159274101257324f

typedef __attribute__((ext_vector_type(8))) short frag8;
typedef __attribute__((ext_vector_type(4))) float f32x4;

__device__ __forceinline__ float ang_sim(float cs) {
    float cc = cs * SCALE_F;
    cc = fminf(fmaxf(cc, -SCALE_F), SCALE_F);
    return 1.0f - acosf(cc) / PI_F;
}
__device__ __forceinline__ unsigned short f2bf(float x) {
    union { float f; unsigned int u; } c; c.f = x;
    unsigned int r = c.u + 0x7fffu + ((c.u >> 16) & 1u);
    return (unsigned short)(r >> 16);
}
__device__ __forceinline__ float bf2f(unsigned short h) {
    union { unsigned int u; float f; } c; c.u = ((unsigned int)h) << 16;
    return c.f;
}
__device__ __forceinline__ void gload16(const unsigned short* g, unsigned short* s) {
    __builtin_amdgcn_global_load_lds(
        (const __attribute__((address_space(1))) unsigned int*)g,
        (__attribute__((address_space(3))) unsigned int*)s, 16, 0, 0);
}
__device__ __forceinline__ float d8(float4 x0, float4 x1, float4 y0, float4 y1) {
    return x0.x*y0.x + x0.y*y0.y + x0.z*y0.z + x0.w*y0.w
         + x1.x*y1.x + x1.y*y1.y + x1.z*y1.z + x1.w*y1.w;
}

// ---------- K1: blocks [0,144): self-contained pre+gram per (dialogue, modality)
//            blocks [144,528): W -> bf16 [n][k], 2 tiles per block ----------
__global__ __launch_bounds__(512) void k_pre_gram_wt(
    const float* __restrict__ a, const float* __restrict__ v,
    const float* __restrict__ l, const float* __restrict__ qmask,
    const float* __restrict__ Wspk, const float* __restrict__ W0,
    const float* __restrict__ Wg,
    float* __restrict__ out, unsigned short* __restrict__ xb,
    float* __restrict__ cross, float* __restrict__ blk,
    float* __restrict__ dinv, unsigned short* __restrict__ Wt)
{
    __shared__ __align__(16) char smem[66816];
    int b = blockIdx.x;
    int t = threadIdx.x;

    if (b >= 144) {
        // ---- wt flavor: two 32x32 transpose tiles per block ----
        float (*tile)[32][33] = (float (*)[32][33])smem;
        int sub = t >> 8, tid = t & 255;
        int idx = (b - 144) * 2 + sub;
        int mm = idx >> 8, rem = idx & 255;
        int by = rem >> 4, bx = rem & 15;
        const float* W = (mm == 0) ? W0 : Wg + (size_t)(mm - 1) * DD * DD;
        int tx = tid & 31, ty = tid >> 5;
#pragma unroll
        for (int q = 0; q < 4; q++) {
            int k = by * 32 + ty + q * 8;
            tile[sub][ty + q * 8][tx] = W[(size_t)k * DD + bx * 32 + tx];
        }
        __syncthreads();
#pragma unroll
        for (int q = 0; q < 4; q++) {
            int n = bx * 32 + ty + q * 8;
            Wt[(size_t)mm * DD * DD + (size_t)n * DD + by * 32 + tx] = f2bf(tile[sub][tx][ty + q * 8]);
        }
        return;
    }

    // ---- gram flavor ----
    unsigned short* Xs = (unsigned short*)smem;          // 64 KB
    float* invnL = (float*)(smem + 65536);               // [64]
    float* c1L = invnL + 64;                             // [64]
    float* c2L = c1L + 64;                               // [64]
    int d = b % N_DIA, m = b / N_DIA;
    int lane = t & 63, wv = t >> 6;                      // 8 waves
    int dbase = d * 64;

    // streaming: 8 utterances per wave; lane covers cols lane*8..lane*8+7
    for (int u = 0; u < 8; u++) {
        int r = u * 8 + wv;
        int i = dbase + r;
        int qb = (r * N_DIA + d) * 2;
        float q0 = qmask[qb], q1 = qmask[qb + 1];
        int spk = (q0 >= q1) ? 0 : 1;
        const float4* ap = (const float4*)(a + (size_t)i * DD) + lane * 2;
        const float4* vp = (const float4*)(v + (size_t)i * DD) + lane * 2;
        const float4* lp = (const float4*)(l + (size_t)i * DD) + lane * 2;
        const float4* wp = (const float4*)(Wspk + (size_t)spk * DD) + lane * 2;
        float4 a0 = ap[0], a1 = ap[1];
        float4 v0 = vp[0], v1 = vp[1];
        float4 l0 = lp[0], l1 = lp[1];
        float4 w0 = wp[0], w1 = wp[1];
        float4 L0 = make_float4(l0.x + w0.x, l0.y + w0.y, l0.z + w0.z, l0.w + w0.w);
        float4 L1 = make_float4(l1.x + w1.x, l1.y + w1.y, l1.z + w1.z, l1.w + w1.w);
        // out x-columns for own modality only
        float* ob = out + (size_t)i * 3072 + m * 1024 + lane * 8;
        if (m == 0)      { *(float4*)ob = a0; *(float4*)(ob + 4) = a1; }
        else if (m == 1) { *(float4*)ob = v0; *(float4*)(ob + 4) = v1; }
        else             { *(float4*)ob = L0; *(float4*)(ob + 4) = L1; }
        // own-modality bf16 -> xb global + Xs LDS (gram layout, unit-swizzled)
        float4 m0, m1;
        if (m == 0) { m0 = a0; m1 = a1; } else if (m == 1) { m0 = v0; m1 = v1; }
        else { m0 = L0; m1 = L1; }
        ushort4 y0, y1;
        y0.x = f2bf(m0.x); y0.y = f2bf(m0.y); y0.z = f2bf(m0.z); y0.w = f2bf(m0.w);
        y1.x = f2bf(m1.x); y1.y = f2bf(m1.y); y1.z = f2bf(m1.z); y1.w = f2bf(m1.w);
        unsigned short* xg = xb + (size_t)m * SEG + (size_t)i * DD + lane * 8;
        *(ushort4*)xg = y0; *(ushort4*)(xg + 4) = y1;
        unsigned short* xd = &Xs[(lane >> 2) * 2048 + r * 32 + (((lane & 3) ^ (r & 3)) << 3)];
        *(ushort4*)xd = y0; *(ushort4*)(xd + 4) = y1;
        // fp32 dots
        float saa = d8(a0, a1, a0, a1), svv = d8(v0, v1, v0, v1), sll = d8(L0, L1, L0, L1);
        float sav = d8(a0, a1, v0, v1), sal = d8(a0, a1, L0, L1), svl = d8(v0, v1, L0, L1);
#pragma unroll
        for (int off = 32; off; off >>= 1) {
            saa += __shfl_down(saa, off, 64);
            svv += __shfl_down(svv, off, 64);
            sll += __shfl_down(sll, off, 64);
            sav += __shfl_down(sav, off, 64);
            sal += __shfl_down(sal, off, 64);
            svl += __shfl_down(svl, off, 64);
        }
        if (lane == 0) {
            float ina = 1.0f / sqrtf(saa);
            float inv_ = 1.0f / sqrtf(svv);
            float inl = 1.0f / sqrtf(sll);
            float s_av = ang_sim(sav * ina * inv_);
            float s_al = ang_sim(sal * ina * inl);
            float s_vl = ang_sim(svl * inv_ * inl);
            if (m == 0) { cross[i] = s_av; cross[NTOT + i] = s_al; cross[2 * NTOT + i] = s_vl; }
            invnL[r] = (m == 0) ? ina : ((m == 1) ? inv_ : inl);
            c1L[r] = (m == 2) ? s_al : s_av;
            c2L[r] = (m == 0) ? s_al : s_vl;
        }
    }
    __syncthreads();

    if (wv < 4) {
        int rsel = lane & 15, quad = lane >> 4;
        int sq = (quad ^ (rsel & 3)) * 8;
        f32x4 acc[4];
#pragma unroll
        for (int j = 0; j < 4; j++) acc[j] = (f32x4){0.f, 0.f, 0.f, 0.f};
#pragma unroll
        for (int c = 0; c < 16; c++) {
            const unsigned short* base = &Xs[c * 2048];
            frag8 bf[4];
#pragma unroll
            for (int j = 0; j < 4; j++)
                bf[j] = *(const frag8*)&base[(j * 16 + rsel) * 32 + sq];
            frag8 af = *(const frag8*)&base[(wv * 16 + rsel) * 32 + sq];
#pragma unroll
            for (int j = 0; j < 4; j++)
                acc[j] = __builtin_amdgcn_mfma_f32_16x16x32_bf16(af, bf[j], acc[j], 0, 0, 0);
        }
        size_t bbase = (size_t)(m * N_DIA + d) * 4096;
        int rowl0 = wv * 16 + quad * 4;
        float ir[4], rs[4] = {0.f, 0.f, 0.f, 0.f};
#pragma unroll
        for (int r = 0; r < 4; r++) ir[r] = invnL[rowl0 + r];
#pragma unroll
        for (int j = 0; j < 4; j++) {
            int coll = j * 16 + rsel;
            float ic = invnL[coll];
#pragma unroll
            for (int r = 0; r < 4; r++) {
                float sim = ang_sim(acc[j][r] * ir[r] * ic);
                blk[bbase + (size_t)(rowl0 + r) * 64 + coll] = sim;
                rs[r] += sim;
            }
        }
#pragma unroll
        for (int off = 8; off; off >>= 1)
#pragma unroll
            for (int r = 0; r < 4; r++) rs[r] += __shfl_down(rs[r], off, 16);
        if (rsel == 0) {
#pragma unroll
            for (int r = 0; r < 4; r++) {
                int rl = rowl0 + r;
                dinv[m * NTOT + dbase + rl] = 1.0f / sqrtf(rs[r] + c1L[rl] + c2L[rl]);
            }
        }
    }
}

// ---------- GEMM: 64(M) x 128(N) tile, dbuf LDS, swizzled, coalesced LDS epilogue ----------
// mode 0: relu(acc + bias[col])                 -> rows only
// mode 1: theta*acc + (1-theta)*A[row][col]     -> rows (+ optional transposed GT)
// second half (by>=144): A2/oRows2/Wb/thetab, rows only
__global__ __launch_bounds__(256) void k_gemm(
    const unsigned short* __restrict__ A, const unsigned short* __restrict__ W,
    const float* __restrict__ bias,
    unsigned short* __restrict__ oRows, unsigned short* __restrict__ oT,
    float theta, int mode,
    const unsigned short* __restrict__ A2, unsigned short* __restrict__ oRows2,
    const unsigned short* __restrict__ Wb, float thetab)
{
    __shared__ __align__(16) char smem[53248];
    unsigned short* const As0 = (unsigned short*)smem;            // 4 KB
    unsigned short* const As1 = (unsigned short*)(smem + 4096);
    unsigned short* const Bs0 = (unsigned short*)(smem + 8192);   // 8 KB
    unsigned short* const Bs1 = (unsigned short*)(smem + 16384);
    unsigned short* const tH  = (unsigned short*)smem;            // [64][136]
    unsigned short* const tR  = (unsigned short*)(smem + 17408);  // [64][136]
    unsigned short* const tT  = (unsigned short*)(smem + 34816);  // [128][72]

    int t = threadIdx.x, lane = t & 63, wv = t >> 6;
    int bx = blockIdx.x, by = blockIdx.y;
    const unsigned short* Ap = A;
    const unsigned short* Wp = W;
    float th = theta;
    unsigned short* oR = oRows;
    unsigned short* oTp = oT;
    if (by >= 144) { Ap = A2; oR = oRows2; oTp = nullptr; Wp = Wb; th = thetab; by -= 144; }
    int mbase = by * 64, nbase = bx * 128;
    int srow = lane >> 2;
    int scol = (((lane & 3) ^ (srow & 3)) * 8);
    int rsel = lane & 15, quad = lane >> 4;
    int sq = (quad ^ (rsel & 3)) * 8;

    const unsigned short* Ag  = Ap + (size_t)(mbase + wv * 16 + srow) * DD + scol;
    const unsigned short* Bg0 = Wp + (size_t)(nbase + wv * 32 + srow) * DD + scol;
    const unsigned short* Bg1 = Wp + (size_t)(nbase + wv * 32 + 16 + srow) * DD + scol;

    f32x4 acc[8];
#pragma unroll
    for (int i = 0; i < 8; i++) acc[i] = (f32x4){0.f, 0.f, 0.f, 0.f};

    gload16(Ag,  As0 + wv * 512);
    gload16(Bg0, Bs0 + wv * 1024);
    gload16(Bg1, Bs0 + wv * 1024 + 512);

#pragma unroll
    for (int kt = 0; kt < 16; kt++) {
        __syncthreads();
        const unsigned short* Ac = (kt & 1) ? As1 : As0;
        const unsigned short* Bc = (kt & 1) ? Bs1 : Bs0;
        if (kt < 15) {
            unsigned short* An = (kt & 1) ? As0 : As1;
            unsigned short* Bn = (kt & 1) ? Bs0 : Bs1;
            gload16(Ag + (kt + 1) * 32,  An + wv * 512);
            gload16(Bg0 + (kt + 1) * 32, Bn + wv * 1024);
            gload16(Bg1 + (kt + 1) * 32, Bn + wv * 1024 + 512);
        }
        frag8 af[4], bfr[2];
#pragma unroll
        for (int i = 0; i < 4; i++)
            af[i] = *(const frag8*)&Ac[(i * 16 + rsel) * 32 + sq];
#pragma unroll
        for (int j = 0; j < 2; j++)
            bfr[j] = *(const frag8*)&Bc[(wv * 32 + j * 16 + rsel) * 32 + sq];
#pragma unroll
        for (int i = 0; i < 4; i++)
#pragma unroll
            for (int j = 0; j < 2; j++)
                acc[i * 2 + j] = __builtin_amdgcn_mfma_f32_16x16x32_bf16(
                    af[i], bfr[j], acc[i * 2 + j], 0, 0, 0);
    }
    __syncthreads();

    int r = t >> 2, c0 = (t & 3) * 32;
    if (mode == 1) {
        const unsigned short* srcA = Ap + (size_t)(mbase + r) * DD + nbase + c0;
#pragma unroll
        for (int u = 0; u < 4; u++)
            *(uint4*)&tH[r * 136 + c0 + u * 8] = *(const uint4*)(srcA + u * 8);
        __syncthreads();
    }
    float omt = 1.0f - th;
#pragma unroll
    for (int i = 0; i < 4; i++)
#pragma unroll
        for (int j = 0; j < 2; j++) {
            int cl = wv * 32 + j * 16 + rsel;
            float bv = 0.f;
            if (mode == 0) bv = bias[nbase + cl];
            float vv[4];
#pragma unroll
            for (int rr = 0; rr < 4; rr++) {
                int rl = i * 16 + quad * 4 + rr;
                float x = acc[i * 2 + j][rr];
                if (mode == 0) x = fmaxf(x + bv, 0.f);
                else           x = th * x + omt * bf2f(tH[rl * 136 + cl]);
                vv[rr] = x;
            }
#pragma unroll
            for (int rr = 0; rr < 4; rr++)
                tR[(i * 16 + quad * 4 + rr) * 136 + cl] = f2bf(vv[rr]);
            if (oTp) {
                ushort4 w4;
                w4.x = f2bf(vv[0]); w4.y = f2bf(vv[1]);
                w4.z = f2bf(vv[2]); w4.w = f2bf(vv[3]);
                *(ushort4*)&tT[cl * 72 + i * 16 + quad * 4] = w4;
            }
        }
    __syncthreads();
    {
        unsigned short* dst = oR + (size_t)(mbase + r) * DD + nbase + c0;
#pragma unroll
        for (int u = 0; u < 4; u++)
            *(uint4*)(dst + u * 8) = *(const uint4*)&tR[r * 136 + c0 + u * 8];
    }
    if (oTp) {
        int c = t >> 1, r0 = (t & 1) * 32;
        unsigned short* dst = oTp + (size_t)(nbase + c) * M3 + mbase + r0;
#pragma unroll
        for (int u = 0; u < 4; u++)
            *(uint4*)(dst + u * 8) = *(const uint4*)&tT[c * 72 + r0 + u * 8];
    }
}

// ---------- adj step on G: h = relu(0.9*(Ad@G + cv1.Gn1 + cv2.Gn2) + 0.1*P0) ----------
// 128-col chunks: grid (4, N_DIA, 3) = 576 blocks, ~42 KB LDS -> 3 blocks/CU
__global__ __launch_bounds__(256) void k_adj(
    const float* __restrict__ blk, const float* __restrict__ cross,
    const float* __restrict__ dinv,
    const unsigned short* __restrict__ GT, const unsigned short* __restrict__ Gr,
    const unsigned short* __restrict__ P0,
    unsigned short* __restrict__ hout, float* __restrict__ outF, int final_mode)
{
    __shared__ __align__(16) unsigned short AdL[64 * 64];    //  8 KB swizzled pitch-64
    __shared__ __align__(16) unsigned short GTL[128 * 64];   // 16 KB swizzled pitch-64
    __shared__ __align__(16) unsigned short OT[64 * 136];    // 17 KB out tile (mode 0)
    __shared__ float dv[64];
    int ch = blockIdx.x, d = blockIdx.y, m = blockIdx.z;
    int t = threadIdx.x;
    int lane = t & 63, wv = t >> 6;
    int dbase = d * 64, cbase = ch * 128;
    int rsel = lane & 15, quad = lane >> 4;

    if (t < 64) dv[t] = dinv[m * NTOT + dbase + t];
    __syncthreads();

    size_t bbase = (size_t)(m * N_DIA + d) * 4096;
#pragma unroll
    for (int q = 0; q < 4; q++) {
        int e4 = t + 256 * q;
        int i = e4 >> 4, j4 = e4 & 15;
        float4 w = *(const float4*)(blk + bbase + (size_t)i * 64 + j4 * 4);
        float di = dv[i];
        ushort4 o;
        o.x = f2bf(w.x * di * dv[j4 * 4 + 0]);
        o.y = f2bf(w.y * di * dv[j4 * 4 + 1]);
        o.z = f2bf(w.z * di * dv[j4 * 4 + 2]);
        o.w = f2bf(w.w * di * dv[j4 * 4 + 3]);
        *(ushort4*)((char*)AdL + i * 128 + (((j4 >> 1) ^ (i & 7)) << 4) + ((j4 & 1) << 3)) = o;
    }
#pragma unroll
    for (int p = 0; p < 4; p++) {
        int e = t + 256 * p;
        int cl = e >> 3;
        int uo = e & 7;
        uint4 w = *(const uint4*)(GT + (size_t)(cbase + cl) * M3 + m * NTOT + dbase + uo * 8);
        *(uint4*)((char*)GTL + cl * 128 + ((uo ^ (cl & 7)) << 4)) = w;
    }
    __syncthreads();

    f32x4 acc[8];
#pragma unroll
    for (int i = 0; i < 8; i++) acc[i] = (f32x4){0.f, 0.f, 0.f, 0.f};
#pragma unroll
    for (int kk = 0; kk < 2; kk++) {
        int su = ((kk * 4 + quad) ^ (rsel & 7)) << 4;
        frag8 bfr[4];
#pragma unroll
        for (int it = 0; it < 4; it++)
            bfr[it] = *(const frag8*)((const char*)AdL + (it * 16 + rsel) * 128 + su);
#pragma unroll
        for (int jc = 0; jc < 2; jc++) {
            frag8 af = *(const frag8*)((const char*)GTL + (wv * 32 + jc * 16 + rsel) * 128 + su);
#pragma unroll
            for (int it = 0; it < 4; it++)
                acc[jc * 4 + it] = __builtin_amdgcn_mfma_f32_16x16x32_bf16(
                    af, bfr[it], acc[jc * 4 + it], 0, 0, 0);
        }
    }

    int n1, n2, p1, p2;
    if (m == 0)      { n1 = 1; n2 = 2; p1 = 0; p2 = 1; }
    else if (m == 1) { n1 = 0; n2 = 2; p1 = 0; p2 = 2; }
    else             { n1 = 0; n2 = 1; p1 = 1; p2 = 2; }
#pragma unroll
    for (int it = 0; it < 4; it++) {
        int il = it * 16 + rsel;
        int gi = dbase + il;
        float dm = dv[il];
        float cv1 = cross[p1 * NTOT + gi] * dm * dinv[n1 * NTOT + gi];
        float cv2 = cross[p2 * NTOT + gi] * dm * dinv[n2 * NTOT + gi];
        size_t r1 = (size_t)(n1 * NTOT + gi) * DD;
        size_t r2 = (size_t)(n2 * NTOT + gi) * DD;
        size_t r0 = (size_t)(m * NTOT + gi) * DD;
#pragma unroll
        for (int jc = 0; jc < 2; jc++) {
            int cl = wv * 32 + jc * 16 + quad * 4;
            int cg = cbase + cl;
            ushort4 u1 = *(const ushort4*)(Gr + r1 + cg);
            ushort4 u2 = *(const ushort4*)(Gr + r2 + cg);
            ushort4 u0 = *(const ushort4*)(P0 + r0 + cg);
            f32x4 aa = acc[jc * 4 + it];
            float o0 = fmaxf(0.9f * (aa[0] + cv1 * bf2f(u1.x) + cv2 * bf2f(u2.x)) + 0.1f * bf2f(u0.x), 0.f);
            float o1 = fmaxf(0.9f * (aa[1] + cv1 * bf2f(u1.y) + cv2 * bf2f(u2.y)) + 0.1f * bf2f(u0.y), 0.f);
            float o2 = fmaxf(0.9f * (aa[2] + cv1 * bf2f(u1.z) + cv2 * bf2f(u2.z)) + 0.1f * bf2f(u0.z), 0.f);
            float o3 = fmaxf(0.9f * (aa[3] + cv1 * bf2f(u1.w) + cv2 * bf2f(u2.w)) + 0.1f * bf2f(u0.w), 0.f);
            if (final_mode) {
                *(float4*)(outF + (size_t)gi * 3072 + m * 1024 + 512 + cg) =
                    make_float4(o0, o1, o2, o3);
            } else {
                ushort4 w;
                w.x = f2bf(o0); w.y = f2bf(o1); w.z = f2bf(o2); w.w = f2bf(o3);
                *(ushort4*)&OT[il * 136 + cl] = w;
            }
        }
    }
    if (!final_mode) {
        __syncthreads();
        int r = t >> 2, c0 = (t & 3) * 32;
        unsigned short* dst = hout + (size_t)(m * NTOT + dbase + r) * DD + cbase + c0;
#pragma unroll
        for (int u = 0; u < 4; u++)
            *(uint4*)(dst + u * 8) = *(const uint4*)&OT[r * 136 + c0 + u * 8];
    }
}

extern "C" void kernel_launch(void* const* d_in, const int* in_sizes, int n_in,
                              void* d_out, int out_size, void* d_ws, size_t ws_size,
                              hipStream_t stream) {
    (void)in_sizes; (void)n_in; (void)out_size; (void)ws_size;
    const float* a     = (const float*)d_in[0];
    const float* v     = (const float*)d_in[1];
    const float* l     = (const float*)d_in[2];
    const float* qmask = (const float*)d_in[3];
    const float* Wspk  = (const float*)d_in[5];
    const float* W0    = (const float*)d_in[6];
    const float* b0    = (const float*)d_in[7];
    const float* Wg    = (const float*)d_in[8];
    float* out = (float*)d_out;
    float* ws = (float*)d_ws;

    float* invn  = ws;                                  // M3 (slot retained, unused)
    float* blk   = invn + M3;                           // 3*48*4096
    float* cross = blk + (size_t)3 * N_DIA * 4096;      // M3
    float* dinvp = cross + M3;                          // M3
    unsigned short* Wt  = (unsigned short*)(dinvp + M3);   // 3*DD*DD
    unsigned short* xb  = Wt + (size_t)3 * DD * DD;        // 3*SEG
    unsigned short* h0  = xb  + 3 * SEG;                   // 3*SEG
    unsigned short* G1r = h0  + 3 * SEG;                   // 3*SEG
    unsigned short* G1T = G1r + 3 * SEG;                   // 3*SEG
    unsigned short* h1  = G1T + 3 * SEG;                   // 3*SEG
    // lifetime aliases (ws footprint identical to verified rounds 2/4):
    unsigned short* P02 = xb;    // xb dead after K2 (h0 gemm)
    unsigned short* G2r = G1r;   // G1r dead after adj1
    unsigned short* G2T = G1T;   // G1T dead after adj1

    const float th1 = 0.40546510810816438f;  // log(1.5)
    const float th2 = 0.22314355131420976f;  // log(1.25)
    const unsigned short* Wt1 = Wt + (size_t)DD * DD;
    const unsigned short* Wt2 = Wt + (size_t)2 * DD * DD;

    // K1: pre + gram (self-contained, dialogue-local) + W conversion
    k_pre_gram_wt<<<528, 512, 0, stream>>>(a, v, l, qmask, Wspk, W0, Wg,
                                           out, xb, cross, blk, dinvp, Wt);
    // K2: h0 = relu(x @ W0 + b0)  (rows only)
    k_gemm<<<dim3(4, 144), 256, 0, stream>>>(xb, Wt, b0, h0, nullptr, 0.f, 0,
                                             nullptr, nullptr, nullptr, 0.f);
    // K3 (batched): y<144: G1 = th1*(h0@W1)+(1-th1)*h0 (rows+T)
    //               y>=144: P02 = th2*(h0@W2)+(1-th2)*h0 (rows)
    k_gemm<<<dim3(4, 288), 256, 0, stream>>>(h0, Wt1, nullptr, G1r, G1T, th1, 1,
                                             h0, P02, Wt2, th2);
    // K4: h1 = relu(0.9*(Ad@G1 + cross terms) + 0.1*G1)
    k_adj<<<dim3(4, N_DIA, 3), 256, 0, stream>>>(blk, cross, dinvp, G1T, G1r, G1r,
                                                 h1, nullptr, 0);
    // K5: G2 = th2*(h1@W2) + (1-th2)*h1 (rows + T)
    k_gemm<<<dim3(4, 144), 256, 0, stream>>>(h1, Wt2, nullptr, G2r, G2T, th2, 1,
                                             nullptr, nullptr, nullptr, 0.f);
    // K6: out_h = relu(0.9*(Ad@G2 + cross terms) + 0.1*P02) -> fp32 output
    k_adj<<<dim3(4, N_DIA, 3), 256, 0, stream>>>(blk, cross, dinvp, G2T, G2r, P02,
                                                 nullptr, out, 1);
}

// Round 7
// 195.127 us; speedup vs baseline: 1.2307x; 1.0683x over previous
//
#include <hip/hip_runtime.h>
#include <math.h>

#define N_DIA 48
#define NTOT  3072     // N utterances
#define DD    512      // D == H
#define M3    9216     // 3N
#define SEG   ((size_t)NTOT * DD)

#define SCALE_F 0.99999f
#define PI_F    3.14159274101257324f

typedef __attribute__((ext_vector_type(8))) short frag8;
typedef __attribute__((ext_vector_type(4))) float f32x4;

__device__ __forceinline__ float ang_sim(float cs) {
    float cc = cs * SCALE_F;
    cc = fminf(fmaxf(cc, -SCALE_F), SCALE_F);
    return 1.0f - acosf(cc) / PI_F;
}
__device__ __forceinline__ unsigned short f2bf(float x) {
    union { float f; unsigned int u; } c; c.f = x;
    unsigned int r = c.u + 0x7fffu + ((c.u >> 16) & 1u);
    return (unsigned short)(r >> 16);
}
__device__ __forceinline__ float bf2f(unsigned short h) {
    union { unsigned int u; float f; } c; c.u = ((unsigned int)h) << 16;
    return c.f;
}
__device__ __forceinline__ void gload16(const unsigned short* g, unsigned short* s) {
    __builtin_amdgcn_global_load_lds(
        (const __attribute__((address_space(1))) unsigned int*)g,
        (__attribute__((address_space(3))) unsigned int*)s, 16, 0, 0);
}

// ---------- K_pre_wt: (blocks 0..767) per-utterance pre; (768..1535) W -> bf16 [n][k] ----------
__global__ __launch_bounds__(256) void k_pre_wt(
    const float* __restrict__ a, const float* __restrict__ v,
    const float* __restrict__ l, const float* __restrict__ qmask,
    const float* __restrict__ Wspk, const float* __restrict__ W0,
    const float* __restrict__ Wg,
    float* __restrict__ out, unsigned short* __restrict__ xb,
    float* __restrict__ invn, float* __restrict__ cross,
    unsigned short* __restrict__ Wt)
{
    __shared__ float tile[32][33];
    int b = blockIdx.x;
    if (b < 768) {
        int wv = threadIdx.x >> 6, t = threadIdx.x & 63;
        int i = b * 4 + wv;                 // utterance, one wave each
        int pos = i & 63, dia = i >> 6;
        int qb = (pos * N_DIA + dia) * 2;
        float q0 = qmask[qb], q1 = qmask[qb + 1];
        int spk = (q0 >= q1) ? 0 : 1;
        const float4* av4 = (const float4*)(a + (size_t)i * DD);
        const float4* vv4 = (const float4*)(v + (size_t)i * DD);
        const float4* lv4 = (const float4*)(l + (size_t)i * DD);
        const float4* wv4 = (const float4*)(Wspk + (size_t)spk * DD);
        float* ob = out + (size_t)i * 3072;
        float saa = 0, svv = 0, sll = 0, sav = 0, sal = 0, svl = 0;
#pragma unroll
        for (int e = 0; e < 2; e++) {
            int idx = e * 64 + t;           // fully coalesced: lane-major
            float4 xa = av4[idx], xv = vv4[idx], xd = lv4[idx], xw = wv4[idx];
            float4 xL = make_float4(xd.x + xw.x, xd.y + xw.y, xd.z + xw.z, xd.w + xw.w);
            *(float4*)(ob + idx * 4)        = xa;
            *(float4*)(ob + 1024 + idx * 4) = xv;
            *(float4*)(ob + 2048 + idx * 4) = xL;
            ushort4 ya, yv, yl;
            ya.x = f2bf(xa.x); ya.y = f2bf(xa.y); ya.z = f2bf(xa.z); ya.w = f2bf(xa.w);
            yv.x = f2bf(xv.x); yv.y = f2bf(xv.y); yv.z = f2bf(xv.z); yv.w = f2bf(xv.w);
            yl.x = f2bf(xL.x); yl.y = f2bf(xL.y); yl.z = f2bf(xL.z); yl.w = f2bf(xL.w);
            *(ushort4*)(xb + (size_t)i * DD + idx * 4) = ya;
            *(ushort4*)(xb + SEG + (size_t)i * DD + idx * 4) = yv;
            *(ushort4*)(xb + 2 * SEG + (size_t)i * DD + idx * 4) = yl;
            saa += xa.x * xa.x + xa.y * xa.y + xa.z * xa.z + xa.w * xa.w;
            svv += xv.x * xv.x + xv.y * xv.y + xv.z * xv.z + xv.w * xv.w;
            sll += xL.x * xL.x + xL.y * xL.y + xL.z * xL.z + xL.w * xL.w;
            sav += xa.x * xv.x + xa.y * xv.y + xa.z * xv.z + xa.w * xv.w;
            sal += xa.x * xL.x + xa.y * xL.y + xa.z * xL.z + xa.w * xL.w;
            svl += xv.x * xL.x + xv.y * xL.y + xv.z * xL.z + xv.w * xL.w;
        }
#pragma unroll
        for (int off = 32; off; off >>= 1) {
            saa += __shfl_down(saa, off, 64);
            svv += __shfl_down(svv, off, 64);
            sll += __shfl_down(sll, off, 64);
            sav += __shfl_down(sav, off, 64);
            sal += __shfl_down(sal, off, 64);
            svl += __shfl_down(svl, off, 64);
        }
        if (t == 0) {
            float ina = 1.0f / sqrtf(saa);
            float inv_ = 1.0f / sqrtf(svv);
            float inl = 1.0f / sqrtf(sll);
            invn[i] = ina; invn[NTOT + i] = inv_; invn[2 * NTOT + i] = inl;
            cross[i]            = ang_sim(sav * ina * inv_);
            cross[NTOT + i]     = ang_sim(sal * ina * inl);
            cross[2 * NTOT + i] = ang_sim(svl * inv_ * inl);
        }
    } else {
        int idx = b - 768;
        int mm = idx >> 8;
        int by = (idx >> 4) & 15, bx = idx & 15;
        const float* W = (mm == 0) ? W0 : Wg + (size_t)(mm - 1) * DD * DD;
        int t = threadIdx.x, tx = t & 31, ty = t >> 5;
#pragma unroll
        for (int q = 0; q < 4; q++) {
            int k = by * 32 + ty + q * 8;
            tile[ty + q * 8][tx] = W[(size_t)k * DD + bx * 32 + tx];
        }
        __syncthreads();
#pragma unroll
        for (int q = 0; q < 4; q++) {
            int n = bx * 32 + ty + q * 8;
            Wt[(size_t)mm * DD * DD + (size_t)n * DD + by * 32 + tx] = f2bf(tile[tx][ty + q * 8]);
        }
    }
}

// ---------- gram (MFMA, swizzled LDS) + fused dinv ----------
__global__ __launch_bounds__(256) void k_gram_mfma(
    const unsigned short* __restrict__ xb, const float* __restrict__ invn,
    const float* __restrict__ cross, float* __restrict__ blk,
    float* __restrict__ dinv)
{
    __shared__ __align__(16) unsigned short Xs[16 * 2048];   // 64 KB
    int d = blockIdx.x, m = blockIdx.y;
    int t = threadIdx.x;
    int lane = t & 63, wv = t >> 6;
    int mrow = m * NTOT + d * 64;
    const unsigned short* src = xb + (size_t)mrow * DD;
    int sunit = ((t & 3) ^ ((t >> 2) & 3)) * 8;              // source pre-swizzle
#pragma unroll
    for (int c = 0; c < 16; c++) {
        gload16(src + (size_t)(t >> 2) * DD + c * 32 + sunit,
                &Xs[c * 2048 + wv * 512]);
    }
    __syncthreads();

    int rsel = lane & 15, quad = lane >> 4;
    int sq = (quad ^ (rsel & 3)) * 8;                        // swizzled read unit
    f32x4 acc[4];
#pragma unroll
    for (int j = 0; j < 4; j++) acc[j] = (f32x4){0.f, 0.f, 0.f, 0.f};
#pragma unroll
    for (int c = 0; c < 16; c++) {
        const unsigned short* base = &Xs[c * 2048];
        frag8 bf[4];
#pragma unroll
        for (int j = 0; j < 4; j++)
            bf[j] = *(const frag8*)&base[(j * 16 + rsel) * 32 + sq];
        frag8 af = *(const frag8*)&base[(wv * 16 + rsel) * 32 + sq];
#pragma unroll
        for (int j = 0; j < 4; j++)
            acc[j] = __builtin_amdgcn_mfma_f32_16x16x32_bf16(af, bf[j], acc[j], 0, 0, 0);
    }

    size_t bbase = (size_t)(m * N_DIA + d) * 4096;
    int rowl0 = wv * 16 + quad * 4;
    float ir[4], rs[4] = {0.f, 0.f, 0.f, 0.f};
#pragma unroll
    for (int r = 0; r < 4; r++) ir[r] = invn[mrow + rowl0 + r];
#pragma unroll
    for (int j = 0; j < 4; j++) {
        int coll = j * 16 + rsel;
        float ic = invn[mrow + coll];
#pragma unroll
        for (int r = 0; r < 4; r++) {
            float sim = ang_sim(acc[j][r] * ir[r] * ic);
            blk[bbase + (size_t)(rowl0 + r) * 64 + coll] = sim;
            rs[r] += sim;
        }
    }
#pragma unroll
    for (int off = 8; off; off >>= 1)
#pragma unroll
        for (int r = 0; r < 4; r++) rs[r] += __shfl_down(rs[r], off, 16);
    if (rsel == 0) {
#pragma unroll
        for (int r = 0; r < 4; r++) {
            int gi = d * 64 + rowl0 + r;
            float c1, c2;
            if (m == 0)      { c1 = cross[gi];        c2 = cross[NTOT + gi]; }
            else if (m == 1) { c1 = cross[gi];        c2 = cross[2 * NTOT + gi]; }
            else             { c1 = cross[NTOT + gi]; c2 = cross[2 * NTOT + gi]; }
            dinv[m * NTOT + gi] = 1.0f / sqrtf(rs[r] + c1 + c2);
        }
    }
}

// ---------- GEMM: 64(M) x 128(N) tile, BK=64 dbuf LDS (8 barriers), swizzled ----------
// mode 0: relu(acc + bias[col])                 -> rows only
// mode 1: theta*acc + (1-theta)*A[row][col]     -> rows (+ optional transposed GT)
// by>=144: second batch A2 -> oRows2 (rows only), same W/theta
__global__ __launch_bounds__(256) void k_gemm(
    const unsigned short* __restrict__ A, const unsigned short* __restrict__ W,
    const float* __restrict__ bias,
    unsigned short* __restrict__ oRows, unsigned short* __restrict__ oT,
    float theta, int mode,
    const unsigned short* __restrict__ A2, unsigned short* __restrict__ oRows2)
{
    __shared__ __align__(16) char smem[53248];
    unsigned short* const As0 = (unsigned short*)smem;            // [64][64]  8 KB
    unsigned short* const As1 = (unsigned short*)(smem + 8192);
    unsigned short* const Bs0 = (unsigned short*)(smem + 16384);  // [128][64] 16 KB
    unsigned short* const Bs1 = (unsigned short*)(smem + 32768);  // ends 49152
    unsigned short* const tH  = (unsigned short*)smem;            // [64][136] (epilogue overlay)
    unsigned short* const tR  = (unsigned short*)(smem + 17408);  // [64][136]
    unsigned short* const tT  = (unsigned short*)(smem + 34816);  // [128][72]

    int t = threadIdx.x, lane = t & 63, wv = t >> 6;
    int bx = blockIdx.x, by = blockIdx.y;
    const unsigned short* Ap = A;
    unsigned short* oR = oRows;
    unsigned short* oTp = oT;
    if (by >= 144) { Ap = A2; oR = oRows2; oTp = nullptr; by -= 144; }
    int mbase = by * 64, nbase = bx * 128;
    int rsel = lane & 15, quad = lane >> 4;
    int r8 = lane >> 3, u8 = lane & 7;
    int su8 = (u8 ^ r8) << 3;                  // source pre-swizzle (elements)

    const unsigned short* Ag = Ap + (size_t)(mbase + wv * 8 + r8) * DD + su8;
    const unsigned short* Bg = W  + (size_t)(nbase + wv * 8 + r8) * DD + su8;

    f32x4 acc[8];
#pragma unroll
    for (int i = 0; i < 8; i++) acc[i] = (f32x4){0.f, 0.f, 0.f, 0.f};

#define STAGE64(kt, Asb, Bsb) do { \
    gload16(Ag + (kt) * 64,                    (Asb) + (wv * 8) * 64); \
    gload16(Ag + (size_t)32 * DD + (kt) * 64,  (Asb) + (32 + wv * 8) * 64); \
    gload16(Bg + (kt) * 64,                    (Bsb) + (wv * 8) * 64); \
    gload16(Bg + (size_t)32 * DD + (kt) * 64,  (Bsb) + (32 + wv * 8) * 64); \
    gload16(Bg + (size_t)64 * DD + (kt) * 64,  (Bsb) + (64 + wv * 8) * 64); \
    gload16(Bg + (size_t)96 * DD + (kt) * 64,  (Bsb) + (96 + wv * 8) * 64); \
} while (0)

    STAGE64(0, As0, Bs0);
#pragma unroll
    for (int kt = 0; kt < 8; kt++) {
        __syncthreads();                       // buf[kt&1] ready; prev reads done
        const unsigned short* Ac = (kt & 1) ? As1 : As0;
        const unsigned short* Bc = (kt & 1) ? Bs1 : Bs0;
        if (kt < 7) {
            unsigned short* An = (kt & 1) ? As0 : As1;
            unsigned short* Bn = (kt & 1) ? Bs0 : Bs1;
            STAGE64(kt + 1, An, Bn);
        }
#pragma unroll
        for (int ks = 0; ks < 2; ks++) {       // MFMA order == old kt 0..15 (bit-identical)
            int su = (((ks << 2) + quad) ^ (rsel & 7)) << 3;
            frag8 af[4], bfr[2];
#pragma unroll
            for (int i = 0; i < 4; i++)
                af[i] = *(const frag8*)&Ac[(i * 16 + rsel) * 64 + su];
#pragma unroll
            for (int j = 0; j < 2; j++)
                bfr[j] = *(const frag8*)&Bc[(wv * 32 + j * 16 + rsel) * 64 + su];
#pragma unroll
            for (int i = 0; i < 4; i++)
#pragma unroll
                for (int j = 0; j < 2; j++)
                    acc[i * 2 + j] = __builtin_amdgcn_mfma_f32_16x16x32_bf16(
                        af[i], bfr[j], acc[i * 2 + j], 0, 0, 0);
        }
    }
#undef STAGE64
    __syncthreads();                           // K-loop LDS dead

    int r = t >> 2, c0 = (t & 3) * 32;
    if (mode == 1) {
        // stage A-tile for exact fp32 blend (coalesced)
        const unsigned short* srcA = Ap + (size_t)(mbase + r) * DD + nbase + c0;
#pragma unroll
        for (int u = 0; u < 4; u++)
            *(uint4*)&tH[r * 136 + c0 + u * 8] = *(const uint4*)(srcA + u * 8);
        __syncthreads();
    }
    float omt = 1.0f - theta;
#pragma unroll
    for (int i = 0; i < 4; i++)
#pragma unroll
        for (int j = 0; j < 2; j++) {
            int cl = wv * 32 + j * 16 + rsel;
            float bv = 0.f;
            if (mode == 0) bv = bias[nbase + cl];
            float vv[4];
#pragma unroll
            for (int rr = 0; rr < 4; rr++) {
                int rl = i * 16 + quad * 4 + rr;
                float x = acc[i * 2 + j][rr];
                if (mode == 0) x = fmaxf(x + bv, 0.f);
                else           x = theta * x + omt * bf2f(tH[rl * 136 + cl]);
                vv[rr] = x;
            }
#pragma unroll
            for (int rr = 0; rr < 4; rr++)
                tR[(i * 16 + quad * 4 + rr) * 136 + cl] = f2bf(vv[rr]);
            if (oTp) {
                ushort4 w4;
                w4.x = f2bf(vv[0]); w4.y = f2bf(vv[1]);
                w4.z = f2bf(vv[2]); w4.w = f2bf(vv[3]);
                *(ushort4*)&tT[cl * 72 + i * 16 + quad * 4] = w4;
            }
        }
    __syncthreads();
    {
        unsigned short* dst = oR + (size_t)(mbase + r) * DD + nbase + c0;
#pragma unroll
        for (int u = 0; u < 4; u++)
            *(uint4*)(dst + u * 8) = *(const uint4*)&tR[r * 136 + c0 + u * 8];
    }
    if (oTp) {
        int c = t >> 1, r0 = (t & 1) * 32;
        unsigned short* dst = oTp + (size_t)(nbase + c) * M3 + mbase + r0;
#pragma unroll
        for (int u = 0; u < 4; u++)
            *(uint4*)(dst + u * 8) = *(const uint4*)&tT[c * 72 + r0 + u * 8];
    }
}

// ---------- adj step on G: h = relu(0.9*(Ad@G + cv1.Gn1 + cv2.Gn2) + 0.1*P0) ----------
// 128-col chunks: grid (4, N_DIA, 3) = 576 blocks, ~42 KB LDS -> 3 blocks/CU
__global__ __launch_bounds__(256) void k_adj(
    const float* __restrict__ blk, const float* __restrict__ cross,
    const float* __restrict__ dinv,
    const unsigned short* __restrict__ GT, const unsigned short* __restrict__ Gr,
    const unsigned short* __restrict__ P0,
    unsigned short* __restrict__ hout, float* __restrict__ outF, int final_mode)
{
    __shared__ __align__(16) unsigned short AdL[64 * 64];    //  8 KB swizzled pitch-64
    __shared__ __align__(16) unsigned short GTL[128 * 64];   // 16 KB swizzled pitch-64
    __shared__ __align__(16) unsigned short OT[64 * 136];    // 17 KB out tile (mode 0)
    __shared__ float dv[64];
    int ch = blockIdx.x, d = blockIdx.y, m = blockIdx.z;
    int t = threadIdx.x;
    int lane = t & 63, wv = t >> 6;
    int dbase = d * 64, cbase = ch * 128;
    int rsel = lane & 15, quad = lane >> 4;

    if (t < 64) dv[t] = dinv[m * NTOT + dbase + t];
    __syncthreads();

    size_t bbase = (size_t)(m * N_DIA + d) * 4096;
#pragma unroll
    for (int q = 0; q < 4; q++) {
        int e4 = t + 256 * q;
        int i = e4 >> 4, j4 = e4 & 15;
        float4 w = *(const float4*)(blk + bbase + (size_t)i * 64 + j4 * 4);
        float di = dv[i];
        ushort4 o;
        o.x = f2bf(w.x * di * dv[j4 * 4 + 0]);
        o.y = f2bf(w.y * di * dv[j4 * 4 + 1]);
        o.z = f2bf(w.z * di * dv[j4 * 4 + 2]);
        o.w = f2bf(w.w * di * dv[j4 * 4 + 3]);
        *(ushort4*)((char*)AdL + i * 128 + (((j4 >> 1) ^ (i & 7)) << 4) + ((j4 & 1) << 3)) = o;
    }
#pragma unroll
    for (int p = 0; p < 4; p++) {
        int e = t + 256 * p;
        int cl = e >> 3;
        int uo = e & 7;
        uint4 w = *(const uint4*)(GT + (size_t)(cbase + cl) * M3 + m * NTOT + dbase + uo * 8);
        *(uint4*)((char*)GTL + cl * 128 + ((uo ^ (cl & 7)) << 4)) = w;
    }
    __syncthreads();

    f32x4 acc[8];
#pragma unroll
    for (int i = 0; i < 8; i++) acc[i] = (f32x4){0.f, 0.f, 0.f, 0.f};
#pragma unroll
    for (int kk = 0; kk < 2; kk++) {
        int su = ((kk * 4 + quad) ^ (rsel & 7)) << 4;
        frag8 bfr[4];
#pragma unroll
        for (int it = 0; it < 4; it++)
            bfr[it] = *(const frag8*)((const char*)AdL + (it * 16 + rsel) * 128 + su);
#pragma unroll
        for (int jc = 0; jc < 2; jc++) {
            frag8 af = *(const frag8*)((const char*)GTL + (wv * 32 + jc * 16 + rsel) * 128 + su);
#pragma unroll
            for (int it = 0; it < 4; it++)
                acc[jc * 4 + it] = __builtin_amdgcn_mfma_f32_16x16x32_bf16(
                    af, bfr[it], acc[jc * 4 + it], 0, 0, 0);
        }
    }

    int n1, n2, p1, p2;
    if (m == 0)      { n1 = 1; n2 = 2; p1 = 0; p2 = 1; }
    else if (m == 1) { n1 = 0; n2 = 2; p1 = 0; p2 = 2; }
    else             { n1 = 0; n2 = 1; p1 = 1; p2 = 2; }
#pragma unroll
    for (int it = 0; it < 4; it++) {
        int il = it * 16 + rsel;
        int gi = dbase + il;
        float dm = dv[il];
        float cv1 = cross[p1 * NTOT + gi] * dm * dinv[n1 * NTOT + gi];
        float cv2 = cross[p2 * NTOT + gi] * dm * dinv[n2 * NTOT + gi];
        size_t r1 = (size_t)(n1 * NTOT + gi) * DD;
        size_t r2 = (size_t)(n2 * NTOT + gi) * DD;
        size_t r0 = (size_t)(m * NTOT + gi) * DD;
#pragma unroll
        for (int jc = 0; jc < 2; jc++) {
            int cl = wv * 32 + jc * 16 + quad * 4;
            int cg = cbase + cl;
            ushort4 u1 = *(const ushort4*)(Gr + r1 + cg);
            ushort4 u2 = *(const ushort4*)(Gr + r2 + cg);
            ushort4 u0 = *(const ushort4*)(P0 + r0 + cg);
            f32x4 aa = acc[jc * 4 + it];
            float o0 = fmaxf(0.9f * (aa[0] + cv1 * bf2f(u1.x) + cv2 * bf2f(u2.x)) + 0.1f * bf2f(u0.x), 0.f);
            float o1 = fmaxf(0.9f * (aa[1] + cv1 * bf2f(u1.y) + cv2 * bf2f(u2.y)) + 0.1f * bf2f(u0.y), 0.f);
            float o2 = fmaxf(0.9f * (aa[2] + cv1 * bf2f(u1.z) + cv2 * bf2f(u2.z)) + 0.1f * bf2f(u0.z), 0.f);
            float o3 = fmaxf(0.9f * (aa[3] + cv1 * bf2f(u1.w) + cv2 * bf2f(u2.w)) + 0.1f * bf2f(u0.w), 0.f);
            if (final_mode) {
                *(float4*)(outF + (size_t)gi * 3072 + m * 1024 + 512 + cg) =
                    make_float4(o0, o1, o2, o3);
            } else {
                ushort4 w;
                w.x = f2bf(o0); w.y = f2bf(o1); w.z = f2bf(o2); w.w = f2bf(o3);
                *(ushort4*)&OT[il * 136 + cl] = w;
            }
        }
    }
    if (!final_mode) {
        __syncthreads();
        int r = t >> 2, c0 = (t & 3) * 32;
        unsigned short* dst = hout + (size_t)(m * NTOT + dbase + r) * DD + cbase + c0;
#pragma unroll
        for (int u = 0; u < 4; u++)
            *(uint4*)(dst + u * 8) = *(const uint4*)&OT[r * 136 + c0 + u * 8];
    }
}

extern "C" void kernel_launch(void* const* d_in, const int* in_sizes, int n_in,
                              void* d_out, int out_size, void* d_ws, size_t ws_size,
                              hipStream_t stream) {
    (void)in_sizes; (void)n_in; (void)out_size; (void)ws_size;
    const float* a     = (const float*)d_in[0];
    const float* v     = (const float*)d_in[1];
    const float* l     = (const float*)d_in[2];
    const float* qmask = (const float*)d_in[3];
    const float* Wspk  = (const float*)d_in[5];
    const float* W0    = (const float*)d_in[6];
    const float* b0    = (const float*)d_in[7];
    const float* Wg    = (const float*)d_in[8];
    float* out = (float*)d_out;
    float* ws = (float*)d_ws;

    float* invn  = ws;                                  // M3
    float* blk   = invn + M3;                           // 3*48*4096
    float* cross = blk + (size_t)3 * N_DIA * 4096;      // M3
    float* dinvp = cross + M3;                          // M3
    unsigned short* Wt  = (unsigned short*)(dinvp + M3);   // 3*DD*DD
    unsigned short* xb  = Wt + (size_t)3 * DD * DD;        // 3*SEG
    unsigned short* h0  = xb  + 3 * SEG;                   // 3*SEG
    unsigned short* G1r = h0  + 3 * SEG;                   // 3*SEG
    unsigned short* G1T = G1r + 3 * SEG;                   // 3*SEG
    unsigned short* h1  = G1T + 3 * SEG;                   // 3*SEG
    // lifetime aliases (ws footprint identical to verified rounds 2/4):
    unsigned short* G2r = xb;    // xb dead after gemm0; G2r born in gemm2
    unsigned short* G2T = G1r;   // G1r dead after adj1
    unsigned short* P02 = G1T;   // G1T dead after adj1

    const float th1 = 0.40546510810816438f;  // log(1.5)
    const float th2 = 0.22314355131420976f;  // log(1.25)

    k_pre_wt<<<1536, 256, 0, stream>>>(a, v, l, qmask, Wspk, W0, Wg, out, xb, invn, cross, Wt);
    k_gram_mfma<<<dim3(N_DIA, 3), 256, 0, stream>>>(xb, invn, cross, blk, dinvp);

    // h0 = relu(x @ W0 + b0)  (rows only)
    k_gemm<<<dim3(4, 144), 256, 0, stream>>>(xb, Wt, b0, h0, nullptr, 0.f, 0, nullptr, nullptr);
    // G1 = th1*(h0@W1) + (1-th1)*h0  (rows + transposed)
    k_gemm<<<dim3(4, 144), 256, 0, stream>>>(h0, Wt + (size_t)DD * DD, nullptr, G1r, G1T,
                                             th1, 1, nullptr, nullptr);
    // h1 = relu(0.9*(Ad@G1 + cross terms) + 0.1*G1)
    k_adj<<<dim3(4, N_DIA, 3), 256, 0, stream>>>(blk, cross, dinvp, G1T, G1r, G1r,
                                                 h1, nullptr, 0);
    // G2 = th2*(h1@W2) + (1-th2)*h1 (rows+T); P02 = th2*(h0@W2) + (1-th2)*h0 (rows, y>=144)
    k_gemm<<<dim3(4, 288), 256, 0, stream>>>(h1, Wt + (size_t)2 * DD * DD, nullptr, G2r, G2T,
                                             th2, 1, h0, P02);
    // out_h = relu(0.9*(Ad@G2 + cross terms) + 0.1*P02) -> fp32 output
    k_adj<<<dim3(4, N_DIA, 3), 256, 0, stream>>>(blk, cross, dinvp, G2T, G2r, P02,
                                                 nullptr, out, 1);
}

// Round 8
// 185.548 us; speedup vs baseline: 1.2942x; 1.0516x over previous
//
#include <hip/hip_runtime.h>
#include <math.h>

#define N_DIA 48
#define NTOT  3072     // N utterances
#define DD    512      // D == H
#define M3    9216     // 3N
#define SEG   ((size_t)NTOT * DD)

#define SCALE_F 0.99999f
#define PI_F    3.14159274101257324f

typedef __attribute__((ext_vector_type(8))) short frag8;
typedef __attribute__((ext_vector_type(4))) float f32x4;

__device__ __forceinline__ float ang_sim(float cs) {
    float cc = cs * SCALE_F;
    cc = fminf(fmaxf(cc, -SCALE_F), SCALE_F);
    return 1.0f - acosf(cc) / PI_F;
}
__device__ __forceinline__ unsigned short f2bf(float x) {
    union { float f; unsigned int u; } c; c.f = x;
    unsigned int r = c.u + 0x7fffu + ((c.u >> 16) & 1u);
    return (unsigned short)(r >> 16);
}
__device__ __forceinline__ float bf2f(unsigned short h) {
    union { unsigned int u; float f; } c; c.u = ((unsigned int)h) << 16;
    return c.f;
}
__device__ __forceinline__ void gload16(const unsigned short* g, unsigned short* s) {
    __builtin_amdgcn_global_load_lds(
        (const __attribute__((address_space(1))) unsigned int*)g,
        (__attribute__((address_space(3))) unsigned int*)s, 16, 0, 0);
}

// ---------- K_pre_wt: (blocks 0..767) per-utterance pre; (768..1535) W -> bf16 [n][k] ----------
__global__ __launch_bounds__(256) void k_pre_wt(
    const float* __restrict__ a, const float* __restrict__ v,
    const float* __restrict__ l, const float* __restrict__ qmask,
    const float* __restrict__ Wspk, const float* __restrict__ W0,
    const float* __restrict__ Wg,
    float* __restrict__ out, unsigned short* __restrict__ xb,
    float* __restrict__ invn, float* __restrict__ cross,
    unsigned short* __restrict__ Wt)
{
    __shared__ float tile[32][33];
    int b = blockIdx.x;
    if (b < 768) {
        int wv = threadIdx.x >> 6, t = threadIdx.x & 63;
        int i = b * 4 + wv;                 // utterance, one wave each
        int pos = i & 63, dia = i >> 6;
        int qb = (pos * N_DIA + dia) * 2;
        float q0 = qmask[qb], q1 = qmask[qb + 1];
        int spk = (q0 >= q1) ? 0 : 1;
        const float4* av4 = (const float4*)(a + (size_t)i * DD);
        const float4* vv4 = (const float4*)(v + (size_t)i * DD);
        const float4* lv4 = (const float4*)(l + (size_t)i * DD);
        const float4* wv4 = (const float4*)(Wspk + (size_t)spk * DD);
        float* ob = out + (size_t)i * 3072;
        float saa = 0, svv = 0, sll = 0, sav = 0, sal = 0, svl = 0;
#pragma unroll
        for (int e = 0; e < 2; e++) {
            int idx = e * 64 + t;           // fully coalesced: lane-major
            float4 xa = av4[idx], xv = vv4[idx], xd = lv4[idx], xw = wv4[idx];
            float4 xL = make_float4(xd.x + xw.x, xd.y + xw.y, xd.z + xw.z, xd.w + xw.w);
            *(float4*)(ob + idx * 4)        = xa;
            *(float4*)(ob + 1024 + idx * 4) = xv;
            *(float4*)(ob + 2048 + idx * 4) = xL;
            ushort4 ya, yv, yl;
            ya.x = f2bf(xa.x); ya.y = f2bf(xa.y); ya.z = f2bf(xa.z); ya.w = f2bf(xa.w);
            yv.x = f2bf(xv.x); yv.y = f2bf(xv.y); yv.z = f2bf(xv.z); yv.w = f2bf(xv.w);
            yl.x = f2bf(xL.x); yl.y = f2bf(xL.y); yl.z = f2bf(xL.z); yl.w = f2bf(xL.w);
            *(ushort4*)(xb + (size_t)i * DD + idx * 4) = ya;
            *(ushort4*)(xb + SEG + (size_t)i * DD + idx * 4) = yv;
            *(ushort4*)(xb + 2 * SEG + (size_t)i * DD + idx * 4) = yl;
            saa += xa.x * xa.x + xa.y * xa.y + xa.z * xa.z + xa.w * xa.w;
            svv += xv.x * xv.x + xv.y * xv.y + xv.z * xv.z + xv.w * xv.w;
            sll += xL.x * xL.x + xL.y * xL.y + xL.z * xL.z + xL.w * xL.w;
            sav += xa.x * xv.x + xa.y * xv.y + xa.z * xv.z + xa.w * xv.w;
            sal += xa.x * xL.x + xa.y * xL.y + xa.z * xL.z + xa.w * xL.w;
            svl += xv.x * xL.x + xv.y * xL.y + xv.z * xL.z + xv.w * xL.w;
        }
#pragma unroll
        for (int off = 32; off; off >>= 1) {
            saa += __shfl_down(saa, off, 64);
            svv += __shfl_down(svv, off, 64);
            sll += __shfl_down(sll, off, 64);
            sav += __shfl_down(sav, off, 64);
            sal += __shfl_down(sal, off, 64);
            svl += __shfl_down(svl, off, 64);
        }
        if (t == 0) {
            float ina = 1.0f / sqrtf(saa);
            float inv_ = 1.0f / sqrtf(svv);
            float inl = 1.0f / sqrtf(sll);
            invn[i] = ina; invn[NTOT + i] = inv_; invn[2 * NTOT + i] = inl;
            cross[i]            = ang_sim(sav * ina * inv_);
            cross[NTOT + i]     = ang_sim(sal * ina * inl);
            cross[2 * NTOT + i] = ang_sim(svl * inv_ * inl);
        }
    } else {
        int idx = b - 768;
        int mm = idx >> 8;
        int by = (idx >> 4) & 15, bx = idx & 15;
        const float* W = (mm == 0) ? W0 : Wg + (size_t)(mm - 1) * DD * DD;
        int t = threadIdx.x, tx = t & 31, ty = t >> 5;
#pragma unroll
        for (int q = 0; q < 4; q++) {
            int k = by * 32 + ty + q * 8;
            tile[ty + q * 8][tx] = W[(size_t)k * DD + bx * 32 + tx];
        }
        __syncthreads();
#pragma unroll
        for (int q = 0; q < 4; q++) {
            int n = bx * 32 + ty + q * 8;
            Wt[(size_t)mm * DD * DD + (size_t)n * DD + by * 32 + tx] = f2bf(tile[tx][ty + q * 8]);
        }
    }
}

// ---------- K2 merged: blocks [0,144): gram (two-phase K-split, 32 KB LDS)
//                       blocks [144,720): gemm0 h0 = relu(xb@W0+b0), BK=64 dbuf ----------
__global__ __launch_bounds__(256) void k_g0_gram(
    const unsigned short* __restrict__ xb, const unsigned short* __restrict__ Wt,
    const float* __restrict__ bias, unsigned short* __restrict__ h0,
    const float* __restrict__ invn, const float* __restrict__ cross,
    float* __restrict__ blk, float* __restrict__ dinv)
{
    __shared__ __align__(16) char smem[53248];
    int b = blockIdx.x;
    int t = threadIdx.x, lane = t & 63, wv = t >> 6;
    int rsel = lane & 15, quad = lane >> 4;

    if (b < 144) {
        // ---- gram flavor: two-phase K-split (c 0..7, then 8..15), acc order preserved ----
        unsigned short* Xs = (unsigned short*)smem;          // 8 c-tiles x [64][32] = 32 KB
        int d = b % N_DIA, m = b / N_DIA;
        int mrow = m * NTOT + d * 64;
        const unsigned short* src = xb + (size_t)mrow * DD;
        int sunit = ((t & 3) ^ ((t >> 2) & 3)) * 8;          // source pre-swizzle
        int sq = (quad ^ (rsel & 3)) * 8;                    // swizzled read unit
        f32x4 acc[4];
#pragma unroll
        for (int j = 0; j < 4; j++) acc[j] = (f32x4){0.f, 0.f, 0.f, 0.f};
#pragma unroll
        for (int p = 0; p < 2; p++) {
            if (p) __syncthreads();                          // phase-0 reads done
#pragma unroll
            for (int c = 0; c < 8; c++) {
                gload16(src + (size_t)(t >> 2) * DD + (p * 8 + c) * 32 + sunit,
                        &Xs[c * 2048 + wv * 512]);
            }
            __syncthreads();
#pragma unroll
            for (int c = 0; c < 8; c++) {
                const unsigned short* base = &Xs[c * 2048];
                frag8 bf[4];
#pragma unroll
                for (int j = 0; j < 4; j++)
                    bf[j] = *(const frag8*)&base[(j * 16 + rsel) * 32 + sq];
                frag8 af = *(const frag8*)&base[(wv * 16 + rsel) * 32 + sq];
#pragma unroll
                for (int j = 0; j < 4; j++)
                    acc[j] = __builtin_amdgcn_mfma_f32_16x16x32_bf16(af, bf[j], acc[j], 0, 0, 0);
            }
        }

        size_t bbase = (size_t)(m * N_DIA + d) * 4096;
        int rowl0 = wv * 16 + quad * 4;
        float ir[4], rs[4] = {0.f, 0.f, 0.f, 0.f};
#pragma unroll
        for (int r = 0; r < 4; r++) ir[r] = invn[mrow + rowl0 + r];
#pragma unroll
        for (int j = 0; j < 4; j++) {
            int coll = j * 16 + rsel;
            float ic = invn[mrow + coll];
#pragma unroll
            for (int r = 0; r < 4; r++) {
                float sim = ang_sim(acc[j][r] * ir[r] * ic);
                blk[bbase + (size_t)(rowl0 + r) * 64 + coll] = sim;
                rs[r] += sim;
            }
        }
#pragma unroll
        for (int off = 8; off; off >>= 1)
#pragma unroll
            for (int r = 0; r < 4; r++) rs[r] += __shfl_down(rs[r], off, 16);
        if (rsel == 0) {
#pragma unroll
            for (int r = 0; r < 4; r++) {
                int gi = d * 64 + rowl0 + r;
                float c1, c2;
                if (m == 0)      { c1 = cross[gi];        c2 = cross[NTOT + gi]; }
                else if (m == 1) { c1 = cross[gi];        c2 = cross[2 * NTOT + gi]; }
                else             { c1 = cross[NTOT + gi]; c2 = cross[2 * NTOT + gi]; }
                dinv[m * NTOT + gi] = 1.0f / sqrtf(rs[r] + c1 + c2);
            }
        }
        return;
    }

    // ---- gemm0 flavor: verbatim R7 k_gemm mode-0 path (BK=64, 8 barriers) ----
    unsigned short* const As0 = (unsigned short*)smem;            // [64][64]  8 KB
    unsigned short* const As1 = (unsigned short*)(smem + 8192);
    unsigned short* const Bs0 = (unsigned short*)(smem + 16384);  // [128][64] 16 KB
    unsigned short* const Bs1 = (unsigned short*)(smem + 32768);
    unsigned short* const tR  = (unsigned short*)(smem + 17408);  // [64][136] epilogue overlay

    int b2 = b - 144;
    int bx = b2 & 3, by = b2 >> 2;
    int mbase = by * 64, nbase = bx * 128;
    int r8 = lane >> 3, u8 = lane & 7;
    int su8 = (u8 ^ r8) << 3;                  // source pre-swizzle (elements)

    const unsigned short* Ag = xb + (size_t)(mbase + wv * 8 + r8) * DD + su8;
    const unsigned short* Bg = Wt + (size_t)(nbase + wv * 8 + r8) * DD + su8;

    f32x4 acc[8];
#pragma unroll
    for (int i = 0; i < 8; i++) acc[i] = (f32x4){0.f, 0.f, 0.f, 0.f};

#define STAGE64(kt, Asb, Bsb) do { \
    gload16(Ag + (kt) * 64,                    (Asb) + (wv * 8) * 64); \
    gload16(Ag + (size_t)32 * DD + (kt) * 64,  (Asb) + (32 + wv * 8) * 64); \
    gload16(Bg + (kt) * 64,                    (Bsb) + (wv * 8) * 64); \
    gload16(Bg + (size_t)32 * DD + (kt) * 64,  (Bsb) + (32 + wv * 8) * 64); \
    gload16(Bg + (size_t)64 * DD + (kt) * 64,  (Bsb) + (64 + wv * 8) * 64); \
    gload16(Bg + (size_t)96 * DD + (kt) * 64,  (Bsb) + (96 + wv * 8) * 64); \
} while (0)

    STAGE64(0, As0, Bs0);
#pragma unroll
    for (int kt = 0; kt < 8; kt++) {
        __syncthreads();
        const unsigned short* Ac = (kt & 1) ? As1 : As0;
        const unsigned short* Bc = (kt & 1) ? Bs1 : Bs0;
        if (kt < 7) {
            unsigned short* An = (kt & 1) ? As0 : As1;
            unsigned short* Bn = (kt & 1) ? Bs0 : Bs1;
            STAGE64(kt + 1, An, Bn);
        }
#pragma unroll
        for (int ks = 0; ks < 2; ks++) {
            int su = (((ks << 2) + quad) ^ (rsel & 7)) << 3;
            frag8 af[4], bfr[2];
#pragma unroll
            for (int i = 0; i < 4; i++)
                af[i] = *(const frag8*)&Ac[(i * 16 + rsel) * 64 + su];
#pragma unroll
            for (int j = 0; j < 2; j++)
                bfr[j] = *(const frag8*)&Bc[(wv * 32 + j * 16 + rsel) * 64 + su];
#pragma unroll
            for (int i = 0; i < 4; i++)
#pragma unroll
                for (int j = 0; j < 2; j++)
                    acc[i * 2 + j] = __builtin_amdgcn_mfma_f32_16x16x32_bf16(
                        af[i], bfr[j], acc[i * 2 + j], 0, 0, 0);
        }
    }
#undef STAGE64
    __syncthreads();

#pragma unroll
    for (int i = 0; i < 4; i++)
#pragma unroll
        for (int j = 0; j < 2; j++) {
            int cl = wv * 32 + j * 16 + rsel;
            float bv = bias[nbase + cl];
#pragma unroll
            for (int rr = 0; rr < 4; rr++) {
                float x = fmaxf(acc[i * 2 + j][rr] + bv, 0.f);
                tR[(i * 16 + quad * 4 + rr) * 136 + cl] = f2bf(x);
            }
        }
    __syncthreads();
    {
        int r = t >> 2, c0 = (t & 3) * 32;
        unsigned short* dst = h0 + (size_t)(mbase + r) * DD + nbase + c0;
#pragma unroll
        for (int u = 0; u < 4; u++)
            *(uint4*)(dst + u * 8) = *(const uint4*)&tR[r * 136 + c0 + u * 8];
    }
}

// ---------- GEMM: 64(M) x 128(N) tile, BK=64 dbuf LDS (8 barriers), swizzled ----------
// mode 1: theta*acc + (1-theta)*A[row][col]  -> rows (+ optional transposed GT)
// by>=144: second batch A2 -> oRows2 (rows only), same W/theta
__global__ __launch_bounds__(256) void k_gemm(
    const unsigned short* __restrict__ A, const unsigned short* __restrict__ W,
    unsigned short* __restrict__ oRows, unsigned short* __restrict__ oT,
    float theta,
    const unsigned short* __restrict__ A2, unsigned short* __restrict__ oRows2)
{
    __shared__ __align__(16) char smem[53248];
    unsigned short* const As0 = (unsigned short*)smem;            // [64][64]  8 KB
    unsigned short* const As1 = (unsigned short*)(smem + 8192);
    unsigned short* const Bs0 = (unsigned short*)(smem + 16384);  // [128][64] 16 KB
    unsigned short* const Bs1 = (unsigned short*)(smem + 32768);
    unsigned short* const tH  = (unsigned short*)smem;            // [64][136] (epilogue overlay)
    unsigned short* const tR  = (unsigned short*)(smem + 17408);  // [64][136]
    unsigned short* const tT  = (unsigned short*)(smem + 34816);  // [128][72]

    int t = threadIdx.x, lane = t & 63, wv = t >> 6;
    int bx = blockIdx.x, by = blockIdx.y;
    const unsigned short* Ap = A;
    unsigned short* oR = oRows;
    unsigned short* oTp = oT;
    if (by >= 144) { Ap = A2; oR = oRows2; oTp = nullptr; by -= 144; }
    int mbase = by * 64, nbase = bx * 128;
    int rsel = lane & 15, quad = lane >> 4;
    int r8 = lane >> 3, u8 = lane & 7;
    int su8 = (u8 ^ r8) << 3;

    const unsigned short* Ag = Ap + (size_t)(mbase + wv * 8 + r8) * DD + su8;
    const unsigned short* Bg = W  + (size_t)(nbase + wv * 8 + r8) * DD + su8;

    f32x4 acc[8];
#pragma unroll
    for (int i = 0; i < 8; i++) acc[i] = (f32x4){0.f, 0.f, 0.f, 0.f};

#define STAGE64(kt, Asb, Bsb) do { \
    gload16(Ag + (kt) * 64,                    (Asb) + (wv * 8) * 64); \
    gload16(Ag + (size_t)32 * DD + (kt) * 64,  (Asb) + (32 + wv * 8) * 64); \
    gload16(Bg + (kt) * 64,                    (Bsb) + (wv * 8) * 64); \
    gload16(Bg + (size_t)32 * DD + (kt) * 64,  (Bsb) + (32 + wv * 8) * 64); \
    gload16(Bg + (size_t)64 * DD + (kt) * 64,  (Bsb) + (64 + wv * 8) * 64); \
    gload16(Bg + (size_t)96 * DD + (kt) * 64,  (Bsb) + (96 + wv * 8) * 64); \
} while (0)

    STAGE64(0, As0, Bs0);
#pragma unroll
    for (int kt = 0; kt < 8; kt++) {
        __syncthreads();
        const unsigned short* Ac = (kt & 1) ? As1 : As0;
        const unsigned short* Bc = (kt & 1) ? Bs1 : Bs0;
        if (kt < 7) {
            unsigned short* An = (kt & 1) ? As0 : As1;
            unsigned short* Bn = (kt & 1) ? Bs0 : Bs1;
            STAGE64(kt + 1, An, Bn);
        }
#pragma unroll
        for (int ks = 0; ks < 2; ks++) {
            int su = (((ks << 2) + quad) ^ (rsel & 7)) << 3;
            frag8 af[4], bfr[2];
#pragma unroll
            for (int i = 0; i < 4; i++)
                af[i] = *(const frag8*)&Ac[(i * 16 + rsel) * 64 + su];
#pragma unroll
            for (int j = 0; j < 2; j++)
                bfr[j] = *(const frag8*)&Bc[(wv * 32 + j * 16 + rsel) * 64 + su];
#pragma unroll
            for (int i = 0; i < 4; i++)
#pragma unroll
                for (int j = 0; j < 2; j++)
                    acc[i * 2 + j] = __builtin_amdgcn_mfma_f32_16x16x32_bf16(
                        af[i], bfr[j], acc[i * 2 + j], 0, 0, 0);
        }
    }
#undef STAGE64
    __syncthreads();

    int r = t >> 2, c0 = (t & 3) * 32;
    {
        // stage A-tile for exact fp32 blend (coalesced)
        const unsigned short* srcA = Ap + (size_t)(mbase + r) * DD + nbase + c0;
#pragma unroll
        for (int u = 0; u < 4; u++)
            *(uint4*)&tH[r * 136 + c0 + u * 8] = *(const uint4*)(srcA + u * 8);
        __syncthreads();
    }
    float omt = 1.0f - theta;
#pragma unroll
    for (int i = 0; i < 4; i++)
#pragma unroll
        for (int j = 0; j < 2; j++) {
            int cl = wv * 32 + j * 16 + rsel;
            float vv[4];
#pragma unroll
            for (int rr = 0; rr < 4; rr++) {
                int rl = i * 16 + quad * 4 + rr;
                vv[rr] = theta * acc[i * 2 + j][rr] + omt * bf2f(tH[rl * 136 + cl]);
            }
#pragma unroll
            for (int rr = 0; rr < 4; rr++)
                tR[(i * 16 + quad * 4 + rr) * 136 + cl] = f2bf(vv[rr]);
            if (oTp) {
                ushort4 w4;
                w4.x = f2bf(vv[0]); w4.y = f2bf(vv[1]);
                w4.z = f2bf(vv[2]); w4.w = f2bf(vv[3]);
                *(ushort4*)&tT[cl * 72 + i * 16 + quad * 4] = w4;
            }
        }
    __syncthreads();
    {
        unsigned short* dst = oR + (size_t)(mbase + r) * DD + nbase + c0;
#pragma unroll
        for (int u = 0; u < 4; u++)
            *(uint4*)(dst + u * 8) = *(const uint4*)&tR[r * 136 + c0 + u * 8];
    }
    if (oTp) {
        int c = t >> 1, r0 = (t & 1) * 32;
        unsigned short* dst = oTp + (size_t)(nbase + c) * M3 + mbase + r0;
#pragma unroll
        for (int u = 0; u < 4; u++)
            *(uint4*)(dst + u * 8) = *(const uint4*)&tT[c * 72 + r0 + u * 8];
    }
}

// ---------- adj step on G: h = relu(0.9*(Ad@G + cv1.Gn1 + cv2.Gn2) + 0.1*P0) ----------
// 128-col chunks: grid (4, N_DIA, 3) = 576 blocks, ~42 KB LDS -> 3 blocks/CU
__global__ __launch_bounds__(256) void k_adj(
    const float* __restrict__ blk, const float* __restrict__ cross,
    const float* __restrict__ dinv,
    const unsigned short* __restrict__ GT, const unsigned short* __restrict__ Gr,
    const unsigned short* __restrict__ P0,
    unsigned short* __restrict__ hout, float* __restrict__ outF, int final_mode)
{
    __shared__ __align__(16) unsigned short AdL[64 * 64];    //  8 KB swizzled pitch-64
    __shared__ __align__(16) unsigned short GTL[128 * 64];   // 16 KB swizzled pitch-64
    __shared__ __align__(16) unsigned short OT[64 * 136];    // 17 KB out tile (mode 0)
    __shared__ float dv[64];
    int ch = blockIdx.x, d = blockIdx.y, m = blockIdx.z;
    int t = threadIdx.x;
    int lane = t & 63, wv = t >> 6;
    int dbase = d * 64, cbase = ch * 128;
    int rsel = lane & 15, quad = lane >> 4;

    if (t < 64) dv[t] = dinv[m * NTOT + dbase + t];
    __syncthreads();

    size_t bbase = (size_t)(m * N_DIA + d) * 4096;
#pragma unroll
    for (int q = 0; q < 4; q++) {
        int e4 = t + 256 * q;
        int i = e4 >> 4, j4 = e4 & 15;
        float4 w = *(const float4*)(blk + bbase + (size_t)i * 64 + j4 * 4);
        float di = dv[i];
        ushort4 o;
        o.x = f2bf(w.x * di * dv[j4 * 4 + 0]);
        o.y = f2bf(w.y * di * dv[j4 * 4 + 1]);
        o.z = f2bf(w.z * di * dv[j4 * 4 + 2]);
        o.w = f2bf(w.w * di * dv[j4 * 4 + 3]);
        *(ushort4*)((char*)AdL + i * 128 + (((j4 >> 1) ^ (i & 7)) << 4) + ((j4 & 1) << 3)) = o;
    }
#pragma unroll
    for (int p = 0; p < 4; p++) {
        int e = t + 256 * p;
        int cl = e >> 3;
        int uo = e & 7;
        uint4 w = *(const uint4*)(GT + (size_t)(cbase + cl) * M3 + m * NTOT + dbase + uo * 8);
        *(uint4*)((char*)GTL + cl * 128 + ((uo ^ (cl & 7)) << 4)) = w;
    }
    __syncthreads();

    f32x4 acc[8];
#pragma unroll
    for (int i = 0; i < 8; i++) acc[i] = (f32x4){0.f, 0.f, 0.f, 0.f};
#pragma unroll
    for (int kk = 0; kk < 2; kk++) {
        int su = ((kk * 4 + quad) ^ (rsel & 7)) << 4;
        frag8 bfr[4];
#pragma unroll
        for (int it = 0; it < 4; it++)
            bfr[it] = *(const frag8*)((const char*)AdL + (it * 16 + rsel) * 128 + su);
#pragma unroll
        for (int jc = 0; jc < 2; jc++) {
            frag8 af = *(const frag8*)((const char*)GTL + (wv * 32 + jc * 16 + rsel) * 128 + su);
#pragma unroll
            for (int it = 0; it < 4; it++)
                acc[jc * 4 + it] = __builtin_amdgcn_mfma_f32_16x16x32_bf16(
                    af, bfr[it], acc[jc * 4 + it], 0, 0, 0);
        }
    }

    int n1, n2, p1, p2;
    if (m == 0)      { n1 = 1; n2 = 2; p1 = 0; p2 = 1; }
    else if (m == 1) { n1 = 0; n2 = 2; p1 = 0; p2 = 2; }
    else             { n1 = 0; n2 = 1; p1 = 1; p2 = 2; }
#pragma unroll
    for (int it = 0; it < 4; it++) {
        int il = it * 16 + rsel;
        int gi = dbase + il;
        float dm = dv[il];
        float cv1 = cross[p1 * NTOT + gi] * dm * dinv[n1 * NTOT + gi];
        float cv2 = cross[p2 * NTOT + gi] * dm * dinv[n2 * NTOT + gi];
        size_t r1 = (size_t)(n1 * NTOT + gi) * DD;
        size_t r2 = (size_t)(n2 * NTOT + gi) * DD;
        size_t r0 = (size_t)(m * NTOT + gi) * DD;
#pragma unroll
        for (int jc = 0; jc < 2; jc++) {
            int cl = wv * 32 + jc * 16 + quad * 4;
            int cg = cbase + cl;
            ushort4 u1 = *(const ushort4*)(Gr + r1 + cg);
            ushort4 u2 = *(const ushort4*)(Gr + r2 + cg);
            ushort4 u0 = *(const ushort4*)(P0 + r0 + cg);
            f32x4 aa = acc[jc * 4 + it];
            float o0 = fmaxf(0.9f * (aa[0] + cv1 * bf2f(u1.x) + cv2 * bf2f(u2.x)) + 0.1f * bf2f(u0.x), 0.f);
            float o1 = fmaxf(0.9f * (aa[1] + cv1 * bf2f(u1.y) + cv2 * bf2f(u2.y)) + 0.1f * bf2f(u0.y), 0.f);
            float o2 = fmaxf(0.9f * (aa[2] + cv1 * bf2f(u1.z) + cv2 * bf2f(u2.z)) + 0.1f * bf2f(u0.z), 0.f);
            float o3 = fmaxf(0.9f * (aa[3] + cv1 * bf2f(u1.w) + cv2 * bf2f(u2.w)) + 0.1f * bf2f(u0.w), 0.f);
            if (final_mode) {
                *(float4*)(outF + (size_t)gi * 3072 + m * 1024 + 512 + cg) =
                    make_float4(o0, o1, o2, o3);
            } else {
                ushort4 w;
                w.x = f2bf(o0); w.y = f2bf(o1); w.z = f2bf(o2); w.w = f2bf(o3);
                *(ushort4*)&OT[il * 136 + cl] = w;
            }
        }
    }
    if (!final_mode) {
        __syncthreads();
        int r = t >> 2, c0 = (t & 3) * 32;
        unsigned short* dst = hout + (size_t)(m * NTOT + dbase + r) * DD + cbase + c0;
#pragma unroll
        for (int u = 0; u < 4; u++)
            *(uint4*)(dst + u * 8) = *(const uint4*)&OT[r * 136 + c0 + u * 8];
    }
}

extern "C" void kernel_launch(void* const* d_in, const int* in_sizes, int n_in,
                              void* d_out, int out_size, void* d_ws, size_t ws_size,
                              hipStream_t stream) {
    (void)in_sizes; (void)n_in; (void)out_size; (void)ws_size;
    const float* a     = (const float*)d_in[0];
    const float* v     = (const float*)d_in[1];
    const float* l     = (const float*)d_in[2];
    const float* qmask = (const float*)d_in[3];
    const float* Wspk  = (const float*)d_in[5];
    const float* W0    = (const float*)d_in[6];
    const float* b0    = (const float*)d_in[7];
    const float* Wg    = (const float*)d_in[8];
    float* out = (float*)d_out;
    float* ws = (float*)d_ws;

    float* invn  = ws;                                  // M3
    float* blk   = invn + M3;                           // 3*48*4096
    float* cross = blk + (size_t)3 * N_DIA * 4096;      // M3
    float* dinvp = cross + M3;                          // M3
    unsigned short* Wt  = (unsigned short*)(dinvp + M3);   // 3*DD*DD
    unsigned short* xb  = Wt + (size_t)3 * DD * DD;        // 3*SEG
    unsigned short* h0  = xb  + 3 * SEG;                   // 3*SEG
    unsigned short* G1r = h0  + 3 * SEG;                   // 3*SEG
    unsigned short* G1T = G1r + 3 * SEG;                   // 3*SEG
    unsigned short* h1  = G1T + 3 * SEG;                   // 3*SEG
    // lifetime aliases (ws footprint identical to verified rounds 2/4/7):
    unsigned short* G2r = xb;    // xb dead after k_g0_gram; G2r born in gemm2
    unsigned short* G2T = G1r;   // G1r dead after adj1
    unsigned short* P02 = G1T;   // G1T dead after adj1

    const float th1 = 0.40546510810816438f;  // log(1.5)
    const float th2 = 0.22314355131420976f;  // log(1.25)

    k_pre_wt<<<1536, 256, 0, stream>>>(a, v, l, qmask, Wspk, W0, Wg, out, xb, invn, cross, Wt);
    // merged: gram (blocks 0..143) + h0 gemm (blocks 144..719)
    k_g0_gram<<<720, 256, 0, stream>>>(xb, Wt, b0, h0, invn, cross, blk, dinvp);
    // G1 = th1*(h0@W1) + (1-th1)*h0  (rows + transposed)
    k_gemm<<<dim3(4, 144), 256, 0, stream>>>(h0, Wt + (size_t)DD * DD, G1r, G1T,
                                             th1, nullptr, nullptr);
    // h1 = relu(0.9*(Ad@G1 + cross terms) + 0.1*G1)
    k_adj<<<dim3(4, N_DIA, 3), 256, 0, stream>>>(blk, cross, dinvp, G1T, G1r, G1r,
                                                 h1, nullptr, 0);
    // G2 = th2*(h1@W2) + (1-th2)*h1 (rows+T); P02 = th2*(h0@W2) + (1-th2)*h0 (rows, y>=144)
    k_gemm<<<dim3(4, 288), 256, 0, stream>>>(h1, Wt + (size_t)2 * DD * DD, G2r, G2T,
                                             th2, h0, P02);
    // out_h = relu(0.9*(Ad@G2 + cross terms) + 0.1*P02) -> fp32 output
    k_adj<<<dim3(4, N_DIA, 3), 256, 0, stream>>>(blk, cross, dinvp, G2T, G2r, P02,
                                                 nullptr, out, 1);
}

// Round 10
// 183.430 us; speedup vs baseline: 1.3092x; 1.0115x over previous
//
#include <hip/hip_runtime.h>
#include <math.h>

#define N_DIA 48
#define NTOT  3072     // N utterances
#define DD    512      // D == H
#define M3    9216     // 3N
#define SEG   ((size_t)NTOT * DD)

#define SCALE_F 0.99999f
#define PI_F    3.14159274101257324f

typedef __attribute__((ext_vector_type(8))) short frag8;
typedef __attribute__((ext_vector_type(4))) float f32x4;

__device__ __forceinline__ float ang_sim(float cs) {
    float cc = cs * SCALE_F;
    cc = fminf(fmaxf(cc, -SCALE_F), SCALE_F);
    return 1.0f - acosf(cc) / PI_F;
}
__device__ __forceinline__ unsigned short f2bf(float x) {
    union { float f; unsigned int u; } c; c.f = x;
    unsigned int r = c.u + 0x7fffu + ((c.u >> 16) & 1u);
    return (unsigned short)(r >> 16);
}
__device__ __forceinline__ float bf2f(unsigned short h) {
    union { unsigned int u; float f; } c; c.u = ((unsigned int)h) << 16;
    return c.f;
}
__device__ __forceinline__ void gload16(const unsigned short* g, unsigned short* s) {
    __builtin_amdgcn_global_load_lds(
        (const __attribute__((address_space(1))) unsigned int*)g,
        (__attribute__((address_space(3))) unsigned int*)s, 16, 0, 0);
}

// ---------- K_pre_wt: (blocks 0..767) per-utterance pre; (768..1535) W -> bf16 [n][k] ----------
__global__ __launch_bounds__(256) void k_pre_wt(
    const float* __restrict__ a, const float* __restrict__ v,
    const float* __restrict__ l, const float* __restrict__ qmask,
    const float* __restrict__ Wspk, const float* __restrict__ W0,
    const float* __restrict__ Wg,
    float* __restrict__ out, unsigned short* __restrict__ xb,
    float* __restrict__ invn, float* __restrict__ cross,
    unsigned short* __restrict__ Wt)
{
    __shared__ float tile[32][33];
    int b = blockIdx.x;
    if (b < 768) {
        int wv = threadIdx.x >> 6, t = threadIdx.x & 63;
        int i = b * 4 + wv;                 // utterance, one wave each
        int pos = i & 63, dia = i >> 6;
        int qb = (pos * N_DIA + dia) * 2;
        float q0 = qmask[qb], q1 = qmask[qb + 1];
        int spk = (q0 >= q1) ? 0 : 1;
        const float4* av4 = (const float4*)(a + (size_t)i * DD);
        const float4* vv4 = (const float4*)(v + (size_t)i * DD);
        const float4* lv4 = (const float4*)(l + (size_t)i * DD);
        const float4* wv4 = (const float4*)(Wspk + (size_t)spk * DD);
        float* ob = out + (size_t)i * 3072;
        float saa = 0, svv = 0, sll = 0, sav = 0, sal = 0, svl = 0;
#pragma unroll
        for (int e = 0; e < 2; e++) {
            int idx = e * 64 + t;           // fully coalesced: lane-major
            float4 xa = av4[idx], xv = vv4[idx], xd = lv4[idx], xw = wv4[idx];
            float4 xL = make_float4(xd.x + xw.x, xd.y + xw.y, xd.z + xw.z, xd.w + xw.w);
            *(float4*)(ob + idx * 4)        = xa;
            *(float4*)(ob + 1024 + idx * 4) = xv;
            *(float4*)(ob + 2048 + idx * 4) = xL;
            ushort4 ya, yv, yl;
            ya.x = f2bf(xa.x); ya.y = f2bf(xa.y); ya.z = f2bf(xa.z); ya.w = f2bf(xa.w);
            yv.x = f2bf(xv.x); yv.y = f2bf(xv.y); yv.z = f2bf(xv.z); yv.w = f2bf(xv.w);
            yl.x = f2bf(xL.x); yl.y = f2bf(xL.y); yl.z = f2bf(xL.z); yl.w = f2bf(xL.w);
            *(ushort4*)(xb + (size_t)i * DD + idx * 4) = ya;
            *(ushort4*)(xb + SEG + (size_t)i * DD + idx * 4) = yv;
            *(ushort4*)(xb + 2 * SEG + (size_t)i * DD + idx * 4) = yl;
            saa += xa.x * xa.x + xa.y * xa.y + xa.z * xa.z + xa.w * xa.w;
            svv += xv.x * xv.x + xv.y * xv.y + xv.z * xv.z + xv.w * xv.w;
            sll += xL.x * xL.x + xL.y * xL.y + xL.z * xL.z + xL.w * xL.w;
            sav += xa.x * xv.x + xa.y * xv.y + xa.z * xv.z + xa.w * xv.w;
            sal += xa.x * xL.x + xa.y * xL.y + xa.z * xL.z + xa.w * xL.w;
            svl += xv.x * xL.x + xv.y * xL.y + xv.z * xL.z + xv.w * xL.w;
        }
#pragma unroll
        for (int off = 32; off; off >>= 1) {
            saa += __shfl_down(saa, off, 64);
            svv += __shfl_down(svv, off, 64);
            sll += __shfl_down(sll, off, 64);
            sav += __shfl_down(sav, off, 64);
            sal += __shfl_down(sal, off, 64);
            svl += __shfl_down(svl, off, 64);
        }
        if (t == 0) {
            float ina = 1.0f / sqrtf(saa);
            float inv_ = 1.0f / sqrtf(svv);
            float inl = 1.0f / sqrtf(sll);
            invn[i] = ina; invn[NTOT + i] = inv_; invn[2 * NTOT + i] = inl;
            cross[i]            = ang_sim(sav * ina * inv_);
            cross[NTOT + i]     = ang_sim(sal * ina * inl);
            cross[2 * NTOT + i] = ang_sim(svl * inv_ * inl);
        }
    } else {
        int idx = b - 768;
        int mm = idx >> 8;
        int by = (idx >> 4) & 15, bx = idx & 15;
        const float* W = (mm == 0) ? W0 : Wg + (size_t)(mm - 1) * DD * DD;
        int t = threadIdx.x, tx = t & 31, ty = t >> 5;
#pragma unroll
        for (int q = 0; q < 4; q++) {
            int k = by * 32 + ty + q * 8;
            tile[ty + q * 8][tx] = W[(size_t)k * DD + bx * 32 + tx];
        }
        __syncthreads();
#pragma unroll
        for (int q = 0; q < 4; q++) {
            int n = bx * 32 + ty + q * 8;
            Wt[(size_t)mm * DD * DD + (size_t)n * DD + by * 32 + tx] = f2bf(tile[tx][ty + q * 8]);
        }
    }
}

// ---------- K2 merged: blocks [0,144): gram (two-phase K-split, 32 KB LDS)
//                       blocks [144,720): gemm0 h0 = relu(xb@W0+b0), BK=64 dbuf ----------
__global__ __launch_bounds__(256) void k_g0_gram(
    const unsigned short* __restrict__ xb, const unsigned short* __restrict__ Wt,
    const float* __restrict__ bias, unsigned short* __restrict__ h0,
    const float* __restrict__ invn, const float* __restrict__ cross,
    float* __restrict__ blk, float* __restrict__ dinv)
{
    __shared__ __align__(16) char smem[53248];
    int b = blockIdx.x;
    int t = threadIdx.x, lane = t & 63, wv = t >> 6;
    int rsel = lane & 15, quad = lane >> 4;

    if (b < 144) {
        // ---- gram flavor: two-phase K-split (c 0..7, then 8..15), acc order preserved ----
        unsigned short* Xs = (unsigned short*)smem;          // 8 c-tiles x [64][32] = 32 KB
        int d = b % N_DIA, m = b / N_DIA;
        int mrow = m * NTOT + d * 64;
        const unsigned short* src = xb + (size_t)mrow * DD;
        int sunit = ((t & 3) ^ ((t >> 2) & 3)) * 8;          // source pre-swizzle
        int sq = (quad ^ (rsel & 3)) * 8;                    // swizzled read unit
        f32x4 acc[4];
#pragma unroll
        for (int j = 0; j < 4; j++) acc[j] = (f32x4){0.f, 0.f, 0.f, 0.f};
#pragma unroll
        for (int p = 0; p < 2; p++) {
            if (p) __syncthreads();                          // phase-0 reads done
#pragma unroll
            for (int c = 0; c < 8; c++) {
                gload16(src + (size_t)(t >> 2) * DD + (p * 8 + c) * 32 + sunit,
                        &Xs[c * 2048 + wv * 512]);
            }
            __syncthreads();
#pragma unroll
            for (int c = 0; c < 8; c++) {
                const unsigned short* base = &Xs[c * 2048];
                frag8 bf[4];
#pragma unroll
                for (int j = 0; j < 4; j++)
                    bf[j] = *(const frag8*)&base[(j * 16 + rsel) * 32 + sq];
                frag8 af = *(const frag8*)&base[(wv * 16 + rsel) * 32 + sq];
#pragma unroll
                for (int j = 0; j < 4; j++)
                    acc[j] = __builtin_amdgcn_mfma_f32_16x16x32_bf16(af, bf[j], acc[j], 0, 0, 0);
            }
        }

        size_t bbase = (size_t)(m * N_DIA + d) * 4096;
        int rowl0 = wv * 16 + quad * 4;
        float ir[4], rs[4] = {0.f, 0.f, 0.f, 0.f};
#pragma unroll
        for (int r = 0; r < 4; r++) ir[r] = invn[mrow + rowl0 + r];
#pragma unroll
        for (int j = 0; j < 4; j++) {
            int coll = j * 16 + rsel;
            float ic = invn[mrow + coll];
#pragma unroll
            for (int r = 0; r < 4; r++) {
                float sim = ang_sim(acc[j][r] * ir[r] * ic);
                blk[bbase + (size_t)(rowl0 + r) * 64 + coll] = sim;
                rs[r] += sim;
            }
        }
#pragma unroll
        for (int off = 8; off; off >>= 1)
#pragma unroll
            for (int r = 0; r < 4; r++) rs[r] += __shfl_down(rs[r], off, 16);
        if (rsel == 0) {
#pragma unroll
            for (int r = 0; r < 4; r++) {
                int gi = d * 64 + rowl0 + r;
                float c1, c2;
                if (m == 0)      { c1 = cross[gi];        c2 = cross[NTOT + gi]; }
                else if (m == 1) { c1 = cross[gi];        c2 = cross[2 * NTOT + gi]; }
                else             { c1 = cross[NTOT + gi]; c2 = cross[2 * NTOT + gi]; }
                dinv[m * NTOT + gi] = 1.0f / sqrtf(rs[r] + c1 + c2);
            }
        }
        return;
    }

    // ---- gemm0 flavor (BK=64, 8 barriers) ----
    unsigned short* const As0 = (unsigned short*)smem;            // [64][64]  8 KB
    unsigned short* const As1 = (unsigned short*)(smem + 8192);
    unsigned short* const Bs0 = (unsigned short*)(smem + 16384);  // [128][64] 16 KB
    unsigned short* const Bs1 = (unsigned short*)(smem + 32768);
    unsigned short* const tR  = (unsigned short*)(smem + 17408);  // [64][136] epilogue overlay

    int b2 = b - 144;
    int bx = b2 & 3, by = b2 >> 2;
    int mbase = by * 64, nbase = bx * 128;
    int r8 = lane >> 3, u8 = lane & 7;
    int su8 = (u8 ^ r8) << 3;                  // source pre-swizzle (elements)

    const unsigned short* Ag = xb + (size_t)(mbase + wv * 8 + r8) * DD + su8;
    const unsigned short* Bg = Wt + (size_t)(nbase + wv * 8 + r8) * DD + su8;

    f32x4 acc[8];
#pragma unroll
    for (int i = 0; i < 8; i++) acc[i] = (f32x4){0.f, 0.f, 0.f, 0.f};

#define STAGE64(kt, Asb, Bsb) do { \
    gload16(Ag + (kt) * 64,                    (Asb) + (wv * 8) * 64); \
    gload16(Ag + (size_t)32 * DD + (kt) * 64,  (Asb) + (32 + wv * 8) * 64); \
    gload16(Bg + (kt) * 64,                    (Bsb) + (wv * 8) * 64); \
    gload16(Bg + (size_t)32 * DD + (kt) * 64,  (Bsb) + (32 + wv * 8) * 64); \
    gload16(Bg + (size_t)64 * DD + (kt) * 64,  (Bsb) + (64 + wv * 8) * 64); \
    gload16(Bg + (size_t)96 * DD + (kt) * 64,  (Bsb) + (96 + wv * 8) * 64); \
} while (0)

    STAGE64(0, As0, Bs0);
#pragma unroll
    for (int kt = 0; kt < 8; kt++) {
        __syncthreads();
        const unsigned short* Ac = (kt & 1) ? As1 : As0;
        const unsigned short* Bc = (kt & 1) ? Bs1 : Bs0;
        if (kt < 7) {
            unsigned short* An = (kt & 1) ? As0 : As1;
            unsigned short* Bn = (kt & 1) ? Bs0 : Bs1;
            STAGE64(kt + 1, An, Bn);
        }
#pragma unroll
        for (int ks = 0; ks < 2; ks++) {
            int su = (((ks << 2) + quad) ^ (rsel & 7)) << 3;
            frag8 af[4], bfr[2];
#pragma unroll
            for (int i = 0; i < 4; i++)
                af[i] = *(const frag8*)&Ac[(i * 16 + rsel) * 64 + su];
#pragma unroll
            for (int j = 0; j < 2; j++)
                bfr[j] = *(const frag8*)&Bc[(wv * 32 + j * 16 + rsel) * 64 + su];
#pragma unroll
            for (int i = 0; i < 4; i++)
#pragma unroll
                for (int j = 0; j < 2; j++)
                    acc[i * 2 + j] = __builtin_amdgcn_mfma_f32_16x16x32_bf16(
                        af[i], bfr[j], acc[i * 2 + j], 0, 0, 0);
        }
    }
#undef STAGE64
    __syncthreads();

#pragma unroll
    for (int i = 0; i < 4; i++)
#pragma unroll
        for (int j = 0; j < 2; j++) {
            int cl = wv * 32 + j * 16 + rsel;
            float bv = bias[nbase + cl];
#pragma unroll
            for (int rr = 0; rr < 4; rr++) {
                float x = fmaxf(acc[i * 2 + j][rr] + bv, 0.f);
                tR[(i * 16 + quad * 4 + rr) * 136 + cl] = f2bf(x);
            }
        }
    __syncthreads();
    {
        int r = t >> 2, c0 = (t & 3) * 32;
        unsigned short* dst = h0 + (size_t)(mbase + r) * DD + nbase + c0;
#pragma unroll
        for (int u = 0; u < 4; u++)
            *(uint4*)(dst + u * 8) = *(const uint4*)&tR[r * 136 + c0 + u * 8];
    }
}

// ---------- GEMM: 64(M) x 128(N) tile, BK=64 dbuf LDS (8 barriers), swizzled ----------
// theta*acc + (1-theta)*A[row][col] -> rows (+ optional transposed oT)
__global__ __launch_bounds__(256) void k_gemm(
    const unsigned short* __restrict__ A, const unsigned short* __restrict__ W,
    unsigned short* __restrict__ oRows, unsigned short* __restrict__ oT,
    float theta)
{
    __shared__ __align__(16) char smem[53248];
    unsigned short* const As0 = (unsigned short*)smem;            // [64][64]  8 KB
    unsigned short* const As1 = (unsigned short*)(smem + 8192);
    unsigned short* const Bs0 = (unsigned short*)(smem + 16384);  // [128][64] 16 KB
    unsigned short* const Bs1 = (unsigned short*)(smem + 32768);
    unsigned short* const tH  = (unsigned short*)smem;            // [64][136] (epilogue overlay)
    unsigned short* const tR  = (unsigned short*)(smem + 17408);  // [64][136]
    unsigned short* const tT  = (unsigned short*)(smem + 34816);  // [128][72]

    int t = threadIdx.x, lane = t & 63, wv = t >> 6;
    int bx = blockIdx.x, by = blockIdx.y;
    int mbase = by * 64, nbase = bx * 128;
    int rsel = lane & 15, quad = lane >> 4;
    int r8 = lane >> 3, u8 = lane & 7;
    int su8 = (u8 ^ r8) << 3;

    const unsigned short* Ag = A + (size_t)(mbase + wv * 8 + r8) * DD + su8;
    const unsigned short* Bg = W + (size_t)(nbase + wv * 8 + r8) * DD + su8;

    f32x4 acc[8];
#pragma unroll
    for (int i = 0; i < 8; i++) acc[i] = (f32x4){0.f, 0.f, 0.f, 0.f};

#define STAGE64(kt, Asb, Bsb) do { \
    gload16(Ag + (kt) * 64,                    (Asb) + (wv * 8) * 64); \
    gload16(Ag + (size_t)32 * DD + (kt) * 64,  (Asb) + (32 + wv * 8) * 64); \
    gload16(Bg + (kt) * 64,                    (Bsb) + (wv * 8) * 64); \
    gload16(Bg + (size_t)32 * DD + (kt) * 64,  (Bsb) + (32 + wv * 8) * 64); \
    gload16(Bg + (size_t)64 * DD + (kt) * 64,  (Bsb) + (64 + wv * 8) * 64); \
    gload16(Bg + (size_t)96 * DD + (kt) * 64,  (Bsb) + (96 + wv * 8) * 64); \
} while (0)

    STAGE64(0, As0, Bs0);
#pragma unroll
    for (int kt = 0; kt < 8; kt++) {
        __syncthreads();
        const unsigned short* Ac = (kt & 1) ? As1 : As0;
        const unsigned short* Bc = (kt & 1) ? Bs1 : Bs0;
        if (kt < 7) {
            unsigned short* An = (kt & 1) ? As0 : As1;
            unsigned short* Bn = (kt & 1) ? Bs0 : Bs1;
            STAGE64(kt + 1, An, Bn);
        }
#pragma unroll
        for (int ks = 0; ks < 2; ks++) {
            int su = (((ks << 2) + quad) ^ (rsel & 7)) << 3;
            frag8 af[4], bfr[2];
#pragma unroll
            for (int i = 0; i < 4; i++)
                af[i] = *(const frag8*)&Ac[(i * 16 + rsel) * 64 + su];
#pragma unroll
            for (int j = 0; j < 2; j++)
                bfr[j] = *(const frag8*)&Bc[(wv * 32 + j * 16 + rsel) * 64 + su];
#pragma unroll
            for (int i = 0; i < 4; i++)
#pragma unroll
                for (int j = 0; j < 2; j++)
                    acc[i * 2 + j] = __builtin_amdgcn_mfma_f32_16x16x32_bf16(
                        af[i], bfr[j], acc[i * 2 + j], 0, 0, 0);
        }
    }
#undef STAGE64
    __syncthreads();

    int r = t >> 2, c0 = (t & 3) * 32;
    {
        // stage A-tile for exact fp32 blend (coalesced)
        const unsigned short* srcA = A + (size_t)(mbase + r) * DD + nbase + c0;
#pragma unroll
        for (int u = 0; u < 4; u++)
            *(uint4*)&tH[r * 136 + c0 + u * 8] = *(const uint4*)(srcA + u * 8);
        __syncthreads();
    }
    float omt = 1.0f - theta;
#pragma unroll
    for (int i = 0; i < 4; i++)
#pragma unroll
        for (int j = 0; j < 2; j++) {
            int cl = wv * 32 + j * 16 + rsel;
            float vv[4];
#pragma unroll
            for (int rr = 0; rr < 4; rr++) {
                int rl = i * 16 + quad * 4 + rr;
                vv[rr] = theta * acc[i * 2 + j][rr] + omt * bf2f(tH[rl * 136 + cl]);
            }
#pragma unroll
            for (int rr = 0; rr < 4; rr++)
                tR[(i * 16 + quad * 4 + rr) * 136 + cl] = f2bf(vv[rr]);
            ushort4 w4;
            w4.x = f2bf(vv[0]); w4.y = f2bf(vv[1]);
            w4.z = f2bf(vv[2]); w4.w = f2bf(vv[3]);
            *(ushort4*)&tT[cl * 72 + i * 16 + quad * 4] = w4;
        }
    __syncthreads();
    {
        unsigned short* dst = oRows + (size_t)(mbase + r) * DD + nbase + c0;
#pragma unroll
        for (int u = 0; u < 4; u++)
            *(uint4*)(dst + u * 8) = *(const uint4*)&tR[r * 136 + c0 + u * 8];
    }
    {
        int c = t >> 1, r0 = (t & 1) * 32;
        unsigned short* dst = oT + (size_t)(nbase + c) * M3 + mbase + r0;
#pragma unroll
        for (int u = 0; u < 4; u++)
            *(uint4*)(dst + u * 8) = *(const uint4*)&tT[c * 72 + r0 + u * 8];
    }
}

// ---------- K4 merged: blocks [0,576): adj1 -> h1; blocks [576,1152): P02 gemm ----------
// adj: h = relu(0.9*(Ad@G + cv1.Gn1 + cv2.Gn2) + 0.1*P0)
// gemm: oR2 = th*(A2@W2) + (1-th)*A2  (rows only)
__global__ __launch_bounds__(256) void k_adjg(
    const float* __restrict__ blk, const float* __restrict__ cross,
    const float* __restrict__ dinv,
    const unsigned short* __restrict__ GT, const unsigned short* __restrict__ Gr,
    const unsigned short* __restrict__ P0, unsigned short* __restrict__ hout,
    const unsigned short* __restrict__ A2, const unsigned short* __restrict__ W2,
    float th, unsigned short* __restrict__ oR2)
{
    __shared__ __align__(16) char smem[53248];
    int b = blockIdx.x;
    int t = threadIdx.x, lane = t & 63, wv = t >> 6;
    int rsel = lane & 15, quad = lane >> 4;

    if (b < 576) {
        // ---- adj flavor (verbatim R8 k_adj, mode 0) ----
        unsigned short* AdL = (unsigned short*)smem;              //  8 KB
        unsigned short* GTL = (unsigned short*)(smem + 8192);     // 16 KB
        unsigned short* OT  = (unsigned short*)(smem + 24576);    // 17 KB
        float* dv = (float*)(smem + 41984);                       // 256 B
        int ch = b & 3, rem = b >> 2;
        int d = rem % N_DIA, m = rem / N_DIA;
        int dbase = d * 64, cbase = ch * 128;

        if (t < 64) dv[t] = dinv[m * NTOT + dbase + t];
        __syncthreads();

        size_t bbase = (size_t)(m * N_DIA + d) * 4096;
#pragma unroll
        for (int q = 0; q < 4; q++) {
            int e4 = t + 256 * q;
            int i = e4 >> 4, j4 = e4 & 15;
            float4 w = *(const float4*)(blk + bbase + (size_t)i * 64 + j4 * 4);
            float di = dv[i];
            ushort4 o;
            o.x = f2bf(w.x * di * dv[j4 * 4 + 0]);
            o.y = f2bf(w.y * di * dv[j4 * 4 + 1]);
            o.z = f2bf(w.z * di * dv[j4 * 4 + 2]);
            o.w = f2bf(w.w * di * dv[j4 * 4 + 3]);
            *(ushort4*)((char*)AdL + i * 128 + (((j4 >> 1) ^ (i & 7)) << 4) + ((j4 & 1) << 3)) = o;
        }
#pragma unroll
        for (int p = 0; p < 4; p++) {
            int e = t + 256 * p;
            int cl = e >> 3;
            int uo = e & 7;
            uint4 w = *(const uint4*)(GT + (size_t)(cbase + cl) * M3 + m * NTOT + dbase + uo * 8);
            *(uint4*)((char*)GTL + cl * 128 + ((uo ^ (cl & 7)) << 4)) = w;
        }
        __syncthreads();

        f32x4 acc[8];
#pragma unroll
        for (int i = 0; i < 8; i++) acc[i] = (f32x4){0.f, 0.f, 0.f, 0.f};
#pragma unroll
        for (int kk = 0; kk < 2; kk++) {
            int su = ((kk * 4 + quad) ^ (rsel & 7)) << 4;
            frag8 bfr[4];
#pragma unroll
            for (int it = 0; it < 4; it++)
                bfr[it] = *(const frag8*)((const char*)AdL + (it * 16 + rsel) * 128 + su);
#pragma unroll
            for (int jc = 0; jc < 2; jc++) {
                frag8 af = *(const frag8*)((const char*)GTL + (wv * 32 + jc * 16 + rsel) * 128 + su);
#pragma unroll
                for (int it = 0; it < 4; it++)
                    acc[jc * 4 + it] = __builtin_amdgcn_mfma_f32_16x16x32_bf16(
                        af, bfr[it], acc[jc * 4 + it], 0, 0, 0);
            }
        }

        int n1, n2, p1, p2;
        if (m == 0)      { n1 = 1; n2 = 2; p1 = 0; p2 = 1; }
        else if (m == 1) { n1 = 0; n2 = 2; p1 = 0; p2 = 2; }
        else             { n1 = 0; n2 = 1; p1 = 1; p2 = 2; }
#pragma unroll
        for (int it = 0; it < 4; it++) {
            int il = it * 16 + rsel;
            int gi = dbase + il;
            float dm = dv[il];
            float cv1 = cross[p1 * NTOT + gi] * dm * dinv[n1 * NTOT + gi];
            float cv2 = cross[p2 * NTOT + gi] * dm * dinv[n2 * NTOT + gi];
            size_t r1 = (size_t)(n1 * NTOT + gi) * DD;
            size_t r2 = (size_t)(n2 * NTOT + gi) * DD;
            size_t r0 = (size_t)(m * NTOT + gi) * DD;
#pragma unroll
            for (int jc = 0; jc < 2; jc++) {
                int cl = wv * 32 + jc * 16 + quad * 4;
                int cg = cbase + cl;
                ushort4 u1 = *(const ushort4*)(Gr + r1 + cg);
                ushort4 u2 = *(const ushort4*)(Gr + r2 + cg);
                ushort4 u0 = *(const ushort4*)(P0 + r0 + cg);
                f32x4 aa = acc[jc * 4 + it];
                ushort4 w;
                w.x = f2bf(fmaxf(0.9f * (aa[0] + cv1 * bf2f(u1.x) + cv2 * bf2f(u2.x)) + 0.1f * bf2f(u0.x), 0.f));
                w.y = f2bf(fmaxf(0.9f * (aa[1] + cv1 * bf2f(u1.y) + cv2 * bf2f(u2.y)) + 0.1f * bf2f(u0.y), 0.f));
                w.z = f2bf(fmaxf(0.9f * (aa[2] + cv1 * bf2f(u1.z) + cv2 * bf2f(u2.z)) + 0.1f * bf2f(u0.z), 0.f));
                w.w = f2bf(fmaxf(0.9f * (aa[3] + cv1 * bf2f(u1.w) + cv2 * bf2f(u2.w)) + 0.1f * bf2f(u0.w), 0.f));
                *(ushort4*)&OT[il * 136 + cl] = w;
            }
        }
        __syncthreads();
        {
            int r = t >> 2, c0 = (t & 3) * 32;
            unsigned short* dst = hout + (size_t)(m * NTOT + dbase + r) * DD + cbase + c0;
#pragma unroll
            for (int u = 0; u < 4; u++)
                *(uint4*)(dst + u * 8) = *(const uint4*)&OT[r * 136 + c0 + u * 8];
        }
        return;
    }

    // ---- P02 gemm flavor: rows-only, BK=64 dbuf (verbatim k_gemm minus oT) ----
    unsigned short* const As0 = (unsigned short*)smem;            // [64][64]  8 KB
    unsigned short* const As1 = (unsigned short*)(smem + 8192);
    unsigned short* const Bs0 = (unsigned short*)(smem + 16384);  // [128][64] 16 KB
    unsigned short* const Bs1 = (unsigned short*)(smem + 32768);
    unsigned short* const tH  = (unsigned short*)smem;            // [64][136]
    unsigned short* const tR  = (unsigned short*)(smem + 17408);  // [64][136]

    int u2 = b - 576;
    int bx = u2 & 3, by = u2 >> 2;
    int mbase = by * 64, nbase = bx * 128;
    int r8 = lane >> 3, u8 = lane & 7;
    int su8 = (u8 ^ r8) << 3;

    const unsigned short* Ag = A2 + (size_t)(mbase + wv * 8 + r8) * DD + su8;
    const unsigned short* Bg = W2 + (size_t)(nbase + wv * 8 + r8) * DD + su8;

    f32x4 acc[8];
#pragma unroll
    for (int i = 0; i < 8; i++) acc[i] = (f32x4){0.f, 0.f, 0.f, 0.f};

#define STAGE64(kt, Asb, Bsb) do { \
    gload16(Ag + (kt) * 64,                    (Asb) + (wv * 8) * 64); \
    gload16(Ag + (size_t)32 * DD + (kt) * 64,  (Asb) + (32 + wv * 8) * 64); \
    gload16(Bg + (kt) * 64,                    (Bsb) + (wv * 8) * 64); \
    gload16(Bg + (size_t)32 * DD + (kt) * 64,  (Bsb) + (32 + wv * 8) * 64); \
    gload16(Bg + (size_t)64 * DD + (kt) * 64,  (Bsb) + (64 + wv * 8) * 64); \
    gload16(Bg + (size_t)96 * DD + (kt) * 64,  (Bsb) + (96 + wv * 8) * 64); \
} while (0)

    STAGE64(0, As0, Bs0);
#pragma unroll
    for (int kt = 0; kt < 8; kt++) {
        __syncthreads();
        const unsigned short* Ac = (kt & 1) ? As1 : As0;
        const unsigned short* Bc = (kt & 1) ? Bs1 : Bs0;
        if (kt < 7) {
            unsigned short* An = (kt & 1) ? As0 : As1;
            unsigned short* Bn = (kt & 1) ? Bs0 : Bs1;
            STAGE64(kt + 1, An, Bn);
        }
#pragma unroll
        for (int ks = 0; ks < 2; ks++) {
            int su = (((ks << 2) + quad) ^ (rsel & 7)) << 3;
            frag8 af[4], bfr[2];
#pragma unroll
            for (int i = 0; i < 4; i++)
                af[i] = *(const frag8*)&Ac[(i * 16 + rsel) * 64 + su];
#pragma unroll
            for (int j = 0; j < 2; j++)
                bfr[j] = *(const frag8*)&Bc[(wv * 32 + j * 16 + rsel) * 64 + su];
#pragma unroll
            for (int i = 0; i < 4; i++)
#pragma unroll
                for (int j = 0; j < 2; j++)
                    acc[i * 2 + j] = __builtin_amdgcn_mfma_f32_16x16x32_bf16(
                        af[i], bfr[j], acc[i * 2 + j], 0, 0, 0);
        }
    }
#undef STAGE64
    __syncthreads();

    int r = t >> 2, c0 = (t & 3) * 32;
    {
        const unsigned short* srcA = A2 + (size_t)(mbase + r) * DD + nbase + c0;
#pragma unroll
        for (int u = 0; u < 4; u++)
            *(uint4*)&tH[r * 136 + c0 + u * 8] = *(const uint4*)(srcA + u * 8);
        __syncthreads();
    }
    float omt = 1.0f - th;
#pragma unroll
    for (int i = 0; i < 4; i++)
#pragma unroll
        for (int j = 0; j < 2; j++) {
            int cl = wv * 32 + j * 16 + rsel;
#pragma unroll
            for (int rr = 0; rr < 4; rr++) {
                int rl = i * 16 + quad * 4 + rr;
                float x = th * acc[i * 2 + j][rr] + omt * bf2f(tH[rl * 136 + cl]);
                tR[rl * 136 + cl] = f2bf(x);
            }
        }
    __syncthreads();
    {
        unsigned short* dst = oR2 + (size_t)(mbase + r) * DD + nbase + c0;
#pragma unroll
        for (int u = 0; u < 4; u++)
            *(uint4*)(dst + u * 8) = *(const uint4*)&tR[r * 136 + c0 + u * 8];
    }
}

// ---------- adj final: out fp32 at [i*3072 + m*1024 + 512 + c] ----------
__global__ __launch_bounds__(256) void k_adj(
    const float* __restrict__ blk, const float* __restrict__ cross,
    const float* __restrict__ dinv,
    const unsigned short* __restrict__ GT, const unsigned short* __restrict__ Gr,
    const unsigned short* __restrict__ P0, float* __restrict__ outF)
{
    __shared__ __align__(16) unsigned short AdL[64 * 64];    //  8 KB swizzled pitch-64
    __shared__ __align__(16) unsigned short GTL[128 * 64];   // 16 KB swizzled pitch-64
    __shared__ float dv[64];
    int ch = blockIdx.x, d = blockIdx.y, m = blockIdx.z;
    int t = threadIdx.x;
    int lane = t & 63, wv = t >> 6;
    int dbase = d * 64, cbase = ch * 128;
    int rsel = lane & 15, quad = lane >> 4;

    if (t < 64) dv[t] = dinv[m * NTOT + dbase + t];
    __syncthreads();

    size_t bbase = (size_t)(m * N_DIA + d) * 4096;
#pragma unroll
    for (int q = 0; q < 4; q++) {
        int e4 = t + 256 * q;
        int i = e4 >> 4, j4 = e4 & 15;
        float4 w = *(const float4*)(blk + bbase + (size_t)i * 64 + j4 * 4);
        float di = dv[i];
        ushort4 o;
        o.x = f2bf(w.x * di * dv[j4 * 4 + 0]);
        o.y = f2bf(w.y * di * dv[j4 * 4 + 1]);
        o.z = f2bf(w.z * di * dv[j4 * 4 + 2]);
        o.w = f2bf(w.w * di * dv[j4 * 4 + 3]);
        *(ushort4*)((char*)AdL + i * 128 + (((j4 >> 1) ^ (i & 7)) << 4) + ((j4 & 1) << 3)) = o;
    }
#pragma unroll
    for (int p = 0; p < 4; p++) {
        int e = t + 256 * p;
        int cl = e >> 3;
        int uo = e & 7;
        uint4 w = *(const uint4*)(GT + (size_t)(cbase + cl) * M3 + m * NTOT + dbase + uo * 8);
        *(uint4*)((char*)GTL + cl * 128 + ((uo ^ (cl & 7)) << 4)) = w;
    }
    __syncthreads();

    f32x4 acc[8];
#pragma unroll
    for (int i = 0; i < 8; i++) acc[i] = (f32x4){0.f, 0.f, 0.f, 0.f};
#pragma unroll
    for (int kk = 0; kk < 2; kk++) {
        int su = ((kk * 4 + quad) ^ (rsel & 7)) << 4;
        frag8 bfr[4];
#pragma unroll
        for (int it = 0; it < 4; it++)
            bfr[it] = *(const frag8*)((const char*)AdL + (it * 16 + rsel) * 128 + su);
#pragma unroll
        for (int jc = 0; jc < 2; jc++) {
            frag8 af = *(const frag8*)((const char*)GTL + (wv * 32 + jc * 16 + rsel) * 128 + su);
#pragma unroll
            for (int it = 0; it < 4; it++)
                acc[jc * 4 + it] = __builtin_amdgcn_mfma_f32_16x16x32_bf16(
                    af, bfr[it], acc[jc * 4 + it], 0, 0, 0);
        }
    }

    int n1, n2, p1, p2;
    if (m == 0)      { n1 = 1; n2 = 2; p1 = 0; p2 = 1; }
    else if (m == 1) { n1 = 0; n2 = 2; p1 = 0; p2 = 2; }
    else             { n1 = 0; n2 = 1; p1 = 1; p2 = 2; }
#pragma unroll
    for (int it = 0; it < 4; it++) {
        int il = it * 16 + rsel;
        int gi = dbase + il;
        float dm = dv[il];
        float cv1 = cross[p1 * NTOT + gi] * dm * dinv[n1 * NTOT + gi];
        float cv2 = cross[p2 * NTOT + gi] * dm * dinv[n2 * NTOT + gi];
        size_t r1 = (size_t)(n1 * NTOT + gi) * DD;
        size_t r2 = (size_t)(n2 * NTOT + gi) * DD;
        size_t r0 = (size_t)(m * NTOT + gi) * DD;
#pragma unroll
        for (int jc = 0; jc < 2; jc++) {
            int cl = wv * 32 + jc * 16 + quad * 4;
            int cg = cbase + cl;
            ushort4 u1 = *(const ushort4*)(Gr + r1 + cg);
            ushort4 u2 = *(const ushort4*)(Gr + r2 + cg);
            ushort4 u0 = *(const ushort4*)(P0 + r0 + cg);
            f32x4 aa = acc[jc * 4 + it];
            float o0 = fmaxf(0.9f * (aa[0] + cv1 * bf2f(u1.x) + cv2 * bf2f(u2.x)) + 0.1f * bf2f(u0.x), 0.f);
            float o1 = fmaxf(0.9f * (aa[1] + cv1 * bf2f(u1.y) + cv2 * bf2f(u2.y)) + 0.1f * bf2f(u0.y), 0.f);
            float o2 = fmaxf(0.9f * (aa[2] + cv1 * bf2f(u1.z) + cv2 * bf2f(u2.z)) + 0.1f * bf2f(u0.z), 0.f);
            float o3 = fmaxf(0.9f * (aa[3] + cv1 * bf2f(u1.w) + cv2 * bf2f(u2.w)) + 0.1f * bf2f(u0.w), 0.f);
            *(float4*)(outF + (size_t)gi * 3072 + m * 1024 + 512 + cg) =
                make_float4(o0, o1, o2, o3);
        }
    }
}

extern "C" void kernel_launch(void* const* d_in, const int* in_sizes, int n_in,
                              void* d_out, int out_size, void* d_ws, size_t ws_size,
                              hipStream_t stream) {
    (void)in_sizes; (void)n_in; (void)out_size; (void)ws_size;
    const float* a     = (const float*)d_in[0];
    const float* v     = (const float*)d_in[1];
    const float* l     = (const float*)d_in[2];
    const float* qmask = (const float*)d_in[3];
    const float* Wspk  = (const float*)d_in[5];
    const float* W0    = (const float*)d_in[6];
    const float* b0    = (const float*)d_in[7];
    const float* Wg    = (const float*)d_in[8];
    float* out = (float*)d_out;
    float* ws = (float*)d_ws;

    float* invn  = ws;                                  // M3
    float* blk   = invn + M3;                           // 3*48*4096
    float* cross = blk + (size_t)3 * N_DIA * 4096;      // M3
    float* dinvp = cross + M3;                          // M3
    unsigned short* Wt  = (unsigned short*)(dinvp + M3);   // 3*DD*DD
    unsigned short* xb  = Wt + (size_t)3 * DD * DD;        // 3*SEG
    unsigned short* h0  = xb  + 3 * SEG;                   // 3*SEG
    unsigned short* G1r = h0  + 3 * SEG;                   // 3*SEG
    unsigned short* G1T = G1r + 3 * SEG;                   // 3*SEG
    unsigned short* h1  = G1T + 3 * SEG;                   // 3*SEG
    // lifetime aliases (ws footprint identical to verified rounds 2/4/7/8):
    unsigned short* P02 = xb;    // xb dead after k_g0_gram; P02 born in k_adjg
    unsigned short* G2r = G1r;   // G1r dead after k_adjg (adj1 reads Gr/P0=G1r)
    unsigned short* G2T = G1T;   // G1T dead after k_adjg (adj1 reads GT=G1T)

    const float th1 = 0.40546510810816438f;  // log(1.5)
    const float th2 = 0.22314355131420976f;  // log(1.25)

    k_pre_wt<<<1536, 256, 0, stream>>>(a, v, l, qmask, Wspk, W0, Wg, out, xb, invn, cross, Wt);
    // merged: gram (blocks 0..143) + h0 gemm (blocks 144..719)
    k_g0_gram<<<720, 256, 0, stream>>>(xb, Wt, b0, h0, invn, cross, blk, dinvp);
    // G1 = th1*(h0@W1) + (1-th1)*h0  (rows + transposed)
    k_gemm<<<dim3(4, 144), 256, 0, stream>>>(h0, Wt + (size_t)DD * DD, G1r, G1T, th1);
    // merged: h1 = relu(0.9*(Ad@G1 + cross) + 0.1*G1) (blocks 0..575)
    //       + P02 = th2*(h0@W2) + (1-th2)*h0          (blocks 576..1151)
    k_adjg<<<1152, 256, 0, stream>>>(blk, cross, dinvp, G1T, G1r, G1r, h1,
                                     h0, Wt + (size_t)2 * DD * DD, th2, P02);
    // G2 = th2*(h1@W2) + (1-th2)*h1 (rows + transposed)
    k_gemm<<<dim3(4, 144), 256, 0, stream>>>(h1, Wt + (size_t)2 * DD * DD, G2r, G2T, th2);
    // out_h = relu(0.9*(Ad@G2 + cross) + 0.1*P02) -> fp32 output
    k_adj<<<dim3(4, N_DIA, 3), 256, 0, stream>>>(blk, cross, dinvp, G2T, G2r, P02, out);
}

// Round 11
// 179.943 us; speedup vs baseline: 1.3345x; 1.0194x over previous
//
#include <hip/hip_runtime.h>
#include <math.h>

#define N_DIA 48
#define NTOT  3072     // N utterances
#define DD    512      // D == H
#define M3    9216     // 3N
#define SEG   ((size_t)NTOT * DD)

#define SCALE_F 0.99999f
#define PI_F    3.14159274101257324f

typedef __attribute__((ext_vector_type(8))) short frag8;
typedef __attribute__((ext_vector_type(4))) float f32x4;

__device__ __forceinline__ float ang_sim(float cs) {
    float cc = cs * SCALE_F;
    cc = fminf(fmaxf(cc, -SCALE_F), SCALE_F);
    return 1.0f - acosf(cc) / PI_F;
}
__device__ __forceinline__ unsigned short f2bf(float x) {
    union { float f; unsigned int u; } c; c.f = x;
    unsigned int r = c.u + 0x7fffu + ((c.u >> 16) & 1u);
    return (unsigned short)(r >> 16);
}
__device__ __forceinline__ float bf2f(unsigned short h) {
    union { unsigned int u; float f; } c; c.u = ((unsigned int)h) << 16;
    return c.f;
}
__device__ __forceinline__ void gload16(const unsigned short* g, unsigned short* s) {
    __builtin_amdgcn_global_load_lds(
        (const __attribute__((address_space(1))) unsigned int*)g,
        (__attribute__((address_space(3))) unsigned int*)s, 16, 0, 0);
}

// ---------- K_pre_wt: (blocks 0..767) per-utterance pre; (768..1535) W -> bf16 [n][k] ----------
__global__ __launch_bounds__(256) void k_pre_wt(
    const float* __restrict__ a, const float* __restrict__ v,
    const float* __restrict__ l, const float* __restrict__ qmask,
    const float* __restrict__ Wspk, const float* __restrict__ W0,
    const float* __restrict__ Wg,
    float* __restrict__ out, unsigned short* __restrict__ xb,
    float* __restrict__ invn, float* __restrict__ cross,
    unsigned short* __restrict__ Wt)
{
    __shared__ float tile[32][33];
    int b = blockIdx.x;
    if (b < 768) {
        int wv = threadIdx.x >> 6, t = threadIdx.x & 63;
        int i = b * 4 + wv;                 // utterance, one wave each
        int pos = i & 63, dia = i >> 6;
        int qb = (pos * N_DIA + dia) * 2;
        float q0 = qmask[qb], q1 = qmask[qb + 1];
        int spk = (q0 >= q1) ? 0 : 1;
        const float4* av4 = (const float4*)(a + (size_t)i * DD);
        const float4* vv4 = (const float4*)(v + (size_t)i * DD);
        const float4* lv4 = (const float4*)(l + (size_t)i * DD);
        const float4* wv4 = (const float4*)(Wspk + (size_t)spk * DD);
        float* ob = out + (size_t)i * 3072;
        float saa = 0, svv = 0, sll = 0, sav = 0, sal = 0, svl = 0;
#pragma unroll
        for (int e = 0; e < 2; e++) {
            int idx = e * 64 + t;           // fully coalesced: lane-major
            float4 xa = av4[idx], xv = vv4[idx], xd = lv4[idx], xw = wv4[idx];
            float4 xL = make_float4(xd.x + xw.x, xd.y + xw.y, xd.z + xw.z, xd.w + xw.w);
            *(float4*)(ob + idx * 4)        = xa;
            *(float4*)(ob + 1024 + idx * 4) = xv;
            *(float4*)(ob + 2048 + idx * 4) = xL;
            ushort4 ya, yv, yl;
            ya.x = f2bf(xa.x); ya.y = f2bf(xa.y); ya.z = f2bf(xa.z); ya.w = f2bf(xa.w);
            yv.x = f2bf(xv.x); yv.y = f2bf(xv.y); yv.z = f2bf(xv.z); yv.w = f2bf(xv.w);
            yl.x = f2bf(xL.x); yl.y = f2bf(xL.y); yl.z = f2bf(xL.z); yl.w = f2bf(xL.w);
            *(ushort4*)(xb + (size_t)i * DD + idx * 4) = ya;
            *(ushort4*)(xb + SEG + (size_t)i * DD + idx * 4) = yv;
            *(ushort4*)(xb + 2 * SEG + (size_t)i * DD + idx * 4) = yl;
            saa += xa.x * xa.x + xa.y * xa.y + xa.z * xa.z + xa.w * xa.w;
            svv += xv.x * xv.x + xv.y * xv.y + xv.z * xv.z + xv.w * xv.w;
            sll += xL.x * xL.x + xL.y * xL.y + xL.z * xL.z + xL.w * xL.w;
            sav += xa.x * xv.x + xa.y * xv.y + xa.z * xv.z + xa.w * xv.w;
            sal += xa.x * xL.x + xa.y * xL.y + xa.z * xL.z + xa.w * xL.w;
            svl += xv.x * xL.x + xv.y * xL.y + xv.z * xL.z + xv.w * xL.w;
        }
#pragma unroll
        for (int off = 32; off; off >>= 1) {
            saa += __shfl_down(saa, off, 64);
            svv += __shfl_down(svv, off, 64);
            sll += __shfl_down(sll, off, 64);
            sav += __shfl_down(sav, off, 64);
            sal += __shfl_down(sal, off, 64);
            svl += __shfl_down(svl, off, 64);
        }
        if (t == 0) {
            float ina = 1.0f / sqrtf(saa);
            float inv_ = 1.0f / sqrtf(svv);
            float inl = 1.0f / sqrtf(sll);
            invn[i] = ina; invn[NTOT + i] = inv_; invn[2 * NTOT + i] = inl;
            cross[i]            = ang_sim(sav * ina * inv_);
            cross[NTOT + i]     = ang_sim(sal * ina * inl);
            cross[2 * NTOT + i] = ang_sim(svl * inv_ * inl);
        }
    } else {
        int idx = b - 768;
        int mm = idx >> 8;
        int by = (idx >> 4) & 15, bx = idx & 15;
        const float* W = (mm == 0) ? W0 : Wg + (size_t)(mm - 1) * DD * DD;
        int t = threadIdx.x, tx = t & 31, ty = t >> 5;
#pragma unroll
        for (int q = 0; q < 4; q++) {
            int k = by * 32 + ty + q * 8;
            tile[ty + q * 8][tx] = W[(size_t)k * DD + bx * 32 + tx];
        }
        __syncthreads();
#pragma unroll
        for (int q = 0; q < 4; q++) {
            int n = bx * 32 + ty + q * 8;
            Wt[(size_t)mm * DD * DD + (size_t)n * DD + by * 32 + tx] = f2bf(tile[tx][ty + q * 8]);
        }
    }
}

// ---------- K2 merged: blocks [0,144): gram (two-phase K-split)
//            blocks [144,720): gemm0 h0 = relu(xb@W0+b0) -> h0 rows + h0T ----------
__global__ __launch_bounds__(256) void k_g0_gram(
    const unsigned short* __restrict__ xb, const unsigned short* __restrict__ Wt,
    const float* __restrict__ bias, unsigned short* __restrict__ h0,
    unsigned short* __restrict__ h0T,
    const float* __restrict__ invn, const float* __restrict__ cross,
    float* __restrict__ blk, float* __restrict__ dinv)
{
    __shared__ __align__(16) char smem[53248];
    int b = blockIdx.x;
    int t = threadIdx.x, lane = t & 63, wv = t >> 6;
    int rsel = lane & 15, quad = lane >> 4;

    if (b < 144) {
        // ---- gram flavor: two-phase K-split (c 0..7, then 8..15), acc order preserved ----
        unsigned short* Xs = (unsigned short*)smem;          // 8 c-tiles x [64][32] = 32 KB
        int d = b % N_DIA, m = b / N_DIA;
        int mrow = m * NTOT + d * 64;
        const unsigned short* src = xb + (size_t)mrow * DD;
        int sunit = ((t & 3) ^ ((t >> 2) & 3)) * 8;          // source pre-swizzle
        int sq = (quad ^ (rsel & 3)) * 8;                    // swizzled read unit
        f32x4 acc[4];
#pragma unroll
        for (int j = 0; j < 4; j++) acc[j] = (f32x4){0.f, 0.f, 0.f, 0.f};
#pragma unroll
        for (int p = 0; p < 2; p++) {
            if (p) __syncthreads();                          // phase-0 reads done
#pragma unroll
            for (int c = 0; c < 8; c++) {
                gload16(src + (size_t)(t >> 2) * DD + (p * 8 + c) * 32 + sunit,
                        &Xs[c * 2048 + wv * 512]);
            }
            __syncthreads();
#pragma unroll
            for (int c = 0; c < 8; c++) {
                const unsigned short* base = &Xs[c * 2048];
                frag8 bf[4];
#pragma unroll
                for (int j = 0; j < 4; j++)
                    bf[j] = *(const frag8*)&base[(j * 16 + rsel) * 32 + sq];
                frag8 af = *(const frag8*)&base[(wv * 16 + rsel) * 32 + sq];
#pragma unroll
                for (int j = 0; j < 4; j++)
                    acc[j] = __builtin_amdgcn_mfma_f32_16x16x32_bf16(af, bf[j], acc[j], 0, 0, 0);
            }
        }

        size_t bbase = (size_t)(m * N_DIA + d) * 4096;
        int rowl0 = wv * 16 + quad * 4;
        float ir[4], rs[4] = {0.f, 0.f, 0.f, 0.f};
#pragma unroll
        for (int r = 0; r < 4; r++) ir[r] = invn[mrow + rowl0 + r];
#pragma unroll
        for (int j = 0; j < 4; j++) {
            int coll = j * 16 + rsel;
            float ic = invn[mrow + coll];
#pragma unroll
            for (int r = 0; r < 4; r++) {
                float sim = ang_sim(acc[j][r] * ir[r] * ic);
                blk[bbase + (size_t)(rowl0 + r) * 64 + coll] = sim;
                rs[r] += sim;
            }
        }
#pragma unroll
        for (int off = 8; off; off >>= 1)
#pragma unroll
            for (int r = 0; r < 4; r++) rs[r] += __shfl_down(rs[r], off, 16);
        if (rsel == 0) {
#pragma unroll
            for (int r = 0; r < 4; r++) {
                int gi = d * 64 + rowl0 + r;
                float c1, c2;
                if (m == 0)      { c1 = cross[gi];        c2 = cross[NTOT + gi]; }
                else if (m == 1) { c1 = cross[gi];        c2 = cross[2 * NTOT + gi]; }
                else             { c1 = cross[NTOT + gi]; c2 = cross[2 * NTOT + gi]; }
                dinv[m * NTOT + gi] = 1.0f / sqrtf(rs[r] + c1 + c2);
            }
        }
        return;
    }

    // ---- gemm0 flavor (BK=64, 8 barriers); emits rows + transposed ----
    unsigned short* const As0 = (unsigned short*)smem;            // [64][64]  8 KB
    unsigned short* const As1 = (unsigned short*)(smem + 8192);
    unsigned short* const Bs0 = (unsigned short*)(smem + 16384);  // [128][64] 16 KB
    unsigned short* const Bs1 = (unsigned short*)(smem + 32768);
    unsigned short* const tR  = (unsigned short*)(smem + 17408);  // [64][136] epilogue overlay
    unsigned short* const tT  = (unsigned short*)(smem + 34816);  // [128][72]

    int b2 = b - 144;
    int bx = b2 & 3, by = b2 >> 2;
    int mbase = by * 64, nbase = bx * 128;
    int r8 = lane >> 3, u8 = lane & 7;
    int su8 = (u8 ^ r8) << 3;                  // source pre-swizzle (elements)

    const unsigned short* Ag = xb + (size_t)(mbase + wv * 8 + r8) * DD + su8;
    const unsigned short* Bg = Wt + (size_t)(nbase + wv * 8 + r8) * DD + su8;

    f32x4 acc[8];
#pragma unroll
    for (int i = 0; i < 8; i++) acc[i] = (f32x4){0.f, 0.f, 0.f, 0.f};

#define STAGE64(kt, Asb, Bsb) do { \
    gload16(Ag + (kt) * 64,                    (Asb) + (wv * 8) * 64); \
    gload16(Ag + (size_t)32 * DD + (kt) * 64,  (Asb) + (32 + wv * 8) * 64); \
    gload16(Bg + (kt) * 64,                    (Bsb) + (wv * 8) * 64); \
    gload16(Bg + (size_t)32 * DD + (kt) * 64,  (Bsb) + (32 + wv * 8) * 64); \
    gload16(Bg + (size_t)64 * DD + (kt) * 64,  (Bsb) + (64 + wv * 8) * 64); \
    gload16(Bg + (size_t)96 * DD + (kt) * 64,  (Bsb) + (96 + wv * 8) * 64); \
} while (0)

    STAGE64(0, As0, Bs0);
#pragma unroll
    for (int kt = 0; kt < 8; kt++) {
        __syncthreads();
        const unsigned short* Ac = (kt & 1) ? As1 : As0;
        const unsigned short* Bc = (kt & 1) ? Bs1 : Bs0;
        if (kt < 7) {
            unsigned short* An = (kt & 1) ? As0 : As1;
            unsigned short* Bn = (kt & 1) ? Bs0 : Bs1;
            STAGE64(kt + 1, An, Bn);
        }
#pragma unroll
        for (int ks = 0; ks < 2; ks++) {
            int su = (((ks << 2) + quad) ^ (rsel & 7)) << 3;
            frag8 af[4], bfr[2];
#pragma unroll
            for (int i = 0; i < 4; i++)
                af[i] = *(const frag8*)&Ac[(i * 16 + rsel) * 64 + su];
#pragma unroll
            for (int j = 0; j < 2; j++)
                bfr[j] = *(const frag8*)&Bc[(wv * 32 + j * 16 + rsel) * 64 + su];
#pragma unroll
            for (int i = 0; i < 4; i++)
#pragma unroll
                for (int j = 0; j < 2; j++)
                    acc[i * 2 + j] = __builtin_amdgcn_mfma_f32_16x16x32_bf16(
                        af[i], bfr[j], acc[i * 2 + j], 0, 0, 0);
        }
    }
#undef STAGE64
    __syncthreads();

#pragma unroll
    for (int i = 0; i < 4; i++)
#pragma unroll
        for (int j = 0; j < 2; j++) {
            int cl = wv * 32 + j * 16 + rsel;
            float bv = bias[nbase + cl];
            float vv[4];
#pragma unroll
            for (int rr = 0; rr < 4; rr++)
                vv[rr] = fmaxf(acc[i * 2 + j][rr] + bv, 0.f);
#pragma unroll
            for (int rr = 0; rr < 4; rr++)
                tR[(i * 16 + quad * 4 + rr) * 136 + cl] = f2bf(vv[rr]);
            ushort4 w4;
            w4.x = f2bf(vv[0]); w4.y = f2bf(vv[1]);
            w4.z = f2bf(vv[2]); w4.w = f2bf(vv[3]);
            *(ushort4*)&tT[cl * 72 + i * 16 + quad * 4] = w4;
        }
    __syncthreads();
    {
        int r = t >> 2, c0 = (t & 3) * 32;
        unsigned short* dst = h0 + (size_t)(mbase + r) * DD + nbase + c0;
#pragma unroll
        for (int u = 0; u < 4; u++)
            *(uint4*)(dst + u * 8) = *(const uint4*)&tR[r * 136 + c0 + u * 8];
    }
    {
        int c = t >> 1, r0 = (t & 1) * 32;
        unsigned short* dst = h0T + (size_t)(nbase + c) * M3 + mbase + r0;
#pragma unroll
        for (int u = 0; u < 4; u++)
            *(uint4*)(dst + u * 8) = *(const uint4*)&tT[c * 72 + r0 + u * 8];
    }
}

// ---------- adjS: S = 0.9*(Ad@G + cv1.Gn1 + cv2.Gn2) + 0.1*P0  (bf16 rows, NO relu) ----------
// 128-col chunks: grid (4, N_DIA, 3) = 576 blocks
__global__ __launch_bounds__(256) void k_adjS(
    const float* __restrict__ blk, const float* __restrict__ cross,
    const float* __restrict__ dinv,
    const unsigned short* __restrict__ GT, const unsigned short* __restrict__ Gr,
    const unsigned short* __restrict__ P0, unsigned short* __restrict__ Sout)
{
    __shared__ __align__(16) unsigned short AdL[64 * 64];    //  8 KB swizzled pitch-64
    __shared__ __align__(16) unsigned short GTL[128 * 64];   // 16 KB swizzled pitch-64
    __shared__ __align__(16) unsigned short OT[64 * 136];    // 17 KB out tile
    __shared__ float dv[64];
    int ch = blockIdx.x, d = blockIdx.y, m = blockIdx.z;
    int t = threadIdx.x;
    int lane = t & 63, wv = t >> 6;
    int dbase = d * 64, cbase = ch * 128;
    int rsel = lane & 15, quad = lane >> 4;

    if (t < 64) dv[t] = dinv[m * NTOT + dbase + t];
    __syncthreads();

    size_t bbase = (size_t)(m * N_DIA + d) * 4096;
#pragma unroll
    for (int q = 0; q < 4; q++) {
        int e4 = t + 256 * q;
        int i = e4 >> 4, j4 = e4 & 15;
        float4 w = *(const float4*)(blk + bbase + (size_t)i * 64 + j4 * 4);
        float di = dv[i];
        ushort4 o;
        o.x = f2bf(w.x * di * dv[j4 * 4 + 0]);
        o.y = f2bf(w.y * di * dv[j4 * 4 + 1]);
        o.z = f2bf(w.z * di * dv[j4 * 4 + 2]);
        o.w = f2bf(w.w * di * dv[j4 * 4 + 3]);
        *(ushort4*)((char*)AdL + i * 128 + (((j4 >> 1) ^ (i & 7)) << 4) + ((j4 & 1) << 3)) = o;
    }
#pragma unroll
    for (int p = 0; p < 4; p++) {
        int e = t + 256 * p;
        int cl = e >> 3;
        int uo = e & 7;
        uint4 w = *(const uint4*)(GT + (size_t)(cbase + cl) * M3 + m * NTOT + dbase + uo * 8);
        *(uint4*)((char*)GTL + cl * 128 + ((uo ^ (cl & 7)) << 4)) = w;
    }
    __syncthreads();

    f32x4 acc[8];
#pragma unroll
    for (int i = 0; i < 8; i++) acc[i] = (f32x4){0.f, 0.f, 0.f, 0.f};
#pragma unroll
    for (int kk = 0; kk < 2; kk++) {
        int su = ((kk * 4 + quad) ^ (rsel & 7)) << 4;
        frag8 bfr[4];
#pragma unroll
        for (int it = 0; it < 4; it++)
            bfr[it] = *(const frag8*)((const char*)AdL + (it * 16 + rsel) * 128 + su);
#pragma unroll
        for (int jc = 0; jc < 2; jc++) {
            frag8 af = *(const frag8*)((const char*)GTL + (wv * 32 + jc * 16 + rsel) * 128 + su);
#pragma unroll
            for (int it = 0; it < 4; it++)
                acc[jc * 4 + it] = __builtin_amdgcn_mfma_f32_16x16x32_bf16(
                    af, bfr[it], acc[jc * 4 + it], 0, 0, 0);
        }
    }

    int n1, n2, p1, p2;
    if (m == 0)      { n1 = 1; n2 = 2; p1 = 0; p2 = 1; }
    else if (m == 1) { n1 = 0; n2 = 2; p1 = 0; p2 = 2; }
    else             { n1 = 0; n2 = 1; p1 = 1; p2 = 2; }
#pragma unroll
    for (int it = 0; it < 4; it++) {
        int il = it * 16 + rsel;
        int gi = dbase + il;
        float dm = dv[il];
        float cv1 = cross[p1 * NTOT + gi] * dm * dinv[n1 * NTOT + gi];
        float cv2 = cross[p2 * NTOT + gi] * dm * dinv[n2 * NTOT + gi];
        size_t r1 = (size_t)(n1 * NTOT + gi) * DD;
        size_t r2 = (size_t)(n2 * NTOT + gi) * DD;
        size_t r0 = (size_t)(m * NTOT + gi) * DD;
#pragma unroll
        for (int jc = 0; jc < 2; jc++) {
            int cl = wv * 32 + jc * 16 + quad * 4;
            int cg = cbase + cl;
            ushort4 u1 = *(const ushort4*)(Gr + r1 + cg);
            ushort4 u2 = *(const ushort4*)(Gr + r2 + cg);
            ushort4 u0 = *(const ushort4*)(P0 + r0 + cg);
            f32x4 aa = acc[jc * 4 + it];
            ushort4 w;
            w.x = f2bf(0.9f * (aa[0] + cv1 * bf2f(u1.x) + cv2 * bf2f(u2.x)) + 0.1f * bf2f(u0.x));
            w.y = f2bf(0.9f * (aa[1] + cv1 * bf2f(u1.y) + cv2 * bf2f(u2.y)) + 0.1f * bf2f(u0.y));
            w.z = f2bf(0.9f * (aa[2] + cv1 * bf2f(u1.z) + cv2 * bf2f(u2.z)) + 0.1f * bf2f(u0.z));
            w.w = f2bf(0.9f * (aa[3] + cv1 * bf2f(u1.w) + cv2 * bf2f(u2.w)) + 0.1f * bf2f(u0.w));
            *(ushort4*)&OT[il * 136 + cl] = w;
        }
    }
    __syncthreads();
    {
        int r = t >> 2, c0 = (t & 3) * 32;
        unsigned short* dst = Sout + (size_t)(m * NTOT + dbase + r) * DD + cbase + c0;
#pragma unroll
        for (int u = 0; u < 4; u++)
            *(uint4*)(dst + u * 8) = *(const uint4*)&OT[r * 136 + c0 + u * 8];
    }
}

// ---------- GEMM: h = relu(theta*(S@W) + (1-theta)*S), BK=64 dbuf ----------
// outF==nullptr: write bf16 rows (oRows) + transposed (oT)
// outF!=nullptr: write fp32 to out at [i*3072 + m*1024 + 512 + col]
__global__ __launch_bounds__(256) void k_gemm_s(
    const unsigned short* __restrict__ A, const unsigned short* __restrict__ W,
    unsigned short* __restrict__ oRows, unsigned short* __restrict__ oT,
    float theta, float* __restrict__ outF)
{
    __shared__ __align__(16) char smem[53248];
    unsigned short* const As0 = (unsigned short*)smem;            // [64][64]  8 KB
    unsigned short* const As1 = (unsigned short*)(smem + 8192);
    unsigned short* const Bs0 = (unsigned short*)(smem + 16384);  // [128][64] 16 KB
    unsigned short* const Bs1 = (unsigned short*)(smem + 32768);
    unsigned short* const tH  = (unsigned short*)smem;            // [64][136] (epilogue overlay)
    unsigned short* const tR  = (unsigned short*)(smem + 17408);  // [64][136]
    unsigned short* const tT  = (unsigned short*)(smem + 34816);  // [128][72]
    float* const tF           = (float*)(smem + 17408);           // [64][132] fp32 (outF mode)

    int t = threadIdx.x, lane = t & 63, wv = t >> 6;
    int bx = blockIdx.x, by = blockIdx.y;
    int mbase = by * 64, nbase = bx * 128;
    int rsel = lane & 15, quad = lane >> 4;
    int r8 = lane >> 3, u8 = lane & 7;
    int su8 = (u8 ^ r8) << 3;

    const unsigned short* Ag = A + (size_t)(mbase + wv * 8 + r8) * DD + su8;
    const unsigned short* Bg = W + (size_t)(nbase + wv * 8 + r8) * DD + su8;

    f32x4 acc[8];
#pragma unroll
    for (int i = 0; i < 8; i++) acc[i] = (f32x4){0.f, 0.f, 0.f, 0.f};

#define STAGE64(kt, Asb, Bsb) do { \
    gload16(Ag + (kt) * 64,                    (Asb) + (wv * 8) * 64); \
    gload16(Ag + (size_t)32 * DD + (kt) * 64,  (Asb) + (32 + wv * 8) * 64); \
    gload16(Bg + (kt) * 64,                    (Bsb) + (wv * 8) * 64); \
    gload16(Bg + (size_t)32 * DD + (kt) * 64,  (Bsb) + (32 + wv * 8) * 64); \
    gload16(Bg + (size_t)64 * DD + (kt) * 64,  (Bsb) + (64 + wv * 8) * 64); \
    gload16(Bg + (size_t)96 * DD + (kt) * 64,  (Bsb) + (96 + wv * 8) * 64); \
} while (0)

    STAGE64(0, As0, Bs0);
#pragma unroll
    for (int kt = 0; kt < 8; kt++) {
        __syncthreads();
        const unsigned short* Ac = (kt & 1) ? As1 : As0;
        const unsigned short* Bc = (kt & 1) ? Bs1 : Bs0;
        if (kt < 7) {
            unsigned short* An = (kt & 1) ? As0 : As1;
            unsigned short* Bn = (kt & 1) ? Bs0 : Bs1;
            STAGE64(kt + 1, An, Bn);
        }
#pragma unroll
        for (int ks = 0; ks < 2; ks++) {
            int su = (((ks << 2) + quad) ^ (rsel & 7)) << 3;
            frag8 af[4], bfr[2];
#pragma unroll
            for (int i = 0; i < 4; i++)
                af[i] = *(const frag8*)&Ac[(i * 16 + rsel) * 64 + su];
#pragma unroll
            for (int j = 0; j < 2; j++)
                bfr[j] = *(const frag8*)&Bc[(wv * 32 + j * 16 + rsel) * 64 + su];
#pragma unroll
            for (int i = 0; i < 4; i++)
#pragma unroll
                for (int j = 0; j < 2; j++)
                    acc[i * 2 + j] = __builtin_amdgcn_mfma_f32_16x16x32_bf16(
                        af[i], bfr[j], acc[i * 2 + j], 0, 0, 0);
        }
    }
#undef STAGE64
    __syncthreads();

    int r = t >> 2, c0 = (t & 3) * 32;
    {
        // stage A-tile for exact fp32 blend (coalesced)
        const unsigned short* srcA = A + (size_t)(mbase + r) * DD + nbase + c0;
#pragma unroll
        for (int u = 0; u < 4; u++)
            *(uint4*)&tH[r * 136 + c0 + u * 8] = *(const uint4*)(srcA + u * 8);
        __syncthreads();
    }
    float omt = 1.0f - theta;
    if (outF == nullptr) {
#pragma unroll
        for (int i = 0; i < 4; i++)
#pragma unroll
            for (int j = 0; j < 2; j++) {
                int cl = wv * 32 + j * 16 + rsel;
                float vv[4];
#pragma unroll
                for (int rr = 0; rr < 4; rr++) {
                    int rl = i * 16 + quad * 4 + rr;
                    vv[rr] = fmaxf(theta * acc[i * 2 + j][rr] + omt * bf2f(tH[rl * 136 + cl]), 0.f);
                }
#pragma unroll
                for (int rr = 0; rr < 4; rr++)
                    tR[(i * 16 + quad * 4 + rr) * 136 + cl] = f2bf(vv[rr]);
                ushort4 w4;
                w4.x = f2bf(vv[0]); w4.y = f2bf(vv[1]);
                w4.z = f2bf(vv[2]); w4.w = f2bf(vv[3]);
                *(ushort4*)&tT[cl * 72 + i * 16 + quad * 4] = w4;
            }
        __syncthreads();
        {
            unsigned short* dst = oRows + (size_t)(mbase + r) * DD + nbase + c0;
#pragma unroll
            for (int u = 0; u < 4; u++)
                *(uint4*)(dst + u * 8) = *(const uint4*)&tR[r * 136 + c0 + u * 8];
        }
        {
            int c = t >> 1, r0 = (t & 1) * 32;
            unsigned short* dst = oT + (size_t)(nbase + c) * M3 + mbase + r0;
#pragma unroll
            for (int u = 0; u < 4; u++)
                *(uint4*)(dst + u * 8) = *(const uint4*)&tT[c * 72 + r0 + u * 8];
        }
    } else {
#pragma unroll
        for (int i = 0; i < 4; i++)
#pragma unroll
            for (int j = 0; j < 2; j++) {
                int cl = wv * 32 + j * 16 + rsel;
#pragma unroll
                for (int rr = 0; rr < 4; rr++) {
                    int rl = i * 16 + quad * 4 + rr;
                    tF[rl * 132 + cl] = fmaxf(theta * acc[i * 2 + j][rr]
                                              + omt * bf2f(tH[rl * 136 + cl]), 0.f);
                }
            }
        __syncthreads();
        int mq = mbase / NTOT;
        int iu0 = mbase - mq * NTOT;
        float* dst = outF + (size_t)(iu0 + r) * 3072 + mq * 1024 + 512 + nbase + c0;
#pragma unroll
        for (int u = 0; u < 8; u++)
            *(float4*)(dst + u * 4) = *(const float4*)&tF[r * 132 + c0 + u * 4];
    }
}

extern "C" void kernel_launch(void* const* d_in, const int* in_sizes, int n_in,
                              void* d_out, int out_size, void* d_ws, size_t ws_size,
                              hipStream_t stream) {
    (void)in_sizes; (void)n_in; (void)out_size; (void)ws_size;
    const float* a     = (const float*)d_in[0];
    const float* v     = (const float*)d_in[1];
    const float* l     = (const float*)d_in[2];
    const float* qmask = (const float*)d_in[3];
    const float* Wspk  = (const float*)d_in[5];
    const float* W0    = (const float*)d_in[6];
    const float* b0    = (const float*)d_in[7];
    const float* Wg    = (const float*)d_in[8];
    float* out = (float*)d_out;
    float* ws = (float*)d_ws;

    float* invn  = ws;                                  // M3
    float* blk   = invn + M3;                           // 3*48*4096
    float* cross = blk + (size_t)3 * N_DIA * 4096;      // M3
    float* dinvp = cross + M3;                          // M3
    unsigned short* Wt  = (unsigned short*)(dinvp + M3);   // 3*DD*DD
    unsigned short* B0  = Wt + (size_t)3 * DD * DD;        // 3*SEG: xb / S1 / S2
    unsigned short* B1  = B0 + 3 * SEG;                    // 3*SEG: h0 rows (live to end)
    unsigned short* B2  = B1 + 3 * SEG;                    // 3*SEG: h0T / h1T
    unsigned short* B3  = B2 + 3 * SEG;                    // 3*SEG: h1 rows
    unsigned short* xb  = B0;
    unsigned short* S1  = B0;   // xb dead after k_g0_gram
    unsigned short* S2  = B0;   // S1 dead after gemm(h1)
    unsigned short* h0r = B1;
    unsigned short* h0T = B2;
    unsigned short* h1T = B2;   // h0T dead after adjS1
    unsigned short* h1r = B3;

    const float th1 = 0.40546510810816438f;  // log(1.5)
    const float th2 = 0.22314355131420976f;  // log(1.25)

    k_pre_wt<<<1536, 256, 0, stream>>>(a, v, l, qmask, Wspk, W0, Wg, out, xb, invn, cross, Wt);
    // merged: gram (blocks 0..143) + h0 gemm -> rows + T (blocks 144..719)
    k_g0_gram<<<720, 256, 0, stream>>>(xb, Wt, b0, h0r, h0T, invn, cross, blk, dinvp);
    // S1 = 0.9*(Ad@h0 + cross terms) + 0.1*h0
    k_adjS<<<dim3(4, N_DIA, 3), 256, 0, stream>>>(blk, cross, dinvp, h0T, h0r, h0r, S1);
    // h1 = relu(th1*(S1@W1) + (1-th1)*S1)  (rows + T)
    k_gemm_s<<<dim3(4, 144), 256, 0, stream>>>(S1, Wt + (size_t)DD * DD, h1r, h1T,
                                               th1, nullptr);
    // S2 = 0.9*(Ad@h1 + cross terms) + 0.1*h0
    k_adjS<<<dim3(4, N_DIA, 3), 256, 0, stream>>>(blk, cross, dinvp, h1T, h1r, h0r, S2);
    // out_h = relu(th2*(S2@W2) + (1-th2)*S2) -> fp32 output
    k_gemm_s<<<dim3(4, 144), 256, 0, stream>>>(S2, Wt + (size_t)2 * DD * DD, nullptr, nullptr,
                                               th2, out);
}

// Round 12
// 176.499 us; speedup vs baseline: 1.3606x; 1.0195x over previous
//
#include <hip/hip_runtime.h>
#include <math.h>

#define N_DIA 48
#define NTOT  3072     // N utterances
#define DD    512      // D == H
#define M3    9216     // 3N
#define SEG   ((size_t)NTOT * DD)

#define SCALE_F 0.99999f
#define PI_F    3.14159274101257324f

typedef __attribute__((ext_vector_type(8))) short frag8;
typedef __attribute__((ext_vector_type(4))) float f32x4;

__device__ __forceinline__ float ang_sim(float cs) {
    float cc = cs * SCALE_F;
    cc = fminf(fmaxf(cc, -SCALE_F), SCALE_F);
    return 1.0f - acosf(cc) / PI_F;
}
__device__ __forceinline__ unsigned short f2bf(float x) {
    union { float f; unsigned int u; } c; c.f = x;
    unsigned int r = c.u + 0x7fffu + ((c.u >> 16) & 1u);
    return (unsigned short)(r >> 16);
}
__device__ __forceinline__ float bf2f(unsigned short h) {
    union { unsigned int u; float f; } c; c.u = ((unsigned int)h) << 16;
    return c.f;
}
__device__ __forceinline__ void gload16(const unsigned short* g, unsigned short* s) {
    __builtin_amdgcn_global_load_lds(
        (const __attribute__((address_space(1))) unsigned int*)g,
        (__attribute__((address_space(3))) unsigned int*)s, 16, 0, 0);
}

// ---------- K1: 768 blocks; each block = pre (4 utterances, register-only) + 1 W-tile ----------
__global__ __launch_bounds__(256) void k_pre_wt(
    const float* __restrict__ a, const float* __restrict__ v,
    const float* __restrict__ l, const float* __restrict__ qmask,
    const float* __restrict__ Wspk, const float* __restrict__ W0,
    const float* __restrict__ Wg,
    float* __restrict__ out, unsigned short* __restrict__ xb,
    float* __restrict__ invn, float* __restrict__ cross,
    unsigned short* __restrict__ Wt)
{
    __shared__ float tile[32][33];
    int b = blockIdx.x;
    {
        // ---- pre phase (no LDS) ----
        int wv = threadIdx.x >> 6, t = threadIdx.x & 63;
        int i = b * 4 + wv;                 // utterance, one wave each
        int pos = i & 63, dia = i >> 6;
        int qb = (pos * N_DIA + dia) * 2;
        float q0 = qmask[qb], q1 = qmask[qb + 1];
        int spk = (q0 >= q1) ? 0 : 1;
        const float4* av4 = (const float4*)(a + (size_t)i * DD);
        const float4* vv4 = (const float4*)(v + (size_t)i * DD);
        const float4* lv4 = (const float4*)(l + (size_t)i * DD);
        const float4* wv4 = (const float4*)(Wspk + (size_t)spk * DD);
        float* ob = out + (size_t)i * 3072;
        float saa = 0, svv = 0, sll = 0, sav = 0, sal = 0, svl = 0;
#pragma unroll
        for (int e = 0; e < 2; e++) {
            int idx = e * 64 + t;           // fully coalesced: lane-major
            float4 xa = av4[idx], xv = vv4[idx], xd = lv4[idx], xw = wv4[idx];
            float4 xL = make_float4(xd.x + xw.x, xd.y + xw.y, xd.z + xw.z, xd.w + xw.w);
            *(float4*)(ob + idx * 4)        = xa;
            *(float4*)(ob + 1024 + idx * 4) = xv;
            *(float4*)(ob + 2048 + idx * 4) = xL;
            ushort4 ya, yv, yl;
            ya.x = f2bf(xa.x); ya.y = f2bf(xa.y); ya.z = f2bf(xa.z); ya.w = f2bf(xa.w);
            yv.x = f2bf(xv.x); yv.y = f2bf(xv.y); yv.z = f2bf(xv.z); yv.w = f2bf(xv.w);
            yl.x = f2bf(xL.x); yl.y = f2bf(xL.y); yl.z = f2bf(xL.z); yl.w = f2bf(xL.w);
            *(ushort4*)(xb + (size_t)i * DD + idx * 4) = ya;
            *(ushort4*)(xb + SEG + (size_t)i * DD + idx * 4) = yv;
            *(ushort4*)(xb + 2 * SEG + (size_t)i * DD + idx * 4) = yl;
            saa += xa.x * xa.x + xa.y * xa.y + xa.z * xa.z + xa.w * xa.w;
            svv += xv.x * xv.x + xv.y * xv.y + xv.z * xv.z + xv.w * xv.w;
            sll += xL.x * xL.x + xL.y * xL.y + xL.z * xL.z + xL.w * xL.w;
            sav += xa.x * xv.x + xa.y * xv.y + xa.z * xv.z + xa.w * xv.w;
            sal += xa.x * xL.x + xa.y * xL.y + xa.z * xL.z + xa.w * xL.w;
            svl += xv.x * xL.x + xv.y * xL.y + xv.z * xL.z + xv.w * xL.w;
        }
#pragma unroll
        for (int off = 32; off; off >>= 1) {
            saa += __shfl_down(saa, off, 64);
            svv += __shfl_down(svv, off, 64);
            sll += __shfl_down(sll, off, 64);
            sav += __shfl_down(sav, off, 64);
            sal += __shfl_down(sal, off, 64);
            svl += __shfl_down(svl, off, 64);
        }
        if (t == 0) {
            float ina = 1.0f / sqrtf(saa);
            float inv_ = 1.0f / sqrtf(svv);
            float inl = 1.0f / sqrtf(sll);
            invn[i] = ina; invn[NTOT + i] = inv_; invn[2 * NTOT + i] = inl;
            cross[i]            = ang_sim(sav * ina * inv_);
            cross[NTOT + i]     = ang_sim(sal * ina * inl);
            cross[2 * NTOT + i] = ang_sim(svl * inv_ * inl);
        }
    }
    {
        // ---- W-tile phase: tile index == block index (768 = 3 x 256) ----
        int mm = b >> 8;
        int rem = b & 255;
        int by = rem >> 4, bx = rem & 15;
        const float* W = (mm == 0) ? W0 : Wg + (size_t)(mm - 1) * DD * DD;
        int t = threadIdx.x, tx = t & 31, ty = t >> 5;
#pragma unroll
        for (int q = 0; q < 4; q++) {
            int k = by * 32 + ty + q * 8;
            tile[ty + q * 8][tx] = W[(size_t)k * DD + bx * 32 + tx];
        }
        __syncthreads();
#pragma unroll
        for (int q = 0; q < 4; q++) {
            int n = bx * 32 + ty + q * 8;
            Wt[(size_t)mm * DD * DD + (size_t)n * DD + by * 32 + tx] = f2bf(tile[tx][ty + q * 8]);
        }
    }
}

// ---------- K2 merged: blocks [0,144): gram (two-phase K-split)
//            blocks [144,720): gemm0 h0 = relu(xb@W0+b0) -> h0 rows + h0T ----------
__global__ __launch_bounds__(256) void k_g0_gram(
    const unsigned short* __restrict__ xb, const unsigned short* __restrict__ Wt,
    const float* __restrict__ bias, unsigned short* __restrict__ h0,
    unsigned short* __restrict__ h0T,
    const float* __restrict__ invn, const float* __restrict__ cross,
    float* __restrict__ blk, float* __restrict__ dinv)
{
    __shared__ __align__(16) char smem[53248];
    int b = blockIdx.x;
    int t = threadIdx.x, lane = t & 63, wv = t >> 6;
    int rsel = lane & 15, quad = lane >> 4;

    if (b < 144) {
        // ---- gram flavor: two-phase K-split (c 0..7, then 8..15), acc order preserved ----
        unsigned short* Xs = (unsigned short*)smem;          // 8 c-tiles x [64][32] = 32 KB
        int d = b % N_DIA, m = b / N_DIA;
        int mrow = m * NTOT + d * 64;
        const unsigned short* src = xb + (size_t)mrow * DD;
        int sunit = ((t & 3) ^ ((t >> 2) & 3)) * 8;          // source pre-swizzle
        int sq = (quad ^ (rsel & 3)) * 8;                    // swizzled read unit
        f32x4 acc[4];
#pragma unroll
        for (int j = 0; j < 4; j++) acc[j] = (f32x4){0.f, 0.f, 0.f, 0.f};
#pragma unroll
        for (int p = 0; p < 2; p++) {
            if (p) __syncthreads();                          // phase-0 reads done
#pragma unroll
            for (int c = 0; c < 8; c++) {
                gload16(src + (size_t)(t >> 2) * DD + (p * 8 + c) * 32 + sunit,
                        &Xs[c * 2048 + wv * 512]);
            }
            __syncthreads();
#pragma unroll
            for (int c = 0; c < 8; c++) {
                const unsigned short* base = &Xs[c * 2048];
                frag8 bf[4];
#pragma unroll
                for (int j = 0; j < 4; j++)
                    bf[j] = *(const frag8*)&base[(j * 16 + rsel) * 32 + sq];
                frag8 af = *(const frag8*)&base[(wv * 16 + rsel) * 32 + sq];
#pragma unroll
                for (int j = 0; j < 4; j++)
                    acc[j] = __builtin_amdgcn_mfma_f32_16x16x32_bf16(af, bf[j], acc[j], 0, 0, 0);
            }
        }

        size_t bbase = (size_t)(m * N_DIA + d) * 4096;
        int rowl0 = wv * 16 + quad * 4;
        float ir[4], rs[4] = {0.f, 0.f, 0.f, 0.f};
#pragma unroll
        for (int r = 0; r < 4; r++) ir[r] = invn[mrow + rowl0 + r];
#pragma unroll
        for (int j = 0; j < 4; j++) {
            int coll = j * 16 + rsel;
            float ic = invn[mrow + coll];
#pragma unroll
            for (int r = 0; r < 4; r++) {
                float sim = ang_sim(acc[j][r] * ir[r] * ic);
                blk[bbase + (size_t)(rowl0 + r) * 64 + coll] = sim;
                rs[r] += sim;
            }
        }
#pragma unroll
        for (int off = 8; off; off >>= 1)
#pragma unroll
            for (int r = 0; r < 4; r++) rs[r] += __shfl_down(rs[r], off, 16);
        if (rsel == 0) {
#pragma unroll
            for (int r = 0; r < 4; r++) {
                int gi = d * 64 + rowl0 + r;
                float c1, c2;
                if (m == 0)      { c1 = cross[gi];        c2 = cross[NTOT + gi]; }
                else if (m == 1) { c1 = cross[gi];        c2 = cross[2 * NTOT + gi]; }
                else             { c1 = cross[NTOT + gi]; c2 = cross[2 * NTOT + gi]; }
                dinv[m * NTOT + gi] = 1.0f / sqrtf(rs[r] + c1 + c2);
            }
        }
        return;
    }

    // ---- gemm0 flavor (BK=64, 8 barriers); emits rows + transposed ----
    // XCD-aware mapping: same-A tiles are 144 apart in block id (144 % 8 == 0 -> same XCD L2)
    unsigned short* const As0 = (unsigned short*)smem;            // [64][64]  8 KB
    unsigned short* const As1 = (unsigned short*)(smem + 8192);
    unsigned short* const Bs0 = (unsigned short*)(smem + 16384);  // [128][64] 16 KB
    unsigned short* const Bs1 = (unsigned short*)(smem + 32768);
    unsigned short* const tR  = (unsigned short*)(smem + 17408);  // [64][136] epilogue overlay
    unsigned short* const tT  = (unsigned short*)(smem + 34816);  // [128][72]

    int b2 = b - 144;
    int by = b2 % 144, bx = b2 / 144;
    int mbase = by * 64, nbase = bx * 128;
    int r8 = lane >> 3, u8 = lane & 7;
    int su8 = (u8 ^ r8) << 3;                  // source pre-swizzle (elements)

    const unsigned short* Ag = xb + (size_t)(mbase + wv * 8 + r8) * DD + su8;
    const unsigned short* Bg = Wt + (size_t)(nbase + wv * 8 + r8) * DD + su8;

    f32x4 acc[8];
#pragma unroll
    for (int i = 0; i < 8; i++) acc[i] = (f32x4){0.f, 0.f, 0.f, 0.f};

#define STAGE64(kt, Asb, Bsb) do { \
    gload16(Ag + (kt) * 64,                    (Asb) + (wv * 8) * 64); \
    gload16(Ag + (size_t)32 * DD + (kt) * 64,  (Asb) + (32 + wv * 8) * 64); \
    gload16(Bg + (kt) * 64,                    (Bsb) + (wv * 8) * 64); \
    gload16(Bg + (size_t)32 * DD + (kt) * 64,  (Bsb) + (32 + wv * 8) * 64); \
    gload16(Bg + (size_t)64 * DD + (kt) * 64,  (Bsb) + (64 + wv * 8) * 64); \
    gload16(Bg + (size_t)96 * DD + (kt) * 64,  (Bsb) + (96 + wv * 8) * 64); \
} while (0)

    STAGE64(0, As0, Bs0);
#pragma unroll
    for (int kt = 0; kt < 8; kt++) {
        __syncthreads();
        const unsigned short* Ac = (kt & 1) ? As1 : As0;
        const unsigned short* Bc = (kt & 1) ? Bs1 : Bs0;
        if (kt < 7) {
            unsigned short* An = (kt & 1) ? As0 : As1;
            unsigned short* Bn = (kt & 1) ? Bs0 : Bs1;
            STAGE64(kt + 1, An, Bn);
        }
#pragma unroll
        for (int ks = 0; ks < 2; ks++) {
            int su = (((ks << 2) + quad) ^ (rsel & 7)) << 3;
            frag8 af[4], bfr[2];
#pragma unroll
            for (int i = 0; i < 4; i++)
                af[i] = *(const frag8*)&Ac[(i * 16 + rsel) * 64 + su];
#pragma unroll
            for (int j = 0; j < 2; j++)
                bfr[j] = *(const frag8*)&Bc[(wv * 32 + j * 16 + rsel) * 64 + su];
#pragma unroll
            for (int i = 0; i < 4; i++)
#pragma unroll
                for (int j = 0; j < 2; j++)
                    acc[i * 2 + j] = __builtin_amdgcn_mfma_f32_16x16x32_bf16(
                        af[i], bfr[j], acc[i * 2 + j], 0, 0, 0);
        }
    }
#undef STAGE64
    __syncthreads();

#pragma unroll
    for (int i = 0; i < 4; i++)
#pragma unroll
        for (int j = 0; j < 2; j++) {
            int cl = wv * 32 + j * 16 + rsel;
            float bv = bias[nbase + cl];
            float vv[4];
#pragma unroll
            for (int rr = 0; rr < 4; rr++)
                vv[rr] = fmaxf(acc[i * 2 + j][rr] + bv, 0.f);
#pragma unroll
            for (int rr = 0; rr < 4; rr++)
                tR[(i * 16 + quad * 4 + rr) * 136 + cl] = f2bf(vv[rr]);
            ushort4 w4;
            w4.x = f2bf(vv[0]); w4.y = f2bf(vv[1]);
            w4.z = f2bf(vv[2]); w4.w = f2bf(vv[3]);
            *(ushort4*)&tT[cl * 72 + i * 16 + quad * 4] = w4;
        }
    __syncthreads();
    {
        int r = t >> 2, c0 = (t & 3) * 32;
        unsigned short* dst = h0 + (size_t)(mbase + r) * DD + nbase + c0;
#pragma unroll
        for (int u = 0; u < 4; u++)
            *(uint4*)(dst + u * 8) = *(const uint4*)&tR[r * 136 + c0 + u * 8];
    }
    {
        int c = t >> 1, r0 = (t & 1) * 32;
        unsigned short* dst = h0T + (size_t)(nbase + c) * M3 + mbase + r0;
#pragma unroll
        for (int u = 0; u < 4; u++)
            *(uint4*)(dst + u * 8) = *(const uint4*)&tT[c * 72 + r0 + u * 8];
    }
}

// ---------- adjS: S = 0.9*(Ad@G + cv1.Gn1 + cv2.Gn2) + 0.1*P0  (bf16 rows, NO relu) ----------
// 128-col chunks: grid (4, N_DIA, 3) = 576 blocks
__global__ __launch_bounds__(256) void k_adjS(
    const float* __restrict__ blk, const float* __restrict__ cross,
    const float* __restrict__ dinv,
    const unsigned short* __restrict__ GT, const unsigned short* __restrict__ Gr,
    const unsigned short* __restrict__ P0, unsigned short* __restrict__ Sout)
{
    __shared__ __align__(16) unsigned short AdL[64 * 64];    //  8 KB swizzled pitch-64
    __shared__ __align__(16) unsigned short GTL[128 * 64];   // 16 KB swizzled pitch-64
    __shared__ __align__(16) unsigned short OT[64 * 136];    // 17 KB out tile
    __shared__ float dv[64];
    int ch = blockIdx.x, d = blockIdx.y, m = blockIdx.z;
    int t = threadIdx.x;
    int lane = t & 63, wv = t >> 6;
    int dbase = d * 64, cbase = ch * 128;
    int rsel = lane & 15, quad = lane >> 4;

    if (t < 64) dv[t] = dinv[m * NTOT + dbase + t];
    __syncthreads();

    size_t bbase = (size_t)(m * N_DIA + d) * 4096;
#pragma unroll
    for (int q = 0; q < 4; q++) {
        int e4 = t + 256 * q;
        int i = e4 >> 4, j4 = e4 & 15;
        float4 w = *(const float4*)(blk + bbase + (size_t)i * 64 + j4 * 4);
        float di = dv[i];
        ushort4 o;
        o.x = f2bf(w.x * di * dv[j4 * 4 + 0]);
        o.y = f2bf(w.y * di * dv[j4 * 4 + 1]);
        o.z = f2bf(w.z * di * dv[j4 * 4 + 2]);
        o.w = f2bf(w.w * di * dv[j4 * 4 + 3]);
        *(ushort4*)((char*)AdL + i * 128 + (((j4 >> 1) ^ (i & 7)) << 4) + ((j4 & 1) << 3)) = o;
    }
#pragma unroll
    for (int p = 0; p < 4; p++) {
        int e = t + 256 * p;
        int cl = e >> 3;
        int uo = e & 7;
        uint4 w = *(const uint4*)(GT + (size_t)(cbase + cl) * M3 + m * NTOT + dbase + uo * 8);
        *(uint4*)((char*)GTL + cl * 128 + ((uo ^ (cl & 7)) << 4)) = w;
    }
    __syncthreads();

    f32x4 acc[8];
#pragma unroll
    for (int i = 0; i < 8; i++) acc[i] = (f32x4){0.f, 0.f, 0.f, 0.f};
#pragma unroll
    for (int kk = 0; kk < 2; kk++) {
        int su = ((kk * 4 + quad) ^ (rsel & 7)) << 4;
        frag8 bfr[4];
#pragma unroll
        for (int it = 0; it < 4; it++)
            bfr[it] = *(const frag8*)((const char*)AdL + (it * 16 + rsel) * 128 + su);
#pragma unroll
        for (int jc = 0; jc < 2; jc++) {
            frag8 af = *(const frag8*)((const char*)GTL + (wv * 32 + jc * 16 + rsel) * 128 + su);
#pragma unroll
            for (int it = 0; it < 4; it++)
                acc[jc * 4 + it] = __builtin_amdgcn_mfma_f32_16x16x32_bf16(
                    af, bfr[it], acc[jc * 4 + it], 0, 0, 0);
        }
    }

    int n1, n2, p1, p2;
    if (m == 0)      { n1 = 1; n2 = 2; p1 = 0; p2 = 1; }
    else if (m == 1) { n1 = 0; n2 = 2; p1 = 0; p2 = 2; }
    else             { n1 = 0; n2 = 1; p1 = 1; p2 = 2; }
#pragma unroll
    for (int it = 0; it < 4; it++) {
        int il = it * 16 + rsel;
        int gi = dbase + il;
        float dm = dv[il];
        float cv1 = cross[p1 * NTOT + gi] * dm * dinv[n1 * NTOT + gi];
        float cv2 = cross[p2 * NTOT + gi] * dm * dinv[n2 * NTOT + gi];
        size_t r1 = (size_t)(n1 * NTOT + gi) * DD;
        size_t r2 = (size_t)(n2 * NTOT + gi) * DD;
        size_t r0 = (size_t)(m * NTOT + gi) * DD;
#pragma unroll
        for (int jc = 0; jc < 2; jc++) {
            int cl = wv * 32 + jc * 16 + quad * 4;
            int cg = cbase + cl;
            ushort4 u1 = *(const ushort4*)(Gr + r1 + cg);
            ushort4 u2 = *(const ushort4*)(Gr + r2 + cg);
            ushort4 u0 = *(const ushort4*)(P0 + r0 + cg);
            f32x4 aa = acc[jc * 4 + it];
            ushort4 w;
            w.x = f2bf(0.9f * (aa[0] + cv1 * bf2f(u1.x) + cv2 * bf2f(u2.x)) + 0.1f * bf2f(u0.x));
            w.y = f2bf(0.9f * (aa[1] + cv1 * bf2f(u1.y) + cv2 * bf2f(u2.y)) + 0.1f * bf2f(u0.y));
            w.z = f2bf(0.9f * (aa[2] + cv1 * bf2f(u1.z) + cv2 * bf2f(u2.z)) + 0.1f * bf2f(u0.z));
            w.w = f2bf(0.9f * (aa[3] + cv1 * bf2f(u1.w) + cv2 * bf2f(u2.w)) + 0.1f * bf2f(u0.w));
            *(ushort4*)&OT[il * 136 + cl] = w;
        }
    }
    __syncthreads();
    {
        int r = t >> 2, c0 = (t & 3) * 32;
        unsigned short* dst = Sout + (size_t)(m * NTOT + dbase + r) * DD + cbase + c0;
#pragma unroll
        for (int u = 0; u < 4; u++)
            *(uint4*)(dst + u * 8) = *(const uint4*)&OT[r * 136 + c0 + u * 8];
    }
}

// ---------- GEMM: h = relu(theta*(S@W) + (1-theta)*S), BK=64 dbuf, XCD-aware 1-D grid ----------
// outF==nullptr: write bf16 rows (oRows) + transposed (oT)
// outF!=nullptr: write fp32 to out at [i*3072 + m*1024 + 512 + col]
__global__ __launch_bounds__(256) void k_gemm_s(
    const unsigned short* __restrict__ A, const unsigned short* __restrict__ W,
    unsigned short* __restrict__ oRows, unsigned short* __restrict__ oT,
    float theta, float* __restrict__ outF)
{
    __shared__ __align__(16) char smem[53248];
    unsigned short* const As0 = (unsigned short*)smem;            // [64][64]  8 KB
    unsigned short* const As1 = (unsigned short*)(smem + 8192);
    unsigned short* const Bs0 = (unsigned short*)(smem + 16384);  // [128][64] 16 KB
    unsigned short* const Bs1 = (unsigned short*)(smem + 32768);
    unsigned short* const tH  = (unsigned short*)smem;            // [64][136] (epilogue overlay)
    unsigned short* const tR  = (unsigned short*)(smem + 17408);  // [64][136]
    unsigned short* const tT  = (unsigned short*)(smem + 34816);  // [128][72]
    float* const tF           = (float*)(smem + 17408);           // [64][132] fp32 (outF mode)

    int t = threadIdx.x, lane = t & 63, wv = t >> 6;
    // XCD-aware: same-A tiles 144 apart in block id (144 % 8 == 0 -> same XCD L2)
    int bl = blockIdx.x;
    int by = bl % 144, bx = bl / 144;
    int mbase = by * 64, nbase = bx * 128;
    int rsel = lane & 15, quad = lane >> 4;
    int r8 = lane >> 3, u8 = lane & 7;
    int su8 = (u8 ^ r8) << 3;

    const unsigned short* Ag = A + (size_t)(mbase + wv * 8 + r8) * DD + su8;
    const unsigned short* Bg = W + (size_t)(nbase + wv * 8 + r8) * DD + su8;

    f32x4 acc[8];
#pragma unroll
    for (int i = 0; i < 8; i++) acc[i] = (f32x4){0.f, 0.f, 0.f, 0.f};

#define STAGE64(kt, Asb, Bsb) do { \
    gload16(Ag + (kt) * 64,                    (Asb) + (wv * 8) * 64); \
    gload16(Ag + (size_t)32 * DD + (kt) * 64,  (Asb) + (32 + wv * 8) * 64); \
    gload16(Bg + (kt) * 64,                    (Bsb) + (wv * 8) * 64); \
    gload16(Bg + (size_t)32 * DD + (kt) * 64,  (Bsb) + (32 + wv * 8) * 64); \
    gload16(Bg + (size_t)64 * DD + (kt) * 64,  (Bsb) + (64 + wv * 8) * 64); \
    gload16(Bg + (size_t)96 * DD + (kt) * 64,  (Bsb) + (96 + wv * 8) * 64); \
} while (0)

    STAGE64(0, As0, Bs0);
#pragma unroll
    for (int kt = 0; kt < 8; kt++) {
        __syncthreads();
        const unsigned short* Ac = (kt & 1) ? As1 : As0;
        const unsigned short* Bc = (kt & 1) ? Bs1 : Bs0;
        if (kt < 7) {
            unsigned short* An = (kt & 1) ? As0 : As1;
            unsigned short* Bn = (kt & 1) ? Bs0 : Bs1;
            STAGE64(kt + 1, An, Bn);
        }
#pragma unroll
        for (int ks = 0; ks < 2; ks++) {
            int su = (((ks << 2) + quad) ^ (rsel & 7)) << 3;
            frag8 af[4], bfr[2];
#pragma unroll
            for (int i = 0; i < 4; i++)
                af[i] = *(const frag8*)&Ac[(i * 16 + rsel) * 64 + su];
#pragma unroll
            for (int j = 0; j < 2; j++)
                bfr[j] = *(const frag8*)&Bc[(wv * 32 + j * 16 + rsel) * 64 + su];
#pragma unroll
            for (int i = 0; i < 4; i++)
#pragma unroll
                for (int j = 0; j < 2; j++)
                    acc[i * 2 + j] = __builtin_amdgcn_mfma_f32_16x16x32_bf16(
                        af[i], bfr[j], acc[i * 2 + j], 0, 0, 0);
        }
    }
#undef STAGE64
    __syncthreads();

    int r = t >> 2, c0 = (t & 3) * 32;
    {
        // stage A-tile for exact fp32 blend (coalesced)
        const unsigned short* srcA = A + (size_t)(mbase + r) * DD + nbase + c0;
#pragma unroll
        for (int u = 0; u < 4; u++)
            *(uint4*)&tH[r * 136 + c0 + u * 8] = *(const uint4*)(srcA + u * 8);
        __syncthreads();
    }
    float omt = 1.0f - theta;
    if (outF == nullptr) {
#pragma unroll
        for (int i = 0; i < 4; i++)
#pragma unroll
            for (int j = 0; j < 2; j++) {
                int cl = wv * 32 + j * 16 + rsel;
                float vv[4];
#pragma unroll
                for (int rr = 0; rr < 4; rr++) {
                    int rl = i * 16 + quad * 4 + rr;
                    vv[rr] = fmaxf(theta * acc[i * 2 + j][rr] + omt * bf2f(tH[rl * 136 + cl]), 0.f);
                }
#pragma unroll
                for (int rr = 0; rr < 4; rr++)
                    tR[(i * 16 + quad * 4 + rr) * 136 + cl] = f2bf(vv[rr]);
                ushort4 w4;
                w4.x = f2bf(vv[0]); w4.y = f2bf(vv[1]);
                w4.z = f2bf(vv[2]); w4.w = f2bf(vv[3]);
                *(ushort4*)&tT[cl * 72 + i * 16 + quad * 4] = w4;
            }
        __syncthreads();
        {
            unsigned short* dst = oRows + (size_t)(mbase + r) * DD + nbase + c0;
#pragma unroll
            for (int u = 0; u < 4; u++)
                *(uint4*)(dst + u * 8) = *(const uint4*)&tR[r * 136 + c0 + u * 8];
        }
        {
            int c = t >> 1, r0 = (t & 1) * 32;
            unsigned short* dst = oT + (size_t)(nbase + c) * M3 + mbase + r0;
#pragma unroll
            for (int u = 0; u < 4; u++)
                *(uint4*)(dst + u * 8) = *(const uint4*)&tT[c * 72 + r0 + u * 8];
        }
    } else {
#pragma unroll
        for (int i = 0; i < 4; i++)
#pragma unroll
            for (int j = 0; j < 2; j++) {
                int cl = wv * 32 + j * 16 + rsel;
#pragma unroll
                for (int rr = 0; rr < 4; rr++) {
                    int rl = i * 16 + quad * 4 + rr;
                    tF[rl * 132 + cl] = fmaxf(theta * acc[i * 2 + j][rr]
                                              + omt * bf2f(tH[rl * 136 + cl]), 0.f);
                }
            }
        __syncthreads();
        int mq = mbase / NTOT;
        int iu0 = mbase - mq * NTOT;
        float* dst = outF + (size_t)(iu0 + r) * 3072 + mq * 1024 + 512 + nbase + c0;
#pragma unroll
        for (int u = 0; u < 8; u++)
            *(float4*)(dst + u * 4) = *(const float4*)&tF[r * 132 + c0 + u * 4];
    }
}

extern "C" void kernel_launch(void* const* d_in, const int* in_sizes, int n_in,
                              void* d_out, int out_size, void* d_ws, size_t ws_size,
                              hipStream_t stream) {
    (void)in_sizes; (void)n_in; (void)out_size; (void)ws_size;
    const float* a     = (const float*)d_in[0];
    const float* v     = (const float*)d_in[1];
    const float* l     = (const float*)d_in[2];
    const float* qmask = (const float*)d_in[3];
    const float* Wspk  = (const float*)d_in[5];
    const float* W0    = (const float*)d_in[6];
    const float* b0    = (const float*)d_in[7];
    const float* Wg    = (const float*)d_in[8];
    float* out = (float*)d_out;
    float* ws = (float*)d_ws;

    float* invn  = ws;                                  // M3
    float* blk   = invn + M3;                           // 3*48*4096
    float* cross = blk + (size_t)3 * N_DIA * 4096;      // M3
    float* dinvp = cross + M3;                          // M3
    unsigned short* Wt  = (unsigned short*)(dinvp + M3);   // 3*DD*DD
    unsigned short* B0  = Wt + (size_t)3 * DD * DD;        // 3*SEG: xb / S1 / S2
    unsigned short* B1  = B0 + 3 * SEG;                    // 3*SEG: h0 rows (live to end)
    unsigned short* B2  = B1 + 3 * SEG;                    // 3*SEG: h0T / h1T
    unsigned short* B3  = B2 + 3 * SEG;                    // 3*SEG: h1 rows
    unsigned short* xb  = B0;
    unsigned short* S1  = B0;   // xb dead after k_g0_gram
    unsigned short* S2  = B0;   // S1 dead after gemm(h1)
    unsigned short* h0r = B1;
    unsigned short* h0T = B2;
    unsigned short* h1T = B2;   // h0T dead after adjS1
    unsigned short* h1r = B3;

    const float th1 = 0.40546510810816438f;  // log(1.5)
    const float th2 = 0.22314355131420976f;  // log(1.25)

    // K1: pre (4 utterances/block) + W-tile (1/block), 768 blocks
    k_pre_wt<<<768, 256, 0, stream>>>(a, v, l, qmask, Wspk, W0, Wg, out, xb, invn, cross, Wt);
    // K2 merged: gram (blocks 0..143) + h0 gemm -> rows + T (blocks 144..719)
    k_g0_gram<<<720, 256, 0, stream>>>(xb, Wt, b0, h0r, h0T, invn, cross, blk, dinvp);
    // K3: S1 = 0.9*(Ad@h0 + cross terms) + 0.1*h0
    k_adjS<<<dim3(4, N_DIA, 3), 256, 0, stream>>>(blk, cross, dinvp, h0T, h0r, h0r, S1);
    // K4: h1 = relu(th1*(S1@W1) + (1-th1)*S1)  (rows + T)
    k_gemm_s<<<576, 256, 0, stream>>>(S1, Wt + (size_t)DD * DD, h1r, h1T, th1, nullptr);
    // K5: S2 = 0.9*(Ad@h1 + cross terms) + 0.1*h0
    k_adjS<<<dim3(4, N_DIA, 3), 256, 0, stream>>>(blk, cross, dinvp, h1T, h1r, h0r, S2);
    // K6: out_h = relu(th2*(S2@W2) + (1-th2)*S2) -> fp32 output
    k_gemm_s<<<576, 256, 0, stream>>>(S2, Wt + (size_t)2 * DD * DD, nullptr, nullptr, th2, out);
}